// Round 5
// baseline (16094.209 us; speedup 1.0000x reference)
//
#include <hip/hip_runtime.h>
#include <hip/hip_bf16.h>

#define DMODEL 256
#define S_TOT  70
#define BATCH  128
#define HEADS  8
#define DHEAD  32
#define PAST_N 50
#define FUT_N  20
#define LAYERS 3
#define FFD    1024

#define BM 32
#define BN 64
#define BK 16

// ---- decode weight-pack layout (uint4 offsets). uint4 = 8 bf16 (k-major) ----
#define LSTRIDE4  114688
#define OFF4_QKV  0
#define OFF4_WO   24576
#define OFF4_CAQ  32768
#define OFF4_CAO  40960
#define OFF4_FF1  49152
#define OFF4_FF2  81920
#define CKV4_OFF  344064
#define TOTAL4    393216
#define NT 512

__device__ __forceinline__ float wave_sum64(float v) {
#pragma unroll
  for (int off = 32; off > 0; off >>= 1) v += __shfl_xor(v, off, 64);
  return v;
}
__device__ __forceinline__ float wave_max64(float v) {
#pragma unroll
  for (int off = 32; off > 0; off >>= 1) v = fmaxf(v, __shfl_xor(v, off, 64));
  return v;
}
__device__ __forceinline__ float gelu_f(float x) {
  return 0.5f * x * (1.0f + erff(x * 0.7071067811865476f));
}
__device__ __forceinline__ uint16_t f2bf(float v) {
  uint32_t b = __float_as_uint(v);
  return (uint16_t)((b + 0x7fffu + ((b >> 16) & 1u)) >> 16);
}
__device__ __forceinline__ float bl16(uint32_t w) { return __uint_as_float(w << 16); }
__device__ __forceinline__ float bh16(uint32_t w) { return __uint_as_float(w & 0xffff0000u); }

// block = 256 threads, one row of 256 elements
__device__ __forceinline__ float ln_norm_256(float x, float g, float b, float* sbuf, int tid) {
  float s = wave_sum64(x);
  if ((tid & 63) == 0) sbuf[tid >> 6] = s;
  __syncthreads();
  float mean = (sbuf[0] + sbuf[1] + sbuf[2] + sbuf[3]) * (1.0f / 256.0f);
  __syncthreads();
  float d = x - mean;
  float vs = wave_sum64(d * d);
  if ((tid & 63) == 0) sbuf[tid >> 6] = vs;
  __syncthreads();
  float var = (sbuf[0] + sbuf[1] + sbuf[2] + sbuf[3]) * (1.0f / 256.0f);
  return d * rsqrtf(var + 1e-5f) * g + b;
}

// ---- register-pipelined column-dot helpers for decode ----
__device__ __forceinline__ void load8g(uint4* dst, const uint4* col, int k8, int N) {
#pragma unroll
  for (int i = 0; i < 8; i++) dst[i] = col[(size_t)(k8 + i) * N];
}
__device__ __forceinline__ float fma8g(const uint4* w, const float4* x4, int k8) {
  float a0 = 0.f, a1 = 0.f, a2 = 0.f, a3 = 0.f;
#pragma unroll
  for (int i = 0; i < 8; i++) {
    const uint4 W = w[i];
    const float4 xa = x4[2 * (k8 + i)];
    const float4 xb = x4[2 * (k8 + i) + 1];
    a0 += bl16(W.x) * xa.x + bh16(W.x) * xa.y;
    a1 += bl16(W.y) * xa.z + bh16(W.y) * xa.w;
    a2 += bl16(W.z) * xb.x + bh16(W.z) * xb.y;
    a3 += bl16(W.w) * xb.z + bh16(W.w) * xb.w;
  }
  return (a0 + a1) + (a2 + a3);
}
// KCH chunks of 8 k8-groups; parity double-buffer (two NAMED buffers, static
// selection -> stays in registers, 64 VGPR of buffer), lookahead 1 chunk.
template <int KCH>
__device__ __forceinline__ float colpipe(const uint4* col, int N, const float4* x4, int k8base) {
  uint4 A[8], B[8];
  load8g(A, col, k8base, N);
  float acc = 0.f;
#pragma unroll
  for (int i = 0; i < KCH; i++) {
    if ((i & 1) == 0) {
      if (i + 1 < KCH) load8g(B, col, k8base + 8 * (i + 1), N);
      acc += fma8g(A, x4, k8base + 8 * i);
    } else {
      if (i + 1 < KCH) load8g(A, col, k8base + 8 * (i + 1), N);
      acc += fma8g(B, x4, k8base + 8 * i);
    }
  }
  return acc;
}

// ======================= prefill kernels (unchanged) =======================
__global__ __launch_bounds__(256) void k_gemm(
    const float* __restrict__ A, const float* __restrict__ W,
    const float* __restrict__ bias, const float* __restrict__ Rres,
    float* __restrict__ C, int M, int N, int K, int act, int outmode,
    float* __restrict__ qout, __hip_bfloat16* __restrict__ kc,
    __hip_bfloat16* __restrict__ vc, __hip_bfloat16* __restrict__ c6,
    int rows_per_b, int pos_base)
{
  __shared__ float As[BK][BM + 2];
  __shared__ float Ws[BK][BN + 4];
  const int tid = threadIdx.x;
  const int bm0 = blockIdx.y * BM;
  const int bn0 = blockIdx.x * BN;
  const int r = tid >> 4, c = tid & 15;
  const int am = tid >> 3, ak = (tid & 7) << 1;
  const int wn = tid >> 2, wk = (tid & 3) << 2;
  const float* Aptr = A + (size_t)(bm0 + am) * K + ak;
  const float* Wptr = W + (size_t)(bn0 + wn) * K + wk;
  float acc[2][4] = {{0.f, 0.f, 0.f, 0.f}, {0.f, 0.f, 0.f, 0.f}};
  for (int k0 = 0; k0 < K; k0 += BK) {
    float2 av = *(const float2*)(Aptr + k0);
    float4 wv = *(const float4*)(Wptr + k0);
    As[ak][am] = av.x;  As[ak + 1][am] = av.y;
    Ws[wk][wn] = wv.x;  Ws[wk + 1][wn] = wv.y;
    Ws[wk + 2][wn] = wv.z;  Ws[wk + 3][wn] = wv.w;
    __syncthreads();
#pragma unroll
    for (int kk = 0; kk < BK; kk++) {
      const float2 a = *(const float2*)&As[kk][r << 1];
      const float4 w = *(const float4*)&Ws[kk][c << 2];
      acc[0][0] += a.x * w.x; acc[0][1] += a.x * w.y;
      acc[0][2] += a.x * w.z; acc[0][3] += a.x * w.w;
      acc[1][0] += a.y * w.x; acc[1][1] += a.y * w.y;
      acc[1][2] += a.y * w.z; acc[1][3] += a.y * w.w;
    }
    __syncthreads();
  }
#pragma unroll
  for (int i = 0; i < 2; i++) {
    const int row = bm0 + (r << 1) + i;
    const int b = row / rows_per_b;
    const int t = pos_base + row % rows_per_b;
#pragma unroll
    for (int j = 0; j < 4; j++) {
      const int n = bn0 + (c << 2) + j;
      float v = acc[i][j] + bias[n];
      if (Rres) v += Rres[(size_t)row * N + n];
      if (act) v = gelu_f(v);
      if (outmode == 0) {
        C[(size_t)row * N + n] = v;
      } else if (outmode == 1) {
        if (n < 256) qout[(size_t)row * DMODEL + n] = v;
        else if (n < 512) kc[((size_t)b * S_TOT + t) * DMODEL + (n - 256)] = __float2bfloat16(v);
        else vc[((size_t)b * S_TOT + t) * DMODEL + (n - 512)] = __float2bfloat16(v);
      } else {
        const int j6 = n >> 8;
        c6[(size_t)j6 * ((size_t)BATCH * S_TOT * DMODEL) +
           ((size_t)b * S_TOT + t) * DMODEL + (n & 255)] = __float2bfloat16(v);
      }
    }
  }
}

__global__ __launch_bounds__(64) void k_attn(
    const float* __restrict__ qbuf, const __hip_bfloat16* __restrict__ kc,
    const __hip_bfloat16* __restrict__ vc, float* __restrict__ outb,
    int rows_per_b, int pos_base)
{
  __shared__ float qs[DHEAD];
  __shared__ float ss[S_TOT];
  const int bid = blockIdx.x;
  const int h = bid & (HEADS - 1);
  const int row = bid >> 3;
  const int b = row / rows_per_b;
  const int t = pos_base + row % rows_per_b;
  const int nk = t + 1;
  const int lane = threadIdx.x;
  if (lane < DHEAD) qs[lane] = qbuf[(size_t)row * DMODEL + h * DHEAD + lane];
  __syncthreads();
  float mx = -1e30f;
  for (int k0 = lane; k0 < nk; k0 += 64) {
    const __hip_bfloat16* kp = kc + ((size_t)b * S_TOT + k0) * DMODEL + h * DHEAD;
    float s = 0.f;
#pragma unroll
    for (int i = 0; i < DHEAD; i++) s += qs[i] * __bfloat162float(kp[i]);
    s *= 0.17677669529663687f;
    ss[k0] = s;
    mx = fmaxf(mx, s);
  }
  mx = wave_max64(mx);
  float sum = 0.f;
  for (int k0 = lane; k0 < nk; k0 += 64) {
    float e = expf(ss[k0] - mx);
    ss[k0] = e;
    sum += e;
  }
  sum = wave_sum64(sum);
  __syncthreads();
  const float inv = 1.0f / sum;
  if (lane < DHEAD) {
    float o = 0.f;
    for (int k0 = 0; k0 < nk; k0++)
      o += ss[k0] * __bfloat162float(vc[((size_t)b * S_TOT + k0) * DMODEL + h * DHEAD + lane]);
    outb[(size_t)row * DMODEL + h * DHEAD + lane] = o * inv;
  }
}

__global__ __launch_bounds__(256) void k_ln(
    const float* __restrict__ Z, const float* __restrict__ g,
    const float* __restrict__ b, float* __restrict__ out)
{
  __shared__ float sbuf[4];
  const int row = blockIdx.x, tid = threadIdx.x;
  float x = Z[(size_t)row * DMODEL + tid];
  out[(size_t)row * DMODEL + tid] = ln_norm_256(x, g[tid], b[tid], sbuf, tid);
}

__global__ __launch_bounds__(256) void k_embed(
    const float* __restrict__ past, const float* __restrict__ in_W,
    const float* __restrict__ in_b, const float* __restrict__ pos_emb,
    const float* __restrict__ ln_w, const float* __restrict__ ln_b,
    float* __restrict__ Aout)
{
  __shared__ float sbuf[4];
  const int rowid = blockIdx.x;
  const int b = rowid / PAST_N, t = rowid % PAST_N;
  const int tid = threadIdx.x;
  float dx = 0.f, dy = 0.f;
  if (t > 0) {
    dx = past[((size_t)b * PAST_N + t) * 2 + 0] - past[((size_t)b * PAST_N + t - 1) * 2 + 0];
    dy = past[((size_t)b * PAST_N + t) * 2 + 1] - past[((size_t)b * PAST_N + t - 1) * 2 + 1];
  }
  float v = in_W[tid * 2 + 0] * dx + in_W[tid * 2 + 1] * dy + in_b[tid] +
            pos_emb[(size_t)t * DMODEL + tid];
  Aout[(size_t)rowid * DMODEL + tid] = ln_norm_256(v, ln_w[tid], ln_b[tid], sbuf, tid);
}

__global__ __launch_bounds__(256) void k_prepack(
    const float* __restrict__ caW, const float* __restrict__ cab,
    float* __restrict__ Wckv, float* __restrict__ bckv)
{
  const int n = blockIdx.x, tid = threadIdx.x;
  const int j = n >> 8, dcol = n & 255;
  const int l = j >> 1, kv = j & 1;
  const int srow = l * 768 + 256 + kv * 256 + dcol;
  Wckv[(size_t)n * 256 + tid] = caW[(size_t)srow * 256 + tid];
  if (tid == 0) bckv[n] = cab[l * 768 + 256 + kv * 256 + dcol];
}

__global__ __launch_bounds__(64) void k_readout(
    const float* __restrict__ X, const float* __restrict__ out_W,
    const float* __restrict__ out_b, const float* __restrict__ past,
    float* __restrict__ cur, float* __restrict__ ndb, float* __restrict__ out,
    int rows_per_b, int s, int init)
{
  const int b = blockIdx.x, lane = threadIdx.x;
  const int row = b * rows_per_b + rows_per_b - 1;
  float p0 = 0.f, p1 = 0.f;
  for (int d = lane; d < DMODEL; d += 64) {
    const float xv = X[(size_t)row * DMODEL + d];
    p0 += xv * out_W[d];
    p1 += xv * out_W[DMODEL + d];
  }
  p0 = wave_sum64(p0);
  p1 = wave_sum64(p1);
  if (lane == 0) {
    const float nd0 = p0 + out_b[0];
    const float nd1 = p1 + out_b[1];
    float c0, c1;
    if (init) {
      c0 = past[((size_t)b * PAST_N + PAST_N - 1) * 2 + 0];
      c1 = past[((size_t)b * PAST_N + PAST_N - 1) * 2 + 1];
    } else {
      c0 = cur[b * 2 + 0];
      c1 = cur[b * 2 + 1];
    }
    c0 += nd0; c1 += nd1;
    cur[b * 2 + 0] = c0; cur[b * 2 + 1] = c1;
    ndb[b * 2 + 0] = nd0; ndb[b * 2 + 1] = nd1;
    out[((size_t)b * FUT_N + s) * 2 + 0] = c0;
    out[((size_t)b * FUT_N + s) * 2 + 1] = c1;
  }
}

// ======================= decode weight pre-pack (uint4, 8 bf16 each) =======
__global__ __launch_bounds__(256) void k_pack_decode4(
    const float* __restrict__ sa_Wqkv, const float* __restrict__ sa_Wo,
    const float* __restrict__ ca_Wqkv, const float* __restrict__ ca_Wo,
    const float* __restrict__ ff1_W, const float* __restrict__ ff2_W,
    uint4* __restrict__ Wp4)
{
  const int g = blockIdx.x * 256 + threadIdx.x;
  if (g >= TOTAL4) return;
  const float* src;
  if (g < CKV4_OFF) {
    const int l = g / LSTRIDE4, r = g % LSTRIDE4;
    if (r < OFF4_WO)       { int rr = r;             int k8 = rr / 768;  int n = rr % 768;  src = sa_Wqkv + (size_t)l * 196608 + (size_t)n * 256  + 8 * k8; }
    else if (r < OFF4_CAQ) { int rr = r - OFF4_WO;   int k8 = rr / 256;  int n = rr % 256;  src = sa_Wo   + (size_t)l * 65536  + (size_t)n * 256  + 8 * k8; }
    else if (r < OFF4_CAO) { int rr = r - OFF4_CAQ;  int k8 = rr / 256;  int n = rr % 256;  src = ca_Wqkv + (size_t)l * 196608 + (size_t)n * 256  + 8 * k8; }
    else if (r < OFF4_FF1) { int rr = r - OFF4_CAO;  int k8 = rr / 256;  int n = rr % 256;  src = ca_Wo   + (size_t)l * 65536  + (size_t)n * 256  + 8 * k8; }
    else if (r < OFF4_FF2) { int rr = r - OFF4_FF1;  int k8 = rr / 1024; int n = rr % 1024; src = ff1_W   + (size_t)l * 262144 + (size_t)n * 256  + 8 * k8; }
    else                   { int rr = r - OFF4_FF2;  int k8 = rr / 256;  int n = rr % 256;  src = ff2_W   + (size_t)l * 262144 + (size_t)n * 1024 + 8 * k8; }
  } else {
    const int r = g - CKV4_OFF;
    const int k8 = r / 1536, n = r % 1536;
    const int j = n >> 8, dcol = n & 255, l = j >> 1, kv = j & 1;
    src = ca_Wqkv + (size_t)l * 196608 + (size_t)(256 + kv * 256 + dcol) * 256 + 8 * k8;
  }
  uint4 u;
  u.x = ((uint32_t)f2bf(src[1]) << 16) | (uint32_t)f2bf(src[0]);
  u.y = ((uint32_t)f2bf(src[3]) << 16) | (uint32_t)f2bf(src[2]);
  u.z = ((uint32_t)f2bf(src[5]) << 16) | (uint32_t)f2bf(src[4]);
  u.w = ((uint32_t)f2bf(src[7]) << 16) | (uint32_t)f2bf(src[6]);
  Wp4[g] = u;
}

// ======================= fused 19-step decode =======================
__global__ __launch_bounds__(NT) void k_decode(
    const uint4* __restrict__ Wp4, const float* __restrict__ bckv,
    const float* __restrict__ in_W, const float* __restrict__ in_b,
    const float* __restrict__ pos_emb,
    const float* __restrict__ ln0_w, const float* __restrict__ ln0_b,
    const float* __restrict__ sa_bqkv, const float* __restrict__ sa_bo,
    const float* __restrict__ ca_bqkv, const float* __restrict__ ca_bo,
    const float* __restrict__ ff1_b, const float* __restrict__ ff2_b,
    const float* __restrict__ ln1_w, const float* __restrict__ ln1_b,
    const float* __restrict__ ln2_w, const float* __restrict__ ln2_b,
    const float* __restrict__ ln3_w, const float* __restrict__ ln3_b,
    const float* __restrict__ out_W, const float* __restrict__ out_b,
    __hip_bfloat16* __restrict__ Ksa, __hip_bfloat16* __restrict__ Vsa,
    __hip_bfloat16* __restrict__ C6,
    const float* __restrict__ ndb, const float* __restrict__ cur,
    float* __restrict__ out)
{
  const int b = blockIdx.x;
  const int tid = threadIdx.x;
  const size_t slab = (size_t)BATCH * S_TOT * DMODEL;

  __shared__ __align__(16) float x[256];
  __shared__ __align__(16) float xt[256];
  __shared__ __align__(16) float q[256];
  __shared__ __align__(16) float att[256];
  __shared__ __align__(16) float hbuf[1024];
  __shared__ float pred[NT];
  __shared__ float kn[256], vn[256];
  __shared__ __align__(16) float ckvn[1536];
  __shared__ float ss[8][72];
  __shared__ float sb[8], sb2[8];
  __shared__ float ndc[4];

  if (tid == 0) {
    ndc[0] = ndb[2 * b];     ndc[1] = ndb[2 * b + 1];
    ndc[2] = cur[2 * b];     ndc[3] = cur[2 * b + 1];
  }
  __syncthreads();

  // value-based LN: normalizes v across tid<256 lanes, stores to dst, syncs
  auto ln_store = [&](float v, const float* g, const float* bb, float* dst) {
    float vv = (tid < 256) ? v : 0.f;
    float s  = wave_sum64(vv);
    float s2 = wave_sum64(vv * vv);
    if ((tid & 63) == 0) { sb[tid >> 6] = s; sb2[tid >> 6] = s2; }
    __syncthreads();
    float mean = (sb[0] + sb[1] + sb[2] + sb[3]) * (1.0f / 256.0f);
    float ex2  = (sb2[0] + sb2[1] + sb2[2] + sb2[3]) * (1.0f / 256.0f);
    float var = ex2 - mean * mean;
    if (tid < 256) dst[tid] = (vv - mean) * rsqrtf(var + 1e-5f) * g[tid] + bb[tid];
    __syncthreads();
  };

  // attention: 1 wave = 1 head; keys 0..pos-1 from bf16 cache, key pos from LDS
  auto attn8 = [&](const __hip_bfloat16* Kc, const __hip_bfloat16* Vc,
                   const float* knw, const float* vnw, int pos) {
    const int h = tid >> 6, lane = tid & 63;
    const float* qh = q + h * 32;
    float mx = -1e30f;
    for (int k0 = lane; k0 <= pos; k0 += 64) {
      float s = 0.f;
      if (k0 == pos) {
        const float* kp = knw + h * 32;
#pragma unroll
        for (int i = 0; i < 32; i++) s += qh[i] * kp[i];
      } else {
        const uint32_t* kp = (const uint32_t*)(Kc + ((size_t)b * S_TOT + k0) * DMODEL + h * 32);
#pragma unroll
        for (int i = 0; i < 16; i++) {
          uint32_t w = kp[i];
          s += bl16(w) * qh[2 * i];
          s += bh16(w) * qh[2 * i + 1];
        }
      }
      s *= 0.17677669529663687f;
      ss[h][k0] = s;
      mx = fmaxf(mx, s);
    }
    mx = wave_max64(mx);
    float sum = 0.f;
    for (int k0 = lane; k0 <= pos; k0 += 64) {
      float e = __expf(ss[h][k0] - mx);
      ss[h][k0] = e;
      sum += e;
    }
    sum = wave_sum64(sum);
    const float inv = 1.0f / sum;
    if (lane < 32) {
      float o = 0.f;
#pragma unroll 4
      for (int k0 = 0; k0 < pos; k0++)
        o += ss[h][k0] * __bfloat162float(Vc[((size_t)b * S_TOT + k0) * DMODEL + h * 32 + lane]);
      o += ss[h][pos] * vnw[h * 32 + lane];
      att[h * 32 + lane] = o * inv;
    }
  };

  const int n8 = tid & 255, half = tid >> 8;

  for (int s = 1; s < FUT_N; s++) {
    const int pos = PAST_N - 1 + s;
    // 1. token embed + LN0 -> xt ; copy to x
    float xe = 0.f;
    if (tid < 256) {
      xe = in_W[tid * 2] * ndc[0] + in_W[tid * 2 + 1] * ndc[1] + in_b[tid] +
           pos_emb[(size_t)pos * DMODEL + tid];
    }
    ln_store(xe, ln0_w, ln0_b, xt);
    if (tid < 256) x[tid] = xt[tid];
    // 2. CA K/V for this token (N=1536, 3 cols/thread), from xt
    {
      const float4* x4 = (const float4*)xt;
      const uint4* W = Wp4 + CKV4_OFF;
      float r0 = colpipe<4>(W + tid, 1536, x4, 0);
      float r1 = colpipe<4>(W + tid + 512, 1536, x4, 0);
      float r2 = colpipe<4>(W + tid + 1024, 1536, x4, 0);
#pragma unroll
      for (int c = 0; c < 3; c++) {
        const int n = tid + c * 512;
        const float rv = (c == 0) ? r0 : (c == 1) ? r1 : r2;
        float v = rv + bckv[n];
        ckvn[n] = v;
        C6[(size_t)(n >> 8) * slab + ((size_t)b * S_TOT + pos) * DMODEL + (n & 255)] =
            __float2bfloat16(v);
      }
      __syncthreads();
    }

    for (int l = 0; l < LAYERS; l++) {
      const uint4* Wl = Wp4 + (size_t)l * LSTRIDE4;
      // a. SA qkv (N=768)
      {
        const float4* x4 = (const float4*)x;
        const uint4* W = Wl + OFF4_QKV;
        float r0 = colpipe<4>(W + tid, 768, x4, 0);
        float r1 = (tid < 256) ? colpipe<4>(W + tid + 512, 768, x4, 0) : 0.f;
        {
          const int n = tid;
          float v = r0 + sa_bqkv[l * 768 + n];
          if (n < 256) q[n] = v;
          else {
            kn[n - 256] = v;
            Ksa[(size_t)l * slab + ((size_t)b * S_TOT + pos) * DMODEL + (n - 256)] =
                __float2bfloat16(v);
          }
        }
        if (tid < 256) {
          const int n = tid + 512;
          float v = r1 + sa_bqkv[l * 768 + n];
          vn[n - 512] = v;
          Vsa[(size_t)l * slab + ((size_t)b * S_TOT + pos) * DMODEL + (n - 512)] =
              __float2bfloat16(v);
        }
        __syncthreads();
      }
      // b. SA attention
      attn8(Ksa + (size_t)l * slab, Vsa + (size_t)l * slab, kn, vn, pos);
      __syncthreads();
      // c. Wo (split-K2) + residual + LN1
      pred[tid] = colpipe<2>(Wl + OFF4_WO + n8, 256, (const float4*)att, half * 16);
      __syncthreads();
      {
        float v = (tid < 256) ? (x[tid] + pred[tid] + pred[tid + 256] + sa_bo[l * 256 + tid]) : 0.f;
        ln_store(v, ln1_w + l * 256, ln1_b + l * 256, x);
      }
      // d. CA q (split-K2)
      pred[tid] = colpipe<2>(Wl + OFF4_CAQ + n8, 256, (const float4*)x, half * 16);
      __syncthreads();
      if (tid < 256) q[tid] = pred[tid] + pred[tid + 256] + ca_bqkv[l * 768 + tid];
      __syncthreads();
      // e. CA attention over C6 caches
      attn8(C6 + (size_t)(2 * l) * slab, C6 + (size_t)(2 * l + 1) * slab,
            ckvn + l * 512, ckvn + l * 512 + 256, pos);
      __syncthreads();
      // f. CA Wo + residual + LN2
      pred[tid] = colpipe<2>(Wl + OFF4_CAO + n8, 256, (const float4*)att, half * 16);
      __syncthreads();
      {
        float v = (tid < 256) ? (x[tid] + pred[tid] + pred[tid + 256] + ca_bo[l * 256 + tid]) : 0.f;
        ln_store(v, ln2_w + l * 256, ln2_b + l * 256, x);
      }
      // g. FF1 + gelu (N=1024, 2 cols/thread)
      {
        const float4* x4 = (const float4*)x;
        const uint4* W = Wl + OFF4_FF1;
        float r0 = colpipe<4>(W + tid, 1024, x4, 0);
        float r1 = colpipe<4>(W + tid + 512, 1024, x4, 0);
        hbuf[tid] = gelu_f(r0 + ff1_b[l * 1024 + tid]);
        hbuf[tid + 512] = gelu_f(r1 + ff1_b[l * 1024 + tid + 512]);
        __syncthreads();
      }
      // h. FF2 (K=1024, split-K2) + residual + LN3
      pred[tid] = colpipe<8>(Wl + OFF4_FF2 + n8, 256, (const float4*)hbuf, half * 64);
      __syncthreads();
      {
        float v = (tid < 256) ? (x[tid] + pred[tid] + pred[tid + 256] + ff2_b[l * 256 + tid]) : 0.f;
        ln_store(v, ln3_w + l * 256, ln3_b + l * 256, x);
      }
    }

    // readout
    {
      const int lane = tid & 63;
      if (tid < 128) {
        const int d0 = tid >> 6;
        float p = 0.f;
        for (int d = lane; d < DMODEL; d += 64) p += x[d] * out_W[d0 * DMODEL + d];
        p = wave_sum64(p);
        if (lane == 0) {
          const float nd = p + out_b[d0];
          ndc[d0] = nd;
          const float c = ndc[2 + d0] + nd;
          ndc[2 + d0] = c;
          out[((size_t)b * FUT_N + s) * 2 + d0] = c;
        }
      }
      __syncthreads();
    }
  }
}

// ======================= host launch =======================
extern "C" void kernel_launch(void* const* d_in, const int* in_sizes, int n_in,
                              void* d_out, int out_size, void* d_ws, size_t ws_size,
                              hipStream_t stream)
{
  const float* past    = (const float*)d_in[0];
  const float* in_W    = (const float*)d_in[1];
  const float* in_b    = (const float*)d_in[2];
  const float* pos_emb = (const float*)d_in[3];
  const float* ln0_w   = (const float*)d_in[4];
  const float* ln0_b   = (const float*)d_in[5];
  const float* sa_Wqkv = (const float*)d_in[6];
  const float* sa_bqkv = (const float*)d_in[7];
  const float* sa_Wo   = (const float*)d_in[8];
  const float* sa_bo   = (const float*)d_in[9];
  const float* ca_Wqkv = (const float*)d_in[10];
  const float* ca_bqkv = (const float*)d_in[11];
  const float* ca_Wo   = (const float*)d_in[12];
  const float* ca_bo   = (const float*)d_in[13];
  const float* ff1_W   = (const float*)d_in[14];
  const float* ff1_b   = (const float*)d_in[15];
  const float* ff2_W   = (const float*)d_in[16];
  const float* ff2_b   = (const float*)d_in[17];
  const float* ln1_w   = (const float*)d_in[18];
  const float* ln1_b   = (const float*)d_in[19];
  const float* ln2_w   = (const float*)d_in[20];
  const float* ln2_b   = (const float*)d_in[21];
  const float* ln3_w   = (const float*)d_in[22];
  const float* ln3_b   = (const float*)d_in[23];
  const float* out_W   = (const float*)d_in[24];
  const float* out_b   = (const float*)d_in[25];
  float* out = (float*)d_out;

  const size_t Mpre = (size_t)BATCH * PAST_N;              // 6400
  const size_t slab = (size_t)BATCH * S_TOT * DMODEL;      // 2,293,760

  float* ws_f = (float*)d_ws;
  float* A    = ws_f;
  float* Bb   = A + Mpre * DMODEL;
  float* qb   = Bb + Mpre * DMODEL;
  float* at   = qb + Mpre * DMODEL;
  float* hb   = at + Mpre * DMODEL;
  float* Wckv = hb + Mpre * FFD;
  float* bckv = Wckv + (size_t)1536 * 256;
  float* ndb  = bckv + 1536;
  float* cur  = ndb + 256;
  __hip_bfloat16* Ksa = (__hip_bfloat16*)(cur + 256);
  __hip_bfloat16* Vsa = Ksa + 3 * slab;
  __hip_bfloat16* C6  = Vsa + 3 * slab;
  uint4* Wp4 = (uint4*)hb;  // aliases hb: free after prefill, used only by decode

  const size_t need = ((size_t)(C6 + 6 * slab) - (size_t)d_ws);
  if (ws_size < need) return;

  auto layer = [&](int l, int M, int rpb, int pbase) {
    const float* Wqkv = sa_Wqkv + (size_t)l * 768 * 256;
    __hip_bfloat16* kcl = Ksa + (size_t)l * slab;
    __hip_bfloat16* vcl = Vsa + (size_t)l * slab;
    k_gemm<<<dim3(768 / BN, M / BM), 256, 0, stream>>>(
        A, Wqkv, sa_bqkv + l * 768, nullptr, nullptr, M, 768, 256, 0, 1,
        qb, kcl, vcl, nullptr, rpb, pbase);
    k_attn<<<M * HEADS, 64, 0, stream>>>(qb, kcl, vcl, at, rpb, pbase);
    k_gemm<<<dim3(256 / BN, M / BM), 256, 0, stream>>>(
        at, sa_Wo + (size_t)l * 65536, sa_bo + l * 256, A, Bb, M, 256, 256, 0, 0,
        nullptr, nullptr, nullptr, nullptr, 1, 0);
    k_ln<<<M, 256, 0, stream>>>(Bb, ln1_w + l * 256, ln1_b + l * 256, A);
    k_gemm<<<dim3(256 / BN, M / BM), 256, 0, stream>>>(
        A, ca_Wqkv + (size_t)l * 768 * 256, ca_bqkv + l * 768, nullptr, qb,
        M, 256, 256, 0, 0, nullptr, nullptr, nullptr, nullptr, 1, 0);
    k_attn<<<M * HEADS, 64, 0, stream>>>(
        qb, C6 + (size_t)(2 * l) * slab, C6 + (size_t)(2 * l + 1) * slab, at, rpb, pbase);
    k_gemm<<<dim3(256 / BN, M / BM), 256, 0, stream>>>(
        at, ca_Wo + (size_t)l * 65536, ca_bo + l * 256, A, Bb, M, 256, 256, 0, 0,
        nullptr, nullptr, nullptr, nullptr, 1, 0);
    k_ln<<<M, 256, 0, stream>>>(Bb, ln2_w + l * 256, ln2_b + l * 256, A);
    k_gemm<<<dim3(FFD / BN, M / BM), 256, 0, stream>>>(
        A, ff1_W + (size_t)l * FFD * 256, ff1_b + l * FFD, nullptr, hb,
        M, FFD, 256, 1, 0, nullptr, nullptr, nullptr, nullptr, 1, 0);
    k_gemm<<<dim3(256 / BN, M / BM), 256, 0, stream>>>(
        hb, ff2_W + (size_t)l * 256 * FFD, ff2_b + l * 256, A, Bb, M, 256, FFD, 0, 0,
        nullptr, nullptr, nullptr, nullptr, 1, 0);
    k_ln<<<M, 256, 0, stream>>>(Bb, ln3_w + l * 256, ln3_b + l * 256, A);
  };

  // ---- prefill over past 50 positions ----
  k_prepack<<<1536, 256, 0, stream>>>(ca_Wqkv, ca_bqkv, Wckv, bckv);
  k_embed<<<(int)Mpre, 256, 0, stream>>>(past, in_W, in_b, pos_emb, ln0_w, ln0_b, A);
  k_gemm<<<dim3(1536 / BN, (int)Mpre / BM), 256, 0, stream>>>(
      A, Wckv, bckv, nullptr, nullptr, (int)Mpre, 1536, 256, 0, 2,
      nullptr, nullptr, nullptr, C6, PAST_N, 0);
  for (int l = 0; l < LAYERS; l++) layer(l, (int)Mpre, PAST_N, 0);
  k_readout<<<BATCH, 64, 0, stream>>>(A, out_W, out_b, past, cur, ndb, out, PAST_N, 0, 1);

  // ---- pack decode weights (into hb scratch, free after prefill) ----
  k_pack_decode4<<<TOTAL4 / 256, 256, 0, stream>>>(
      sa_Wqkv, sa_Wo, ca_Wqkv, ca_Wo, ff1_W, ff2_W, Wp4);

  // ---- fused 19-step decode: one WG per batch element ----
  k_decode<<<BATCH, NT, 0, stream>>>(
      Wp4, bckv, in_W, in_b, pos_emb, ln0_w, ln0_b,
      sa_bqkv, sa_bo, ca_bqkv, ca_bo, ff1_b, ff2_b,
      ln1_w, ln1_b, ln2_w, ln2_b, ln3_w, ln3_b,
      out_W, out_b, Ksa, Vsa, C6, ndb, cur, out);
}

// Round 6
// 5826.085 us; speedup vs baseline: 2.7624x; 2.7624x over previous
//
#include <hip/hip_runtime.h>
#include <hip/hip_bf16.h>

#define DMODEL 256
#define S_TOT  70
#define BATCH  128
#define HEADS  8
#define DHEAD  32
#define PAST_N 50
#define FUT_N  20
#define LAYERS 3
#define FFD    1024

#define BM 32
#define BN 64
#define BK 16

#define NT 512
// ---- decode weight stream: 212 tiles of 2048 uint4 (32KB) per step, in
// exact consumption order: CKV(32) + per layer [QKV 16 | WO 4 | CAQ 4 |
// CAO 4 | FF1 16 | FF2 16]. Tiles with N<2048 row-pad (pad never read).
#define TILES_STEP 212
#define TILE_U4    2048
#define TOTAL_U4   (TILES_STEP * TILE_U4)

__device__ __forceinline__ float wave_sum64(float v) {
#pragma unroll
  for (int off = 32; off > 0; off >>= 1) v += __shfl_xor(v, off, 64);
  return v;
}
__device__ __forceinline__ float wave_max64(float v) {
#pragma unroll
  for (int off = 32; off > 0; off >>= 1) v = fmaxf(v, __shfl_xor(v, off, 64));
  return v;
}
__device__ __forceinline__ float gelu_f(float x) {
  return 0.5f * x * (1.0f + erff(x * 0.7071067811865476f));
}
__device__ __forceinline__ uint16_t f2bf(float v) {
  uint32_t b = __float_as_uint(v);
  return (uint16_t)((b + 0x7fffu + ((b >> 16) & 1u)) >> 16);
}
__device__ __forceinline__ float bl16(uint32_t w) { return __uint_as_float(w << 16); }
__device__ __forceinline__ float bh16(uint32_t w) { return __uint_as_float(w & 0xffff0000u); }

__device__ __forceinline__ float fma8u(uint4 W, float4 xa, float4 xb, float acc) {
  acc += bl16(W.x) * xa.x + bh16(W.x) * xa.y;
  acc += bl16(W.y) * xa.z + bh16(W.y) * xa.w;
  acc += bl16(W.z) * xb.x + bh16(W.z) * xb.y;
  acc += bl16(W.w) * xb.z + bh16(W.w) * xb.w;
  return acc;
}

// raw barrier + LDS fence (no vmcnt drain — preserves weight prefetch queue)
#define SYNC() do { __builtin_amdgcn_sched_barrier(0); \
  asm volatile("s_waitcnt lgkmcnt(0)" ::: "memory"); \
  __builtin_amdgcn_s_barrier(); \
  __builtin_amdgcn_sched_barrier(0); } while (0)
// full drain (step boundary hygiene)
#define SYNCV() do { __builtin_amdgcn_sched_barrier(0); \
  asm volatile("s_waitcnt vmcnt(0) lgkmcnt(0)" ::: "memory"); \
  __builtin_amdgcn_s_barrier(); \
  __builtin_amdgcn_sched_barrier(0); } while (0)

__device__ __forceinline__ void gld_lds16(const uint4* g, uint4* l) {
  __builtin_amdgcn_global_load_lds(
      (const __attribute__((address_space(1))) void*)g,
      (__attribute__((address_space(3))) void*)l, 16, 0, 0);
}

// block = 256 threads, one row of 256 elements (prefill LN)
__device__ __forceinline__ float ln_norm_256(float x, float g, float b, float* sbuf, int tid) {
  float s = wave_sum64(x);
  if ((tid & 63) == 0) sbuf[tid >> 6] = s;
  __syncthreads();
  float mean = (sbuf[0] + sbuf[1] + sbuf[2] + sbuf[3]) * (1.0f / 256.0f);
  __syncthreads();
  float d = x - mean;
  float vs = wave_sum64(d * d);
  if ((tid & 63) == 0) sbuf[tid >> 6] = vs;
  __syncthreads();
  float var = (sbuf[0] + sbuf[1] + sbuf[2] + sbuf[3]) * (1.0f / 256.0f);
  return d * rsqrtf(var + 1e-5f) * g + b;
}

// ======================= prefill kernels (unchanged) =======================
__global__ __launch_bounds__(256) void k_gemm(
    const float* __restrict__ A, const float* __restrict__ W,
    const float* __restrict__ bias, const float* __restrict__ Rres,
    float* __restrict__ C, int M, int N, int K, int act, int outmode,
    float* __restrict__ qout, __hip_bfloat16* __restrict__ kc,
    __hip_bfloat16* __restrict__ vc, __hip_bfloat16* __restrict__ c6,
    int rows_per_b, int pos_base)
{
  __shared__ float As[BK][BM + 2];
  __shared__ float Ws[BK][BN + 4];
  const int tid = threadIdx.x;
  const int bm0 = blockIdx.y * BM;
  const int bn0 = blockIdx.x * BN;
  const int r = tid >> 4, c = tid & 15;
  const int am = tid >> 3, ak = (tid & 7) << 1;
  const int wn = tid >> 2, wk = (tid & 3) << 2;
  const float* Aptr = A + (size_t)(bm0 + am) * K + ak;
  const float* Wptr = W + (size_t)(bn0 + wn) * K + wk;
  float acc[2][4] = {{0.f, 0.f, 0.f, 0.f}, {0.f, 0.f, 0.f, 0.f}};
  for (int k0 = 0; k0 < K; k0 += BK) {
    float2 av = *(const float2*)(Aptr + k0);
    float4 wv = *(const float4*)(Wptr + k0);
    As[ak][am] = av.x;  As[ak + 1][am] = av.y;
    Ws[wk][wn] = wv.x;  Ws[wk + 1][wn] = wv.y;
    Ws[wk + 2][wn] = wv.z;  Ws[wk + 3][wn] = wv.w;
    __syncthreads();
#pragma unroll
    for (int kk = 0; kk < BK; kk++) {
      const float2 a = *(const float2*)&As[kk][r << 1];
      const float4 w = *(const float4*)&Ws[kk][c << 2];
      acc[0][0] += a.x * w.x; acc[0][1] += a.x * w.y;
      acc[0][2] += a.x * w.z; acc[0][3] += a.x * w.w;
      acc[1][0] += a.y * w.x; acc[1][1] += a.y * w.y;
      acc[1][2] += a.y * w.z; acc[1][3] += a.y * w.w;
    }
    __syncthreads();
  }
#pragma unroll
  for (int i = 0; i < 2; i++) {
    const int row = bm0 + (r << 1) + i;
    const int b = row / rows_per_b;
    const int t = pos_base + row % rows_per_b;
#pragma unroll
    for (int j = 0; j < 4; j++) {
      const int n = bn0 + (c << 2) + j;
      float v = acc[i][j] + bias[n];
      if (Rres) v += Rres[(size_t)row * N + n];
      if (act) v = gelu_f(v);
      if (outmode == 0) {
        C[(size_t)row * N + n] = v;
      } else if (outmode == 1) {
        if (n < 256) qout[(size_t)row * DMODEL + n] = v;
        else if (n < 512) kc[((size_t)b * S_TOT + t) * DMODEL + (n - 256)] = __float2bfloat16(v);
        else vc[((size_t)b * S_TOT + t) * DMODEL + (n - 512)] = __float2bfloat16(v);
      } else {
        const int j6 = n >> 8;
        c6[(size_t)j6 * ((size_t)BATCH * S_TOT * DMODEL) +
           ((size_t)b * S_TOT + t) * DMODEL + (n & 255)] = __float2bfloat16(v);
      }
    }
  }
}

__global__ __launch_bounds__(64) void k_attn(
    const float* __restrict__ qbuf, const __hip_bfloat16* __restrict__ kc,
    const __hip_bfloat16* __restrict__ vc, float* __restrict__ outb,
    int rows_per_b, int pos_base)
{
  __shared__ float qs[DHEAD];
  __shared__ float ss[S_TOT];
  const int bid = blockIdx.x;
  const int h = bid & (HEADS - 1);
  const int row = bid >> 3;
  const int b = row / rows_per_b;
  const int t = pos_base + row % rows_per_b;
  const int nk = t + 1;
  const int lane = threadIdx.x;
  if (lane < DHEAD) qs[lane] = qbuf[(size_t)row * DMODEL + h * DHEAD + lane];
  __syncthreads();
  float mx = -1e30f;
  for (int k0 = lane; k0 < nk; k0 += 64) {
    const __hip_bfloat16* kp = kc + ((size_t)b * S_TOT + k0) * DMODEL + h * DHEAD;
    float s = 0.f;
#pragma unroll
    for (int i = 0; i < DHEAD; i++) s += qs[i] * __bfloat162float(kp[i]);
    s *= 0.17677669529663687f;
    ss[k0] = s;
    mx = fmaxf(mx, s);
  }
  mx = wave_max64(mx);
  float sum = 0.f;
  for (int k0 = lane; k0 < nk; k0 += 64) {
    float e = expf(ss[k0] - mx);
    ss[k0] = e;
    sum += e;
  }
  sum = wave_sum64(sum);
  __syncthreads();
  const float inv = 1.0f / sum;
  if (lane < DHEAD) {
    float o = 0.f;
    for (int k0 = 0; k0 < nk; k0++)
      o += ss[k0] * __bfloat162float(vc[((size_t)b * S_TOT + k0) * DMODEL + h * DHEAD + lane]);
    outb[(size_t)row * DMODEL + h * DHEAD + lane] = o * inv;
  }
}

__global__ __launch_bounds__(256) void k_ln(
    const float* __restrict__ Z, const float* __restrict__ g,
    const float* __restrict__ b, float* __restrict__ out)
{
  __shared__ float sbuf[4];
  const int row = blockIdx.x, tid = threadIdx.x;
  float x = Z[(size_t)row * DMODEL + tid];
  out[(size_t)row * DMODEL + tid] = ln_norm_256(x, g[tid], b[tid], sbuf, tid);
}

__global__ __launch_bounds__(256) void k_embed(
    const float* __restrict__ past, const float* __restrict__ in_W,
    const float* __restrict__ in_b, const float* __restrict__ pos_emb,
    const float* __restrict__ ln_w, const float* __restrict__ ln_b,
    float* __restrict__ Aout)
{
  __shared__ float sbuf[4];
  const int rowid = blockIdx.x;
  const int b = rowid / PAST_N, t = rowid % PAST_N;
  const int tid = threadIdx.x;
  float dx = 0.f, dy = 0.f;
  if (t > 0) {
    dx = past[((size_t)b * PAST_N + t) * 2 + 0] - past[((size_t)b * PAST_N + t - 1) * 2 + 0];
    dy = past[((size_t)b * PAST_N + t) * 2 + 1] - past[((size_t)b * PAST_N + t - 1) * 2 + 1];
  }
  float v = in_W[tid * 2 + 0] * dx + in_W[tid * 2 + 1] * dy + in_b[tid] +
            pos_emb[(size_t)t * DMODEL + tid];
  Aout[(size_t)rowid * DMODEL + tid] = ln_norm_256(v, ln_w[tid], ln_b[tid], sbuf, tid);
}

__global__ __launch_bounds__(256) void k_prepack(
    const float* __restrict__ caW, const float* __restrict__ cab,
    float* __restrict__ Wckv, float* __restrict__ bckv)
{
  const int n = blockIdx.x, tid = threadIdx.x;
  const int j = n >> 8, dcol = n & 255;
  const int l = j >> 1, kv = j & 1;
  const int srow = l * 768 + 256 + kv * 256 + dcol;
  Wckv[(size_t)n * 256 + tid] = caW[(size_t)srow * 256 + tid];
  if (tid == 0) bckv[n] = cab[l * 768 + 256 + kv * 256 + dcol];
}

__global__ __launch_bounds__(64) void k_readout(
    const float* __restrict__ X, const float* __restrict__ out_W,
    const float* __restrict__ out_b, const float* __restrict__ past,
    float* __restrict__ cur, float* __restrict__ ndb, float* __restrict__ out,
    int rows_per_b, int s, int init)
{
  const int b = blockIdx.x, lane = threadIdx.x;
  const int row = b * rows_per_b + rows_per_b - 1;
  float p0 = 0.f, p1 = 0.f;
  for (int d = lane; d < DMODEL; d += 64) {
    const float xv = X[(size_t)row * DMODEL + d];
    p0 += xv * out_W[d];
    p1 += xv * out_W[DMODEL + d];
  }
  p0 = wave_sum64(p0);
  p1 = wave_sum64(p1);
  if (lane == 0) {
    const float nd0 = p0 + out_b[0];
    const float nd1 = p1 + out_b[1];
    float c0, c1;
    if (init) {
      c0 = past[((size_t)b * PAST_N + PAST_N - 1) * 2 + 0];
      c1 = past[((size_t)b * PAST_N + PAST_N - 1) * 2 + 1];
    } else {
      c0 = cur[b * 2 + 0];
      c1 = cur[b * 2 + 1];
    }
    c0 += nd0; c1 += nd1;
    cur[b * 2 + 0] = c0; cur[b * 2 + 1] = c1;
    ndb[b * 2 + 0] = nd0; ndb[b * 2 + 1] = nd1;
    out[((size_t)b * FUT_N + s) * 2 + 0] = c0;
    out[((size_t)b * FUT_N + s) * 2 + 1] = c1;
  }
}

// ======================= decode stream pack =======================
// One thread per uint4 of the 212-tile stream. Tile t, off in [0,2048):
//   t<32            : CKV  row k8=t,        n=off (<1536)
//   else r=t-32, l=r/60, p=r%60:
//     p<16 : QKV  rows 2p+off/768,   n=off%768 (off<1536)
//     p<20 : WO   k8=8(p-16)+off/256, n=off&255
//     p<24 : CAQ  k8=8(p-20)+off/256, n=off&255
//     p<28 : CAO  k8=8(p-24)+off/256, n=off&255
//     p<44 : FF1  rows 2(p-28)+off/1024, n=off&1023
//     else : FF2  k8=8(p-44)+off/256, n=off&255   (K=1024 source)
__global__ __launch_bounds__(256) void k_pack_stream(
    const float* __restrict__ sa_Wqkv, const float* __restrict__ sa_Wo,
    const float* __restrict__ ca_Wqkv, const float* __restrict__ ca_Wo,
    const float* __restrict__ ff1_W, const float* __restrict__ ff2_W,
    uint4* __restrict__ Wd)
{
  const unsigned g = blockIdx.x * 256 + threadIdx.x;
  if (g >= TOTAL_U4) return;
  const unsigned tile = g >> 11, off = g & 2047u;
  const float* src = nullptr;
  if (tile < 32) {
    if (off < 1536) {
      const int k8 = tile, n = off;
      const int j = n >> 8, dcol = n & 255, l = j >> 1, kv = j & 1;
      src = ca_Wqkv + (size_t)l * 196608 + (size_t)(256 + kv * 256 + dcol) * 256 + 8 * k8;
    }
  } else {
    const unsigned r = tile - 32, l = r / 60, p = r % 60;
    if (p < 16) {
      if (off < 1536) {
        const int row = off / 768, n = off % 768, k8 = 2 * p + row;
        src = sa_Wqkv + (size_t)l * 196608 + (size_t)n * 256 + 8 * k8;
      }
    } else if (p < 20) {
      const int k8 = 8 * (p - 16) + (off >> 8), n = off & 255;
      src = sa_Wo + (size_t)l * 65536 + (size_t)n * 256 + 8 * k8;
    } else if (p < 24) {
      const int k8 = 8 * (p - 20) + (off >> 8), n = off & 255;
      src = ca_Wqkv + (size_t)l * 196608 + (size_t)n * 256 + 8 * k8;
    } else if (p < 28) {
      const int k8 = 8 * (p - 24) + (off >> 8), n = off & 255;
      src = ca_Wo + (size_t)l * 65536 + (size_t)n * 256 + 8 * k8;
    } else if (p < 44) {
      const int row = off >> 10, n = off & 1023, k8 = 2 * (p - 28) + row;
      src = ff1_W + (size_t)l * 262144 + (size_t)n * 256 + 8 * k8;
    } else {
      const int k8 = 8 * (p - 44) + (off >> 8), n = off & 255;
      src = ff2_W + (size_t)l * 262144 + (size_t)n * 1024 + 8 * k8;
    }
  }
  uint4 u = {0u, 0u, 0u, 0u};
  if (src) {
    u.x = ((uint32_t)f2bf(src[1]) << 16) | (uint32_t)f2bf(src[0]);
    u.y = ((uint32_t)f2bf(src[3]) << 16) | (uint32_t)f2bf(src[2]);
    u.z = ((uint32_t)f2bf(src[5]) << 16) | (uint32_t)f2bf(src[4]);
    u.w = ((uint32_t)f2bf(src[7]) << 16) | (uint32_t)f2bf(src[6]);
  }
  Wd[g] = u;
}

// ======================= fused 19-step decode =======================
// one WG (512 thr) per batch element; weights stream through a 3-slot 96KB
// LDS ring via global_load_lds; counted vmcnt keeps 2 tiles (64KB) in flight.
__global__ __launch_bounds__(NT) void k_decode(
    const uint4* __restrict__ Wd, const float* __restrict__ bckv,
    const float* __restrict__ in_W, const float* __restrict__ in_b,
    const float* __restrict__ pos_emb,
    const float* __restrict__ ln0_w, const float* __restrict__ ln0_b,
    const float* __restrict__ sa_bqkv, const float* __restrict__ sa_bo,
    const float* __restrict__ ca_bqkv, const float* __restrict__ ca_bo,
    const float* __restrict__ ff1_b, const float* __restrict__ ff2_b,
    const float* __restrict__ ln1_w, const float* __restrict__ ln1_b,
    const float* __restrict__ ln2_w, const float* __restrict__ ln2_b,
    const float* __restrict__ ln3_w, const float* __restrict__ ln3_b,
    const float* __restrict__ out_W, const float* __restrict__ out_b,
    __hip_bfloat16* __restrict__ Ksa, __hip_bfloat16* __restrict__ Vsa,
    __hip_bfloat16* __restrict__ C6,
    const float* __restrict__ ndb, const float* __restrict__ cur,
    float* __restrict__ out)
{
  const int b = blockIdx.x;
  const int tid = threadIdx.x;
  const size_t slab = (size_t)BATCH * S_TOT * DMODEL;

  __shared__ __align__(16) uint4 lds_w[3 * TILE_U4];   // 96 KB
  __shared__ __align__(16) float x[256];
  __shared__ __align__(16) float xt[256];
  __shared__ __align__(16) float q[256];
  __shared__ __align__(16) float att[256];
  __shared__ __align__(16) float hbuf[1024];
  __shared__ float pred[NT];
  __shared__ float kn[256], vn[256];
  __shared__ __align__(16) float ckvn[1536];
  __shared__ float ss[8][72];
  __shared__ float sb[8], sb2[8];
  __shared__ float ndc[4];

  const float4* x4x = (const float4*)x;
  const float4* x4t = (const float4*)xt;
  const float4* a4  = (const float4*)att;
  const float4* h4  = (const float4*)hbuf;

  if (tid == 0) {
    ndc[0] = ndb[2 * b];     ndc[1] = ndb[2 * b + 1];
    ndc[2] = cur[2 * b];     ndc[3] = cur[2 * b + 1];
  }

  auto issue_tile = [&](unsigned g) {
    const unsigned sidx = g % (unsigned)TILES_STEP;
    const unsigned slot = g % 3u;
    const uint4* src = Wd + (size_t)sidx * TILE_U4 + tid;
    uint4* dst = &lds_w[slot * TILE_U4 + tid];
#pragma unroll
    for (int j = 0; j < 4; j++) gld_lds16(src + j * 512, dst + j * 512);
  };
  // entering compute of tile g: ensure g landed (<=4 younger in flight),
  // barrier (everyone done with tile g-1's slot), then issue g+2 into it.
  auto tile_wait_issue = [&](unsigned g) {
    __builtin_amdgcn_sched_barrier(0);
    asm volatile("s_waitcnt vmcnt(4) lgkmcnt(0)" ::: "memory");
    __builtin_amdgcn_sched_barrier(0);
    __builtin_amdgcn_s_barrier();
    __builtin_amdgcn_sched_barrier(0);
    issue_tile(g + 2);
    __builtin_amdgcn_sched_barrier(0);
  };

  auto ln_store = [&](float v, const float* g, const float* bb, float* dst) {
    float vv = (tid < 256) ? v : 0.f;
    float s  = wave_sum64(vv);
    float s2 = wave_sum64(vv * vv);
    if ((tid & 63) == 0) { sb[tid >> 6] = s; sb2[tid >> 6] = s2; }
    SYNC();
    float mean = (sb[0] + sb[1] + sb[2] + sb[3]) * (1.0f / 256.0f);
    float ex2  = (sb2[0] + sb2[1] + sb2[2] + sb2[3]) * (1.0f / 256.0f);
    float var = ex2 - mean * mean;
    if (tid < 256) dst[tid] = (vv - mean) * rsqrtf(var + 1e-5f) * g[tid] + bb[tid];
    SYNC();
  };

  auto attn8 = [&](const __hip_bfloat16* Kc, const __hip_bfloat16* Vc,
                   const float* knw, const float* vnw, int pos) {
    const int h = tid >> 6, lane = tid & 63;
    const float* qh = q + h * 32;
    float mx = -1e30f;
    for (int k0 = lane; k0 <= pos; k0 += 64) {
      float s = 0.f;
      if (k0 == pos) {
        const float* kp = knw + h * 32;
#pragma unroll
        for (int i = 0; i < 32; i++) s += qh[i] * kp[i];
      } else {
        const uint32_t* kp = (const uint32_t*)(Kc + ((size_t)b * S_TOT + k0) * DMODEL + h * 32);
#pragma unroll
        for (int i = 0; i < 16; i++) {
          uint32_t w = kp[i];
          s += bl16(w) * qh[2 * i];
          s += bh16(w) * qh[2 * i + 1];
        }
      }
      s *= 0.17677669529663687f;
      ss[h][k0] = s;
      mx = fmaxf(mx, s);
    }
    mx = wave_max64(mx);
    float sum = 0.f;
    for (int k0 = lane; k0 <= pos; k0 += 64) {
      float e = __expf(ss[h][k0] - mx);
      ss[h][k0] = e;
      sum += e;
    }
    sum = wave_sum64(sum);
    const float inv = 1.0f / sum;
    if (lane < 32) {
      float o = 0.f;
#pragma unroll 4
      for (int k0 = 0; k0 < pos; k0++)
        o += ss[h][k0] * __bfloat162float(Vc[((size_t)b * S_TOT + k0) * DMODEL + h * 32 + lane]);
      o += ss[h][pos] * vnw[h * 32 + lane];
      att[h * 32 + lane] = o * inv;
    }
  };

  const int n8 = tid & 255, half = tid >> 8;
  unsigned gt = 0;
  issue_tile(0);
  issue_tile(1);

  for (int s = 1; s < FUT_N; s++) {
    const int pos = PAST_N - 1 + s;
    SYNCV();  // step-boundary drain (ndc / cache-store visibility hygiene)

    // 1. token embed + LN0 -> xt ; copy to x
    float xe = 0.f;
    if (tid < 256) {
      xe = in_W[tid * 2] * ndc[0] + in_W[tid * 2 + 1] * ndc[1] + in_b[tid] +
           pos_emb[(size_t)pos * DMODEL + tid];
    }
    ln_store(xe, ln0_w, ln0_b, xt);
    if (tid < 256) x[tid] = xt[tid];

    // 2. CKV: 32 tiles, cols tid, tid+512, tid+1024, x = xt
    {
      float a0 = 0.f, a1 = 0.f, a2 = 0.f;
      for (int t = 0; t < 32; t++) {
        tile_wait_issue(gt);
        const uint4* T = &lds_w[(gt % 3u) * TILE_U4];
        const float4 xa = x4t[2 * t], xb = x4t[2 * t + 1];
        a0 = fma8u(T[tid],        xa, xb, a0);
        a1 = fma8u(T[tid + 512],  xa, xb, a1);
        a2 = fma8u(T[tid + 1024], xa, xb, a2);
        gt++;
      }
      float v0 = a0 + bckv[tid];
      float v1 = a1 + bckv[tid + 512];
      float v2 = a2 + bckv[tid + 1024];
      ckvn[tid] = v0; ckvn[tid + 512] = v1; ckvn[tid + 1024] = v2;
      {
        int n = tid;
        C6[(size_t)(n >> 8) * slab + ((size_t)b * S_TOT + pos) * DMODEL + (n & 255)] = __float2bfloat16(v0);
        n = tid + 512;
        C6[(size_t)(n >> 8) * slab + ((size_t)b * S_TOT + pos) * DMODEL + (n & 255)] = __float2bfloat16(v1);
        n = tid + 1024;
        C6[(size_t)(n >> 8) * slab + ((size_t)b * S_TOT + pos) * DMODEL + (n & 255)] = __float2bfloat16(v2);
      }
      SYNC();
    }

    for (int l = 0; l < LAYERS; l++) {
      // a. QKV: 16 tiles (rows 2t,2t+1 of [32][768]); x source = x
      {
        float q0 = 0.f, q1 = 0.f;
        for (int t = 0; t < 16; t++) {
          tile_wait_issue(gt);
          const uint4* T = &lds_w[(gt % 3u) * TILE_U4];
          const float4 xa0 = x4x[4 * t],     xb0 = x4x[4 * t + 1];
          const float4 xa1 = x4x[4 * t + 2], xb1 = x4x[4 * t + 3];
          q0 = fma8u(T[tid],       xa0, xb0, q0);
          q0 = fma8u(T[768 + tid], xa1, xb1, q0);
          if (tid < 256) {
            q1 = fma8u(T[512 + tid],  xa0, xb0, q1);
            q1 = fma8u(T[1280 + tid], xa1, xb1, q1);
          }
          gt++;
        }
        {
          const int n = tid;
          float v = q0 + sa_bqkv[l * 768 + n];
          if (n < 256) q[n] = v;
          else {
            kn[n - 256] = v;
            Ksa[(size_t)l * slab + ((size_t)b * S_TOT + pos) * DMODEL + (n - 256)] = __float2bfloat16(v);
          }
        }
        if (tid < 256) {
          const int n = tid + 512;
          float v = q1 + sa_bqkv[l * 768 + n];
          vn[n - 512] = v;
          Vsa[(size_t)l * slab + ((size_t)b * S_TOT + pos) * DMODEL + (n - 512)] = __float2bfloat16(v);
        }
        SYNC();
      }
      // b. SA attention
      attn8(Ksa + (size_t)l * slab, Vsa + (size_t)l * slab, kn, vn, pos);
      SYNC();
      // c. WO: 4 tiles (rows 8t..8t+7 of [32][256]); split-K by half; x = att
      {
        float acc = 0.f;
        for (int t = 0; t < 4; t++) {
          tile_wait_issue(gt);
          const uint4* T = &lds_w[(gt % 3u) * TILE_U4];
#pragma unroll
          for (int rr = 0; rr < 4; rr++) {
            const int k8 = 8 * t + 4 * half + rr;
            acc = fma8u(T[(4 * half + rr) * 256 + n8], a4[2 * k8], a4[2 * k8 + 1], acc);
          }
          gt++;
        }
        pred[tid] = acc;
        SYNC();
        float v = (tid < 256) ? (x[tid] + pred[tid] + pred[tid + 256] + sa_bo[l * 256 + tid]) : 0.f;
        ln_store(v, ln1_w + l * 256, ln1_b + l * 256, x);
      }
      // d. CAQ: 4 tiles; x source = x
      {
        float acc = 0.f;
        for (int t = 0; t < 4; t++) {
          tile_wait_issue(gt);
          const uint4* T = &lds_w[(gt % 3u) * TILE_U4];
#pragma unroll
          for (int rr = 0; rr < 4; rr++) {
            const int k8 = 8 * t + 4 * half + rr;
            acc = fma8u(T[(4 * half + rr) * 256 + n8], x4x[2 * k8], x4x[2 * k8 + 1], acc);
          }
          gt++;
        }
        pred[tid] = acc;
        SYNC();
        if (tid < 256) q[tid] = pred[tid] + pred[tid + 256] + ca_bqkv[l * 768 + tid];
        SYNC();
      }
      // e. CA attention
      attn8(C6 + (size_t)(2 * l) * slab, C6 + (size_t)(2 * l + 1) * slab,
            ckvn + l * 512, ckvn + l * 512 + 256, pos);
      SYNC();
      // f. CAO: 4 tiles; x = att
      {
        float acc = 0.f;
        for (int t = 0; t < 4; t++) {
          tile_wait_issue(gt);
          const uint4* T = &lds_w[(gt % 3u) * TILE_U4];
#pragma unroll
          for (int rr = 0; rr < 4; rr++) {
            const int k8 = 8 * t + 4 * half + rr;
            acc = fma8u(T[(4 * half + rr) * 256 + n8], a4[2 * k8], a4[2 * k8 + 1], acc);
          }
          gt++;
        }
        pred[tid] = acc;
        SYNC();
        float v = (tid < 256) ? (x[tid] + pred[tid] + pred[tid + 256] + ca_bo[l * 256 + tid]) : 0.f;
        ln_store(v, ln2_w + l * 256, ln2_b + l * 256, x);
      }
      // g. FF1: 16 tiles (rows 2t,2t+1 of [32][1024]); cols tid, tid+512
      {
        float f0 = 0.f, f1 = 0.f;
        for (int t = 0; t < 16; t++) {
          tile_wait_issue(gt);
          const uint4* T = &lds_w[(gt % 3u) * TILE_U4];
          const float4 xa0 = x4x[4 * t],     xb0 = x4x[4 * t + 1];
          const float4 xa1 = x4x[4 * t + 2], xb1 = x4x[4 * t + 3];
          f0 = fma8u(T[tid],        xa0, xb0, f0);
          f0 = fma8u(T[1024 + tid], xa1, xb1, f0);
          f1 = fma8u(T[512 + tid],  xa0, xb0, f1);
          f1 = fma8u(T[1536 + tid], xa1, xb1, f1);
          gt++;
        }
        hbuf[tid]       = gelu_f(f0 + ff1_b[l * 1024 + tid]);
        hbuf[tid + 512] = gelu_f(f1 + ff1_b[l * 1024 + tid + 512]);
        SYNC();
      }
      // h. FF2: 16 tiles (rows 8t..8t+7 of [128][256]); x = hbuf
      {
        float acc = 0.f;
        for (int t = 0; t < 16; t++) {
          tile_wait_issue(gt);
          const uint4* T = &lds_w[(gt % 3u) * TILE_U4];
#pragma unroll
          for (int rr = 0; rr < 4; rr++) {
            const int k8 = 8 * t + 4 * half + rr;
            acc = fma8u(T[(4 * half + rr) * 256 + n8], h4[2 * k8], h4[2 * k8 + 1], acc);
          }
          gt++;
        }
        pred[tid] = acc;
        SYNC();
        float v = (tid < 256) ? (x[tid] + pred[tid] + pred[tid + 256] + ff2_b[l * 256 + tid]) : 0.f;
        ln_store(v, ln3_w + l * 256, ln3_b + l * 256, x);
      }
    }

    // readout
    {
      const int lane = tid & 63;
      if (tid < 128) {
        const int d0 = tid >> 6;
        float p = 0.f;
        for (int d = lane; d < DMODEL; d += 64) p += x[d] * out_W[d0 * DMODEL + d];
        p = wave_sum64(p);
        if (lane == 0) {
          const float nd = p + out_b[d0];
          ndc[d0] = nd;
          const float c = ndc[2 + d0] + nd;
          ndc[2 + d0] = c;
          out[((size_t)b * FUT_N + s) * 2 + d0] = c;
        }
      }
      SYNC();
    }
  }
  asm volatile("s_waitcnt vmcnt(0)" ::: "memory");  // drain before endpgm
}

// ======================= host launch =======================
extern "C" void kernel_launch(void* const* d_in, const int* in_sizes, int n_in,
                              void* d_out, int out_size, void* d_ws, size_t ws_size,
                              hipStream_t stream)
{
  const float* past    = (const float*)d_in[0];
  const float* in_W    = (const float*)d_in[1];
  const float* in_b    = (const float*)d_in[2];
  const float* pos_emb = (const float*)d_in[3];
  const float* ln0_w   = (const float*)d_in[4];
  const float* ln0_b   = (const float*)d_in[5];
  const float* sa_Wqkv = (const float*)d_in[6];
  const float* sa_bqkv = (const float*)d_in[7];
  const float* sa_Wo   = (const float*)d_in[8];
  const float* sa_bo   = (const float*)d_in[9];
  const float* ca_Wqkv = (const float*)d_in[10];
  const float* ca_bqkv = (const float*)d_in[11];
  const float* ca_Wo   = (const float*)d_in[12];
  const float* ca_bo   = (const float*)d_in[13];
  const float* ff1_W   = (const float*)d_in[14];
  const float* ff1_b   = (const float*)d_in[15];
  const float* ff2_W   = (const float*)d_in[16];
  const float* ff2_b   = (const float*)d_in[17];
  const float* ln1_w   = (const float*)d_in[18];
  const float* ln1_b   = (const float*)d_in[19];
  const float* ln2_w   = (const float*)d_in[20];
  const float* ln2_b   = (const float*)d_in[21];
  const float* ln3_w   = (const float*)d_in[22];
  const float* ln3_b   = (const float*)d_in[23];
  const float* out_W   = (const float*)d_in[24];
  const float* out_b   = (const float*)d_in[25];
  float* out = (float*)d_out;

  const size_t Mpre = (size_t)BATCH * PAST_N;              // 6400
  const size_t slab = (size_t)BATCH * S_TOT * DMODEL;      // 2,293,760

  float* ws_f = (float*)d_ws;
  float* A    = ws_f;
  float* Bb   = A + Mpre * DMODEL;
  float* qb   = Bb + Mpre * DMODEL;
  float* at   = qb + Mpre * DMODEL;
  float* hb   = at + Mpre * DMODEL;
  float* Wckv = hb + Mpre * FFD;
  float* bckv = Wckv + (size_t)1536 * 256;
  float* ndb  = bckv + 1536;
  float* cur  = ndb + 256;
  __hip_bfloat16* Ksa = (__hip_bfloat16*)(cur + 256);
  __hip_bfloat16* Vsa = Ksa + 3 * slab;
  __hip_bfloat16* C6  = Vsa + 3 * slab;
  uint4* Wd = (uint4*)hb;  // aliases hb: free after prefill, used only by decode

  const size_t need = ((size_t)(C6 + 6 * slab) - (size_t)d_ws);
  if (ws_size < need) return;

  auto layer = [&](int l, int M, int rpb, int pbase) {
    const float* Wqkv = sa_Wqkv + (size_t)l * 768 * 256;
    __hip_bfloat16* kcl = Ksa + (size_t)l * slab;
    __hip_bfloat16* vcl = Vsa + (size_t)l * slab;
    k_gemm<<<dim3(768 / BN, M / BM), 256, 0, stream>>>(
        A, Wqkv, sa_bqkv + l * 768, nullptr, nullptr, M, 768, 256, 0, 1,
        qb, kcl, vcl, nullptr, rpb, pbase);
    k_attn<<<M * HEADS, 64, 0, stream>>>(qb, kcl, vcl, at, rpb, pbase);
    k_gemm<<<dim3(256 / BN, M / BM), 256, 0, stream>>>(
        at, sa_Wo + (size_t)l * 65536, sa_bo + l * 256, A, Bb, M, 256, 256, 0, 0,
        nullptr, nullptr, nullptr, nullptr, 1, 0);
    k_ln<<<M, 256, 0, stream>>>(Bb, ln1_w + l * 256, ln1_b + l * 256, A);
    k_gemm<<<dim3(256 / BN, M / BM), 256, 0, stream>>>(
        A, ca_Wqkv + (size_t)l * 768 * 256, ca_bqkv + l * 768, nullptr, qb,
        M, 256, 256, 0, 0, nullptr, nullptr, nullptr, nullptr, 1, 0);
    k_attn<<<M * HEADS, 64, 0, stream>>>(
        qb, C6 + (size_t)(2 * l) * slab, C6 + (size_t)(2 * l + 1) * slab, at, rpb, pbase);
    k_gemm<<<dim3(256 / BN, M / BM), 256, 0, stream>>>(
        at, ca_Wo + (size_t)l * 65536, ca_bo + l * 256, A, Bb, M, 256, 256, 0, 0,
        nullptr, nullptr, nullptr, nullptr, 1, 0);
    k_ln<<<M, 256, 0, stream>>>(Bb, ln2_w + l * 256, ln2_b + l * 256, A);
    k_gemm<<<dim3(FFD / BN, M / BM), 256, 0, stream>>>(
        A, ff1_W + (size_t)l * FFD * 256, ff1_b + l * FFD, nullptr, hb,
        M, FFD, 256, 1, 0, nullptr, nullptr, nullptr, nullptr, 1, 0);
    k_gemm<<<dim3(256 / BN, M / BM), 256, 0, stream>>>(
        hb, ff2_W + (size_t)l * 256 * FFD, ff2_b + l * 256, A, Bb, M, 256, FFD, 0, 0,
        nullptr, nullptr, nullptr, nullptr, 1, 0);
    k_ln<<<M, 256, 0, stream>>>(Bb, ln3_w + l * 256, ln3_b + l * 256, A);
  };

  // ---- prefill over past 50 positions ----
  k_prepack<<<1536, 256, 0, stream>>>(ca_Wqkv, ca_bqkv, Wckv, bckv);
  k_embed<<<(int)Mpre, 256, 0, stream>>>(past, in_W, in_b, pos_emb, ln0_w, ln0_b, A);
  k_gemm<<<dim3(1536 / BN, (int)Mpre / BM), 256, 0, stream>>>(
      A, Wckv, bckv, nullptr, nullptr, (int)Mpre, 1536, 256, 0, 2,
      nullptr, nullptr, nullptr, C6, PAST_N, 0);
  for (int l = 0; l < LAYERS; l++) layer(l, (int)Mpre, PAST_N, 0);
  k_readout<<<BATCH, 64, 0, stream>>>(A, out_W, out_b, past, cur, ndb, out, PAST_N, 0, 1);

  // ---- pack decode weight stream (into hb scratch, free after prefill) ----
  k_pack_stream<<<(TOTAL_U4 + 255) / 256, 256, 0, stream>>>(
      sa_Wqkv, sa_Wo, ca_Wqkv, ca_Wo, ff1_W, ff2_W, Wd);

  // ---- fused 19-step decode: one WG per batch element ----
  k_decode<<<BATCH, NT, 0, stream>>>(
      Wd, bckv, in_W, in_b, pos_emb, ln0_w, ln0_b,
      sa_bqkv, sa_bo, ca_bqkv, ca_bo, ff1_b, ff2_b,
      ln1_w, ln1_b, ln2_w, ln2_b, ln3_w, ln3_b,
      out_W, out_b, Ksa, Vsa, C6, ndb, cur, out);
}

// Round 7
// 5334.127 us; speedup vs baseline: 3.0172x; 1.0922x over previous
//
#include <hip/hip_runtime.h>
#include <hip/hip_bf16.h>

#define DMODEL 256
#define S_TOT  70
#define BATCH  128
#define HEADS  8
#define DHEAD  32
#define PAST_N 50
#define FUT_N  20
#define LAYERS 3
#define FFD    1024

#define BM 32
#define BN 64
#define BK 16

#define NT 512
// ---- decode weight stream: 212 tiles of 2048 uint4 (32KB) per step, in
// exact consumption order: CKV(32) + per layer [QKV 16 | WO 4 | CAQ 4 |
// CAO 4 | FF1 16 | FF2 16]. Tiles with N<2048 row-pad (pad never read).
#define TILES_STEP 212
#define TILE_U4    2048
#define TOTAL_U4   (TILES_STEP * TILE_U4)

__device__ __forceinline__ float wave_sum64(float v) {
#pragma unroll
  for (int off = 32; off > 0; off >>= 1) v += __shfl_xor(v, off, 64);
  return v;
}
__device__ __forceinline__ float wave_max64(float v) {
#pragma unroll
  for (int off = 32; off > 0; off >>= 1) v = fmaxf(v, __shfl_xor(v, off, 64));
  return v;
}
__device__ __forceinline__ float gelu_f(float x) {
  return 0.5f * x * (1.0f + erff(x * 0.7071067811865476f));
}
__device__ __forceinline__ uint16_t f2bf(float v) {
  uint32_t b = __float_as_uint(v);
  return (uint16_t)((b + 0x7fffu + ((b >> 16) & 1u)) >> 16);
}
__device__ __forceinline__ float bl16(uint32_t w) { return __uint_as_float(w << 16); }
__device__ __forceinline__ float bh16(uint32_t w) { return __uint_as_float(w & 0xffff0000u); }

__device__ __forceinline__ float fma8u(uint4 W, float4 xa, float4 xb, float acc) {
  acc += bl16(W.x) * xa.x + bh16(W.x) * xa.y;
  acc += bl16(W.y) * xa.z + bh16(W.y) * xa.w;
  acc += bl16(W.z) * xb.x + bh16(W.z) * xb.y;
  acc += bl16(W.w) * xb.z + bh16(W.w) * xb.w;
  return acc;
}

// raw barrier + LDS fence (no vmcnt drain — preserves weight prefetch queue)
#define SYNC() do { __builtin_amdgcn_sched_barrier(0); \
  asm volatile("s_waitcnt lgkmcnt(0)" ::: "memory"); \
  __builtin_amdgcn_s_barrier(); \
  __builtin_amdgcn_sched_barrier(0); } while (0)
// full drain (step boundary hygiene)
#define SYNCV() do { __builtin_amdgcn_sched_barrier(0); \
  asm volatile("s_waitcnt vmcnt(0) lgkmcnt(0)" ::: "memory"); \
  __builtin_amdgcn_s_barrier(); \
  __builtin_amdgcn_sched_barrier(0); } while (0)

__device__ __forceinline__ void gld_lds16(const uint4* g, uint4* l) {
  __builtin_amdgcn_global_load_lds(
      (const __attribute__((address_space(1))) void*)g,
      (__attribute__((address_space(3))) void*)l, 16, 0, 0);
}

// block = 256 threads, one row of 256 elements (prefill LN)
__device__ __forceinline__ float ln_norm_256(float x, float g, float b, float* sbuf, int tid) {
  float s = wave_sum64(x);
  if ((tid & 63) == 0) sbuf[tid >> 6] = s;
  __syncthreads();
  float mean = (sbuf[0] + sbuf[1] + sbuf[2] + sbuf[3]) * (1.0f / 256.0f);
  __syncthreads();
  float d = x - mean;
  float vs = wave_sum64(d * d);
  if ((tid & 63) == 0) sbuf[tid >> 6] = vs;
  __syncthreads();
  float var = (sbuf[0] + sbuf[1] + sbuf[2] + sbuf[3]) * (1.0f / 256.0f);
  return d * rsqrtf(var + 1e-5f) * g + b;
}

// ======================= prefill kernels (unchanged) =======================
__global__ __launch_bounds__(256) void k_gemm(
    const float* __restrict__ A, const float* __restrict__ W,
    const float* __restrict__ bias, const float* __restrict__ Rres,
    float* __restrict__ C, int M, int N, int K, int act, int outmode,
    float* __restrict__ qout, __hip_bfloat16* __restrict__ kc,
    __hip_bfloat16* __restrict__ vc, __hip_bfloat16* __restrict__ c6,
    int rows_per_b, int pos_base)
{
  __shared__ float As[BK][BM + 2];
  __shared__ float Ws[BK][BN + 4];
  const int tid = threadIdx.x;
  const int bm0 = blockIdx.y * BM;
  const int bn0 = blockIdx.x * BN;
  const int r = tid >> 4, c = tid & 15;
  const int am = tid >> 3, ak = (tid & 7) << 1;
  const int wn = tid >> 2, wk = (tid & 3) << 2;
  const float* Aptr = A + (size_t)(bm0 + am) * K + ak;
  const float* Wptr = W + (size_t)(bn0 + wn) * K + wk;
  float acc[2][4] = {{0.f, 0.f, 0.f, 0.f}, {0.f, 0.f, 0.f, 0.f}};
  for (int k0 = 0; k0 < K; k0 += BK) {
    float2 av = *(const float2*)(Aptr + k0);
    float4 wv = *(const float4*)(Wptr + k0);
    As[ak][am] = av.x;  As[ak + 1][am] = av.y;
    Ws[wk][wn] = wv.x;  Ws[wk + 1][wn] = wv.y;
    Ws[wk + 2][wn] = wv.z;  Ws[wk + 3][wn] = wv.w;
    __syncthreads();
#pragma unroll
    for (int kk = 0; kk < BK; kk++) {
      const float2 a = *(const float2*)&As[kk][r << 1];
      const float4 w = *(const float4*)&Ws[kk][c << 2];
      acc[0][0] += a.x * w.x; acc[0][1] += a.x * w.y;
      acc[0][2] += a.x * w.z; acc[0][3] += a.x * w.w;
      acc[1][0] += a.y * w.x; acc[1][1] += a.y * w.y;
      acc[1][2] += a.y * w.z; acc[1][3] += a.y * w.w;
    }
    __syncthreads();
  }
#pragma unroll
  for (int i = 0; i < 2; i++) {
    const int row = bm0 + (r << 1) + i;
    const int b = row / rows_per_b;
    const int t = pos_base + row % rows_per_b;
#pragma unroll
    for (int j = 0; j < 4; j++) {
      const int n = bn0 + (c << 2) + j;
      float v = acc[i][j] + bias[n];
      if (Rres) v += Rres[(size_t)row * N + n];
      if (act) v = gelu_f(v);
      if (outmode == 0) {
        C[(size_t)row * N + n] = v;
      } else if (outmode == 1) {
        if (n < 256) qout[(size_t)row * DMODEL + n] = v;
        else if (n < 512) kc[((size_t)b * S_TOT + t) * DMODEL + (n - 256)] = __float2bfloat16(v);
        else vc[((size_t)b * S_TOT + t) * DMODEL + (n - 512)] = __float2bfloat16(v);
      } else {
        const int j6 = n >> 8;
        c6[(size_t)j6 * ((size_t)BATCH * S_TOT * DMODEL) +
           ((size_t)b * S_TOT + t) * DMODEL + (n & 255)] = __float2bfloat16(v);
      }
    }
  }
}

__global__ __launch_bounds__(64) void k_attn(
    const float* __restrict__ qbuf, const __hip_bfloat16* __restrict__ kc,
    const __hip_bfloat16* __restrict__ vc, float* __restrict__ outb,
    int rows_per_b, int pos_base)
{
  __shared__ float qs[DHEAD];
  __shared__ float ss[S_TOT];
  const int bid = blockIdx.x;
  const int h = bid & (HEADS - 1);
  const int row = bid >> 3;
  const int b = row / rows_per_b;
  const int t = pos_base + row % rows_per_b;
  const int nk = t + 1;
  const int lane = threadIdx.x;
  if (lane < DHEAD) qs[lane] = qbuf[(size_t)row * DMODEL + h * DHEAD + lane];
  __syncthreads();
  float mx = -1e30f;
  for (int k0 = lane; k0 < nk; k0 += 64) {
    const __hip_bfloat16* kp = kc + ((size_t)b * S_TOT + k0) * DMODEL + h * DHEAD;
    float s = 0.f;
#pragma unroll
    for (int i = 0; i < DHEAD; i++) s += qs[i] * __bfloat162float(kp[i]);
    s *= 0.17677669529663687f;
    ss[k0] = s;
    mx = fmaxf(mx, s);
  }
  mx = wave_max64(mx);
  float sum = 0.f;
  for (int k0 = lane; k0 < nk; k0 += 64) {
    float e = expf(ss[k0] - mx);
    ss[k0] = e;
    sum += e;
  }
  sum = wave_sum64(sum);
  __syncthreads();
  const float inv = 1.0f / sum;
  if (lane < DHEAD) {
    float o = 0.f;
    for (int k0 = 0; k0 < nk; k0++)
      o += ss[k0] * __bfloat162float(vc[((size_t)b * S_TOT + k0) * DMODEL + h * DHEAD + lane]);
    outb[(size_t)row * DMODEL + h * DHEAD + lane] = o * inv;
  }
}

__global__ __launch_bounds__(256) void k_ln(
    const float* __restrict__ Z, const float* __restrict__ g,
    const float* __restrict__ b, float* __restrict__ out)
{
  __shared__ float sbuf[4];
  const int row = blockIdx.x, tid = threadIdx.x;
  float x = Z[(size_t)row * DMODEL + tid];
  out[(size_t)row * DMODEL + tid] = ln_norm_256(x, g[tid], b[tid], sbuf, tid);
}

__global__ __launch_bounds__(256) void k_embed(
    const float* __restrict__ past, const float* __restrict__ in_W,
    const float* __restrict__ in_b, const float* __restrict__ pos_emb,
    const float* __restrict__ ln_w, const float* __restrict__ ln_b,
    float* __restrict__ Aout)
{
  __shared__ float sbuf[4];
  const int rowid = blockIdx.x;
  const int b = rowid / PAST_N, t = rowid % PAST_N;
  const int tid = threadIdx.x;
  float dx = 0.f, dy = 0.f;
  if (t > 0) {
    dx = past[((size_t)b * PAST_N + t) * 2 + 0] - past[((size_t)b * PAST_N + t - 1) * 2 + 0];
    dy = past[((size_t)b * PAST_N + t) * 2 + 1] - past[((size_t)b * PAST_N + t - 1) * 2 + 1];
  }
  float v = in_W[tid * 2 + 0] * dx + in_W[tid * 2 + 1] * dy + in_b[tid] +
            pos_emb[(size_t)t * DMODEL + tid];
  Aout[(size_t)rowid * DMODEL + tid] = ln_norm_256(v, ln_w[tid], ln_b[tid], sbuf, tid);
}

__global__ __launch_bounds__(256) void k_prepack(
    const float* __restrict__ caW, const float* __restrict__ cab,
    float* __restrict__ Wckv, float* __restrict__ bckv)
{
  const int n = blockIdx.x, tid = threadIdx.x;
  const int j = n >> 8, dcol = n & 255;
  const int l = j >> 1, kv = j & 1;
  const int srow = l * 768 + 256 + kv * 256 + dcol;
  Wckv[(size_t)n * 256 + tid] = caW[(size_t)srow * 256 + tid];
  if (tid == 0) bckv[n] = cab[l * 768 + 256 + kv * 256 + dcol];
}

__global__ __launch_bounds__(64) void k_readout(
    const float* __restrict__ X, const float* __restrict__ out_W,
    const float* __restrict__ out_b, const float* __restrict__ past,
    float* __restrict__ cur, float* __restrict__ ndb, float* __restrict__ out,
    int rows_per_b, int s, int init)
{
  const int b = blockIdx.x, lane = threadIdx.x;
  const int row = b * rows_per_b + rows_per_b - 1;
  float p0 = 0.f, p1 = 0.f;
  for (int d = lane; d < DMODEL; d += 64) {
    const float xv = X[(size_t)row * DMODEL + d];
    p0 += xv * out_W[d];
    p1 += xv * out_W[DMODEL + d];
  }
  p0 = wave_sum64(p0);
  p1 = wave_sum64(p1);
  if (lane == 0) {
    const float nd0 = p0 + out_b[0];
    const float nd1 = p1 + out_b[1];
    float c0, c1;
    if (init) {
      c0 = past[((size_t)b * PAST_N + PAST_N - 1) * 2 + 0];
      c1 = past[((size_t)b * PAST_N + PAST_N - 1) * 2 + 1];
    } else {
      c0 = cur[b * 2 + 0];
      c1 = cur[b * 2 + 1];
    }
    c0 += nd0; c1 += nd1;
    cur[b * 2 + 0] = c0; cur[b * 2 + 1] = c1;
    ndb[b * 2 + 0] = nd0; ndb[b * 2 + 1] = nd1;
    out[((size_t)b * FUT_N + s) * 2 + 0] = c0;
    out[((size_t)b * FUT_N + s) * 2 + 1] = c1;
  }
}

// ======================= decode stream pack (unchanged layout) =======================
__global__ __launch_bounds__(256) void k_pack_stream(
    const float* __restrict__ sa_Wqkv, const float* __restrict__ sa_Wo,
    const float* __restrict__ ca_Wqkv, const float* __restrict__ ca_Wo,
    const float* __restrict__ ff1_W, const float* __restrict__ ff2_W,
    uint4* __restrict__ Wd)
{
  const unsigned g = blockIdx.x * 256 + threadIdx.x;
  if (g >= TOTAL_U4) return;
  const unsigned tile = g >> 11, off = g & 2047u;
  const float* src = nullptr;
  if (tile < 32) {
    if (off < 1536) {
      const int k8 = tile, n = off;
      const int j = n >> 8, dcol = n & 255, l = j >> 1, kv = j & 1;
      src = ca_Wqkv + (size_t)l * 196608 + (size_t)(256 + kv * 256 + dcol) * 256 + 8 * k8;
    }
  } else {
    const unsigned r = tile - 32, l = r / 60, p = r % 60;
    if (p < 16) {
      if (off < 1536) {
        const int row = off / 768, n = off % 768, k8 = 2 * p + row;
        src = sa_Wqkv + (size_t)l * 196608 + (size_t)n * 256 + 8 * k8;
      }
    } else if (p < 20) {
      const int k8 = 8 * (p - 16) + (off >> 8), n = off & 255;
      src = sa_Wo + (size_t)l * 65536 + (size_t)n * 256 + 8 * k8;
    } else if (p < 24) {
      const int k8 = 8 * (p - 20) + (off >> 8), n = off & 255;
      src = ca_Wqkv + (size_t)l * 196608 + (size_t)n * 256 + 8 * k8;
    } else if (p < 28) {
      const int k8 = 8 * (p - 24) + (off >> 8), n = off & 255;
      src = ca_Wo + (size_t)l * 65536 + (size_t)n * 256 + 8 * k8;
    } else if (p < 44) {
      const int row = off >> 10, n = off & 1023, k8 = 2 * (p - 28) + row;
      src = ff1_W + (size_t)l * 262144 + (size_t)n * 256 + 8 * k8;
    } else {
      const int k8 = 8 * (p - 44) + (off >> 8), n = off & 255;
      src = ff2_W + (size_t)l * 262144 + (size_t)n * 1024 + 8 * k8;
    }
  }
  uint4 u = {0u, 0u, 0u, 0u};
  if (src) {
    u.x = ((uint32_t)f2bf(src[1]) << 16) | (uint32_t)f2bf(src[0]);
    u.y = ((uint32_t)f2bf(src[3]) << 16) | (uint32_t)f2bf(src[2]);
    u.z = ((uint32_t)f2bf(src[5]) << 16) | (uint32_t)f2bf(src[4]);
    u.w = ((uint32_t)f2bf(src[7]) << 16) | (uint32_t)f2bf(src[6]);
  }
  Wd[g] = u;
}

// ======================= fused 19-step decode =======================
// one WG (512 thr) per batch element; weights stream through a 4-slot 128KB
// LDS ring via global_load_lds; counted vmcnt(8) keeps 2-3 tiles in flight.
// All per-tid constants are preloaded to REGISTERS before the loop so no
// global scalar load inside the loop forces an in-order vmcnt drain.
__global__ __launch_bounds__(NT) void k_decode(
    const uint4* __restrict__ Wd, const float* __restrict__ bckv,
    const float* __restrict__ in_W, const float* __restrict__ in_b,
    const float* __restrict__ pos_emb,
    const float* __restrict__ ln0_w, const float* __restrict__ ln0_b,
    const float* __restrict__ sa_bqkv, const float* __restrict__ sa_bo,
    const float* __restrict__ ca_bqkv, const float* __restrict__ ca_bo,
    const float* __restrict__ ff1_b, const float* __restrict__ ff2_b,
    const float* __restrict__ ln1_w, const float* __restrict__ ln1_b,
    const float* __restrict__ ln2_w, const float* __restrict__ ln2_b,
    const float* __restrict__ ln3_w, const float* __restrict__ ln3_b,
    const float* __restrict__ out_W, const float* __restrict__ out_b,
    __hip_bfloat16* __restrict__ Ksa, __hip_bfloat16* __restrict__ Vsa,
    __hip_bfloat16* __restrict__ C6,
    const float* __restrict__ ndb, const float* __restrict__ cur,
    float* __restrict__ out)
{
  const int b = blockIdx.x;
  const int tid = threadIdx.x;
  const size_t slab = (size_t)BATCH * S_TOT * DMODEL;

  __shared__ __align__(16) uint4 lds_w[4 * TILE_U4];   // 128 KB
  __shared__ __align__(16) float x[256];
  __shared__ __align__(16) float xt[256];
  __shared__ __align__(16) float q[256];
  __shared__ __align__(16) float att[256];
  __shared__ __align__(16) float hbuf[1024];
  __shared__ float pred[NT];
  __shared__ float kn[256], vn[256];
  __shared__ __align__(16) float ckvn[1536];
  __shared__ float ss[8][72];
  __shared__ float sb[8], sb2[8];
  __shared__ float ndc[4];

  const float4* x4x = (const float4*)x;
  const float4* x4t = (const float4*)xt;
  const float4* a4  = (const float4*)att;
  const float4* h4  = (const float4*)hbuf;

  // ---- preload ALL per-tid constants into registers (one-time) ----
  const bool lo = tid < 256;
  const float c_bk0 = bckv[tid], c_bk1 = bckv[tid + 512], c_bk2 = bckv[tid + 1024];
  float c_inW0 = 0.f, c_inW1 = 0.f, c_inb = 0.f, c_l0w = 0.f, c_l0b = 0.f;
  if (lo) {
    c_inW0 = in_W[2 * tid]; c_inW1 = in_W[2 * tid + 1]; c_inb = in_b[tid];
    c_l0w = ln0_w[tid];     c_l0b = ln0_b[tid];
  }
  float bq0[LAYERS], bq1[LAYERS], bso[LAYERS], bcq[LAYERS], bco[LAYERS];
  float bf10[LAYERS], bf11[LAYERS], bf2[LAYERS];
  float w1[LAYERS], bb1[LAYERS], w2[LAYERS], bb2[LAYERS], w3[LAYERS], bb3[LAYERS];
#pragma unroll
  for (int l = 0; l < LAYERS; l++) {
    bq0[l] = sa_bqkv[l * 768 + tid];
    bq1[l] = lo ? sa_bqkv[l * 768 + 512 + tid] : 0.f;
    bso[l] = lo ? sa_bo[l * 256 + tid] : 0.f;
    bcq[l] = lo ? ca_bqkv[l * 768 + tid] : 0.f;
    bco[l] = lo ? ca_bo[l * 256 + tid] : 0.f;
    bf10[l] = ff1_b[l * 1024 + tid];
    bf11[l] = ff1_b[l * 1024 + 512 + tid];
    bf2[l] = lo ? ff2_b[l * 256 + tid] : 0.f;
    w1[l] = lo ? ln1_w[l * 256 + tid] : 0.f;  bb1[l] = lo ? ln1_b[l * 256 + tid] : 0.f;
    w2[l] = lo ? ln2_w[l * 256 + tid] : 0.f;  bb2[l] = lo ? ln2_b[l * 256 + tid] : 0.f;
    w3[l] = lo ? ln3_w[l * 256 + tid] : 0.f;  bb3[l] = lo ? ln3_b[l * 256 + tid] : 0.f;
  }
  float c_ow[4] = {0.f, 0.f, 0.f, 0.f};
  float c_ob = 0.f;
  if (tid < 128) {
    const int d0 = tid >> 6, ll = tid & 63;
#pragma unroll
    for (int j = 0; j < 4; j++) c_ow[j] = out_W[d0 * 256 + ll + 64 * j];
    c_ob = out_b[d0];
  }
  if (tid == 0) {
    ndc[0] = ndb[2 * b];     ndc[1] = ndb[2 * b + 1];
    ndc[2] = cur[2 * b];     ndc[3] = cur[2 * b + 1];
  }
  // flush const loads so the vmcnt queue holds only tile prefetches
  asm volatile("s_waitcnt vmcnt(0)" ::: "memory");

  auto issue_tile = [&](unsigned g) {
    const unsigned sidx = g % (unsigned)TILES_STEP;
    const unsigned slot = g & 3u;
    const uint4* src = Wd + (size_t)sidx * TILE_U4 + tid;
    uint4* dst = &lds_w[slot * TILE_U4 + tid];
#pragma unroll
    for (int j = 0; j < 4; j++) gld_lds16(src + j * 512, dst + j * 512);
  };
  // entering compute of tile g: wait for g (allow 2 tiles = 8 loads younger),
  // barrier (slot g-1's readers done), issue g+3 into that slot.
  auto tile_wait_issue = [&](unsigned g) {
    __builtin_amdgcn_sched_barrier(0);
    asm volatile("s_waitcnt vmcnt(8) lgkmcnt(0)" ::: "memory");
    __builtin_amdgcn_sched_barrier(0);
    __builtin_amdgcn_s_barrier();
    __builtin_amdgcn_sched_barrier(0);
    issue_tile(g + 3);
    __builtin_amdgcn_sched_barrier(0);
  };

  auto ln_store = [&](float v, float gw, float gb, float* dst) {
    float vv = lo ? v : 0.f;
    float s  = wave_sum64(vv);
    float s2 = wave_sum64(vv * vv);
    if ((tid & 63) == 0) { sb[tid >> 6] = s; sb2[tid >> 6] = s2; }
    SYNC();
    float mean = (sb[0] + sb[1] + sb[2] + sb[3]) * (1.0f / 256.0f);
    float ex2  = (sb2[0] + sb2[1] + sb2[2] + sb2[3]) * (1.0f / 256.0f);
    float var = ex2 - mean * mean;
    if (lo) dst[tid] = (vv - mean) * rsqrtf(var + 1e-5f) * gw + gb;
    SYNC();
  };

  auto attn8 = [&](const __hip_bfloat16* Kc, const __hip_bfloat16* Vc,
                   const float* knw, const float* vnw, int pos) {
    const int h = tid >> 6, lane = tid & 63;
    const float* qh = q + h * 32;
    float mx = -1e30f;
    for (int k0 = lane; k0 <= pos; k0 += 64) {
      float s = 0.f;
      if (k0 == pos) {
        const float* kp = knw + h * 32;
#pragma unroll
        for (int i = 0; i < 32; i++) s += qh[i] * kp[i];
      } else {
        const uint32_t* kp = (const uint32_t*)(Kc + ((size_t)b * S_TOT + k0) * DMODEL + h * 32);
#pragma unroll
        for (int i = 0; i < 16; i++) {
          uint32_t w = kp[i];
          s += bl16(w) * qh[2 * i];
          s += bh16(w) * qh[2 * i + 1];
        }
      }
      s *= 0.17677669529663687f;
      ss[h][k0] = s;
      mx = fmaxf(mx, s);
    }
    mx = wave_max64(mx);
    float sum = 0.f;
    for (int k0 = lane; k0 <= pos; k0 += 64) {
      float e = __expf(ss[h][k0] - mx);
      ss[h][k0] = e;
      sum += e;
    }
    sum = wave_sum64(sum);
    const float inv = 1.0f / sum;
    // V-pass: all 64 lanes; half kpar handles keys kpar, kpar+2, ...
    const int kpar = lane >> 5, d = lane & 31;
    const __hip_bfloat16* vbase = Vc + (size_t)b * S_TOT * DMODEL + h * 32 + d;
    float oA = 0.f, oB = 0.f;
    int k0 = kpar;
    for (; k0 + 2 < pos; k0 += 4) {
      oA += ss[h][k0]     * __bfloat162float(vbase[(size_t)k0 * DMODEL]);
      oB += ss[h][k0 + 2] * __bfloat162float(vbase[(size_t)(k0 + 2) * DMODEL]);
    }
    for (; k0 < pos; k0 += 2)
      oA += ss[h][k0] * __bfloat162float(vbase[(size_t)k0 * DMODEL]);
    float o = oA + oB;
    o += __shfl_xor(o, 32, 64);
    if (lane < 32) {
      o += ss[h][pos] * vnw[h * 32 + lane];
      att[h * 32 + lane] = o * inv;
    }
  };

  const int n8 = tid & 255, half = tid >> 8;
  unsigned gt = 0;
  issue_tile(0);
  issue_tile(1);
  issue_tile(2);

  for (int s = 1; s < FUT_N; s++) {
    const int pos = PAST_N - 1 + s;
    SYNCV();  // step-boundary drain (cache-store -> next-step read visibility)

    // 1. token embed + LN0 -> xt ; copy to x  (pos_emb: 1 global row/step)
    float xe = 0.f;
    if (lo) {
      xe = c_inW0 * ndc[0] + c_inW1 * ndc[1] + c_inb + pos_emb[(size_t)pos * DMODEL + tid];
    }
    ln_store(xe, c_l0w, c_l0b, xt);
    if (lo) x[tid] = xt[tid];

    // 2. CKV: 32 tiles, cols tid, tid+512, tid+1024, x = xt
    {
      float a0 = 0.f, a1 = 0.f, a2 = 0.f;
      for (int t = 0; t < 32; t++) {
        tile_wait_issue(gt);
        const uint4* T = &lds_w[(gt & 3u) * TILE_U4];
        const float4 xa = x4t[2 * t], xb = x4t[2 * t + 1];
        a0 = fma8u(T[tid],        xa, xb, a0);
        a1 = fma8u(T[tid + 512],  xa, xb, a1);
        a2 = fma8u(T[tid + 1024], xa, xb, a2);
        gt++;
      }
      float v0 = a0 + c_bk0;
      float v1 = a1 + c_bk1;
      float v2 = a2 + c_bk2;
      ckvn[tid] = v0; ckvn[tid + 512] = v1; ckvn[tid + 1024] = v2;
      {
        int n = tid;
        C6[(size_t)(n >> 8) * slab + ((size_t)b * S_TOT + pos) * DMODEL + (n & 255)] = __float2bfloat16(v0);
        n = tid + 512;
        C6[(size_t)(n >> 8) * slab + ((size_t)b * S_TOT + pos) * DMODEL + (n & 255)] = __float2bfloat16(v1);
        n = tid + 1024;
        C6[(size_t)(n >> 8) * slab + ((size_t)b * S_TOT + pos) * DMODEL + (n & 255)] = __float2bfloat16(v2);
      }
      SYNC();
    }

#pragma unroll
    for (int l = 0; l < LAYERS; l++) {
      // a. QKV: 16 tiles (rows 2t,2t+1 of [32][768]); x source = x
      {
        float q0 = 0.f, q1 = 0.f;
        for (int t = 0; t < 16; t++) {
          tile_wait_issue(gt);
          const uint4* T = &lds_w[(gt & 3u) * TILE_U4];
          const float4 xa0 = x4x[4 * t],     xb0 = x4x[4 * t + 1];
          const float4 xa1 = x4x[4 * t + 2], xb1 = x4x[4 * t + 3];
          q0 = fma8u(T[tid],       xa0, xb0, q0);
          q0 = fma8u(T[768 + tid], xa1, xb1, q0);
          if (lo) {
            q1 = fma8u(T[512 + tid],  xa0, xb0, q1);
            q1 = fma8u(T[1280 + tid], xa1, xb1, q1);
          }
          gt++;
        }
        {
          const int n = tid;
          float v = q0 + bq0[l];
          if (n < 256) q[n] = v;
          else {
            kn[n - 256] = v;
            Ksa[(size_t)l * slab + ((size_t)b * S_TOT + pos) * DMODEL + (n - 256)] = __float2bfloat16(v);
          }
        }
        if (lo) {
          const int n = tid + 512;
          float v = q1 + bq1[l];
          vn[n - 512] = v;
          Vsa[(size_t)l * slab + ((size_t)b * S_TOT + pos) * DMODEL + (n - 512)] = __float2bfloat16(v);
        }
        SYNC();
      }
      // b. SA attention
      attn8(Ksa + (size_t)l * slab, Vsa + (size_t)l * slab, kn, vn, pos);
      SYNC();
      // c. WO: 4 tiles; split-K by half; x = att
      {
        float acc = 0.f;
        for (int t = 0; t < 4; t++) {
          tile_wait_issue(gt);
          const uint4* T = &lds_w[(gt & 3u) * TILE_U4];
#pragma unroll
          for (int rr = 0; rr < 4; rr++) {
            const int k8 = 8 * t + 4 * half + rr;
            acc = fma8u(T[(4 * half + rr) * 256 + n8], a4[2 * k8], a4[2 * k8 + 1], acc);
          }
          gt++;
        }
        pred[tid] = acc;
        SYNC();
        float v = lo ? (x[tid] + pred[tid] + pred[tid + 256] + bso[l]) : 0.f;
        ln_store(v, w1[l], bb1[l], x);
      }
      // d. CAQ: 4 tiles; x source = x
      {
        float acc = 0.f;
        for (int t = 0; t < 4; t++) {
          tile_wait_issue(gt);
          const uint4* T = &lds_w[(gt & 3u) * TILE_U4];
#pragma unroll
          for (int rr = 0; rr < 4; rr++) {
            const int k8 = 8 * t + 4 * half + rr;
            acc = fma8u(T[(4 * half + rr) * 256 + n8], x4x[2 * k8], x4x[2 * k8 + 1], acc);
          }
          gt++;
        }
        pred[tid] = acc;
        SYNC();
        if (lo) q[tid] = pred[tid] + pred[tid + 256] + bcq[l];
        SYNC();
      }
      // e. CA attention
      attn8(C6 + (size_t)(2 * l) * slab, C6 + (size_t)(2 * l + 1) * slab,
            ckvn + l * 512, ckvn + l * 512 + 256, pos);
      SYNC();
      // f. CAO: 4 tiles; x = att
      {
        float acc = 0.f;
        for (int t = 0; t < 4; t++) {
          tile_wait_issue(gt);
          const uint4* T = &lds_w[(gt & 3u) * TILE_U4];
#pragma unroll
          for (int rr = 0; rr < 4; rr++) {
            const int k8 = 8 * t + 4 * half + rr;
            acc = fma8u(T[(4 * half + rr) * 256 + n8], a4[2 * k8], a4[2 * k8 + 1], acc);
          }
          gt++;
        }
        pred[tid] = acc;
        SYNC();
        float v = lo ? (x[tid] + pred[tid] + pred[tid + 256] + bco[l]) : 0.f;
        ln_store(v, w2[l], bb2[l], x);
      }
      // g. FF1: 16 tiles; cols tid, tid+512
      {
        float f0 = 0.f, f1 = 0.f;
        for (int t = 0; t < 16; t++) {
          tile_wait_issue(gt);
          const uint4* T = &lds_w[(gt & 3u) * TILE_U4];
          const float4 xa0 = x4x[4 * t],     xb0 = x4x[4 * t + 1];
          const float4 xa1 = x4x[4 * t + 2], xb1 = x4x[4 * t + 3];
          f0 = fma8u(T[tid],        xa0, xb0, f0);
          f0 = fma8u(T[1024 + tid], xa1, xb1, f0);
          f1 = fma8u(T[512 + tid],  xa0, xb0, f1);
          f1 = fma8u(T[1536 + tid], xa1, xb1, f1);
          gt++;
        }
        hbuf[tid]       = gelu_f(f0 + bf10[l]);
        hbuf[tid + 512] = gelu_f(f1 + bf11[l]);
        SYNC();
      }
      // h. FF2: 16 tiles; split-K by half; x = hbuf
      {
        float acc = 0.f;
        for (int t = 0; t < 16; t++) {
          tile_wait_issue(gt);
          const uint4* T = &lds_w[(gt & 3u) * TILE_U4];
#pragma unroll
          for (int rr = 0; rr < 4; rr++) {
            const int k8 = 8 * t + 4 * half + rr;
            acc = fma8u(T[(4 * half + rr) * 256 + n8], h4[2 * k8], h4[2 * k8 + 1], acc);
          }
          gt++;
        }
        pred[tid] = acc;
        SYNC();
        float v = lo ? (x[tid] + pred[tid] + pred[tid + 256] + bf2[l]) : 0.f;
        ln_store(v, w3[l], bb3[l], x);
      }
    }

    // readout (register out_W)
    {
      const int lane = tid & 63;
      if (tid < 128) {
        const int d0 = tid >> 6;
        float p = 0.f;
#pragma unroll
        for (int j = 0; j < 4; j++) p += x[lane + 64 * j] * c_ow[j];
        p = wave_sum64(p);
        if (lane == 0) {
          const float nd = p + c_ob;
          ndc[d0] = nd;
          const float c = ndc[2 + d0] + nd;
          ndc[2 + d0] = c;
          out[((size_t)b * FUT_N + s) * 2 + d0] = c;
        }
      }
      SYNC();
    }
  }
  asm volatile("s_waitcnt vmcnt(0)" ::: "memory");  // drain before endpgm
}

// ======================= host launch =======================
extern "C" void kernel_launch(void* const* d_in, const int* in_sizes, int n_in,
                              void* d_out, int out_size, void* d_ws, size_t ws_size,
                              hipStream_t stream)
{
  const float* past    = (const float*)d_in[0];
  const float* in_W    = (const float*)d_in[1];
  const float* in_b    = (const float*)d_in[2];
  const float* pos_emb = (const float*)d_in[3];
  const float* ln0_w   = (const float*)d_in[4];
  const float* ln0_b   = (const float*)d_in[5];
  const float* sa_Wqkv = (const float*)d_in[6];
  const float* sa_bqkv = (const float*)d_in[7];
  const float* sa_Wo   = (const float*)d_in[8];
  const float* sa_bo   = (const float*)d_in[9];
  const float* ca_Wqkv = (const float*)d_in[10];
  const float* ca_bqkv = (const float*)d_in[11];
  const float* ca_Wo   = (const float*)d_in[12];
  const float* ca_bo   = (const float*)d_in[13];
  const float* ff1_W   = (const float*)d_in[14];
  const float* ff1_b   = (const float*)d_in[15];
  const float* ff2_W   = (const float*)d_in[16];
  const float* ff2_b   = (const float*)d_in[17];
  const float* ln1_w   = (const float*)d_in[18];
  const float* ln1_b   = (const float*)d_in[19];
  const float* ln2_w   = (const float*)d_in[20];
  const float* ln2_b   = (const float*)d_in[21];
  const float* ln3_w   = (const float*)d_in[22];
  const float* ln3_b   = (const float*)d_in[23];
  const float* out_W   = (const float*)d_in[24];
  const float* out_b   = (const float*)d_in[25];
  float* out = (float*)d_out;

  const size_t Mpre = (size_t)BATCH * PAST_N;              // 6400
  const size_t slab = (size_t)BATCH * S_TOT * DMODEL;      // 2,293,760

  float* ws_f = (float*)d_ws;
  float* A    = ws_f;
  float* Bb   = A + Mpre * DMODEL;
  float* qb   = Bb + Mpre * DMODEL;
  float* at   = qb + Mpre * DMODEL;
  float* hb   = at + Mpre * DMODEL;
  float* Wckv = hb + Mpre * FFD;
  float* bckv = Wckv + (size_t)1536 * 256;
  float* ndb  = bckv + 1536;
  float* cur  = ndb + 256;
  __hip_bfloat16* Ksa = (__hip_bfloat16*)(cur + 256);
  __hip_bfloat16* Vsa = Ksa + 3 * slab;
  __hip_bfloat16* C6  = Vsa + 3 * slab;
  uint4* Wd = (uint4*)hb;  // aliases hb: free after prefill, used only by decode

  const size_t need = ((size_t)(C6 + 6 * slab) - (size_t)d_ws);
  if (ws_size < need) return;

  auto layer = [&](int l, int M, int rpb, int pbase) {
    const float* Wqkv = sa_Wqkv + (size_t)l * 768 * 256;
    __hip_bfloat16* kcl = Ksa + (size_t)l * slab;
    __hip_bfloat16* vcl = Vsa + (size_t)l * slab;
    k_gemm<<<dim3(768 / BN, M / BM), 256, 0, stream>>>(
        A, Wqkv, sa_bqkv + l * 768, nullptr, nullptr, M, 768, 256, 0, 1,
        qb, kcl, vcl, nullptr, rpb, pbase);
    k_attn<<<M * HEADS, 64, 0, stream>>>(qb, kcl, vcl, at, rpb, pbase);
    k_gemm<<<dim3(256 / BN, M / BM), 256, 0, stream>>>(
        at, sa_Wo + (size_t)l * 65536, sa_bo + l * 256, A, Bb, M, 256, 256, 0, 0,
        nullptr, nullptr, nullptr, nullptr, 1, 0);
    k_ln<<<M, 256, 0, stream>>>(Bb, ln1_w + l * 256, ln1_b + l * 256, A);
    k_gemm<<<dim3(256 / BN, M / BM), 256, 0, stream>>>(
        A, ca_Wqkv + (size_t)l * 768 * 256, ca_bqkv + l * 768, nullptr, qb,
        M, 256, 256, 0, 0, nullptr, nullptr, nullptr, nullptr, 1, 0);
    k_attn<<<M * HEADS, 64, 0, stream>>>(
        qb, C6 + (size_t)(2 * l) * slab, C6 + (size_t)(2 * l + 1) * slab, at, rpb, pbase);
    k_gemm<<<dim3(256 / BN, M / BM), 256, 0, stream>>>(
        at, ca_Wo + (size_t)l * 65536, ca_bo + l * 256, A, Bb, M, 256, 256, 0, 0,
        nullptr, nullptr, nullptr, nullptr, 1, 0);
    k_ln<<<M, 256, 0, stream>>>(Bb, ln2_w + l * 256, ln2_b + l * 256, A);
    k_gemm<<<dim3(FFD / BN, M / BM), 256, 0, stream>>>(
        A, ff1_W + (size_t)l * FFD * 256, ff1_b + l * FFD, nullptr, hb,
        M, FFD, 256, 1, 0, nullptr, nullptr, nullptr, nullptr, 1, 0);
    k_gemm<<<dim3(256 / BN, M / BM), 256, 0, stream>>>(
        hb, ff2_W + (size_t)l * 256 * FFD, ff2_b + l * 256, A, Bb, M, 256, FFD, 0, 0,
        nullptr, nullptr, nullptr, nullptr, 1, 0);
    k_ln<<<M, 256, 0, stream>>>(Bb, ln3_w + l * 256, ln3_b + l * 256, A);
  };

  // ---- prefill over past 50 positions ----
  k_prepack<<<1536, 256, 0, stream>>>(ca_Wqkv, ca_bqkv, Wckv, bckv);
  k_embed<<<(int)Mpre, 256, 0, stream>>>(past, in_W, in_b, pos_emb, ln0_w, ln0_b, A);
  k_gemm<<<dim3(1536 / BN, (int)Mpre / BM), 256, 0, stream>>>(
      A, Wckv, bckv, nullptr, nullptr, (int)Mpre, 1536, 256, 0, 2,
      nullptr, nullptr, nullptr, C6, PAST_N, 0);
  for (int l = 0; l < LAYERS; l++) layer(l, (int)Mpre, PAST_N, 0);
  k_readout<<<BATCH, 64, 0, stream>>>(A, out_W, out_b, past, cur, ndb, out, PAST_N, 0, 1);

  // ---- pack decode weight stream (into hb scratch, free after prefill) ----
  k_pack_stream<<<(TOTAL_U4 + 255) / 256, 256, 0, stream>>>(
      sa_Wqkv, sa_Wo, ca_Wqkv, ca_Wo, ff1_W, ff2_W, Wd);

  // ---- fused 19-step decode: one WG per batch element ----
  k_decode<<<BATCH, NT, 0, stream>>>(
      Wd, bckv, in_W, in_b, pos_emb, ln0_w, ln0_b,
      sa_bqkv, sa_bo, ca_bqkv, ca_bo, ff1_b, ff2_b,
      ln1_w, ln1_b, ln2_w, ln2_b, ln3_w, ln3_b,
      out_W, out_b, Ksa, Vsa, C6, ndb, cur, out);
}

// Round 8
// 5329.516 us; speedup vs baseline: 3.0198x; 1.0009x over previous
//
#include <hip/hip_runtime.h>
#include <hip/hip_bf16.h>

#define DMODEL 256
#define S_TOT  70
#define BATCH  128
#define HEADS  8
#define DHEAD  32
#define PAST_N 50
#define FUT_N  20
#define LAYERS 3
#define FFD    1024

#define BM 32
#define BN 64
#define BK 16

#define NT 512
// ---- decode weight stream: 212 tiles of 2048 uint4 (32KB) per step, in
// exact consumption order: CKV(32) + per layer [QKV 16 | WO 4 | CAQ 4 |
// CAO 4 | FF1 16 | FF2 16]. Tiles with N<2048 row-pad (pad never read).
// 4 replicas to cut same-address requester congestion (WG reads copy b&3).
#define TILES_STEP 212
#define TILE_U4    2048
#define TOTAL_U4   (TILES_STEP * TILE_U4)
#define NCOPY      4

__device__ __forceinline__ float wave_sum64(float v) {
#pragma unroll
  for (int off = 32; off > 0; off >>= 1) v += __shfl_xor(v, off, 64);
  return v;
}
__device__ __forceinline__ float wave_max64(float v) {
#pragma unroll
  for (int off = 32; off > 0; off >>= 1) v = fmaxf(v, __shfl_xor(v, off, 64));
  return v;
}
__device__ __forceinline__ float gelu_f(float x) {
  return 0.5f * x * (1.0f + erff(x * 0.7071067811865476f));
}
__device__ __forceinline__ uint16_t f2bf(float v) {
  uint32_t b = __float_as_uint(v);
  return (uint16_t)((b + 0x7fffu + ((b >> 16) & 1u)) >> 16);
}
__device__ __forceinline__ float bl16(uint32_t w) { return __uint_as_float(w << 16); }
__device__ __forceinline__ float bh16(uint32_t w) { return __uint_as_float(w & 0xffff0000u); }

__device__ __forceinline__ float fma8u(uint4 W, float4 xa, float4 xb, float acc) {
  acc += bl16(W.x) * xa.x + bh16(W.x) * xa.y;
  acc += bl16(W.y) * xa.z + bh16(W.y) * xa.w;
  acc += bl16(W.z) * xb.x + bh16(W.z) * xb.y;
  acc += bl16(W.w) * xb.z + bh16(W.w) * xb.w;
  return acc;
}
__device__ __forceinline__ float dot8q(uint4 W, const float* qq) {
  return bl16(W.x) * qq[0] + bh16(W.x) * qq[1] +
         bl16(W.y) * qq[2] + bh16(W.y) * qq[3] +
         bl16(W.z) * qq[4] + bh16(W.z) * qq[5] +
         bl16(W.w) * qq[6] + bh16(W.w) * qq[7];
}

// raw barrier + LDS fence (no vmcnt drain — preserves weight prefetch queue)
#define SYNC() do { __builtin_amdgcn_sched_barrier(0); \
  asm volatile("s_waitcnt lgkmcnt(0)" ::: "memory"); \
  __builtin_amdgcn_s_barrier(); \
  __builtin_amdgcn_sched_barrier(0); } while (0)
// full drain (step boundary hygiene)
#define SYNCV() do { __builtin_amdgcn_sched_barrier(0); \
  asm volatile("s_waitcnt vmcnt(0) lgkmcnt(0)" ::: "memory"); \
  __builtin_amdgcn_s_barrier(); \
  __builtin_amdgcn_sched_barrier(0); } while (0)

__device__ __forceinline__ void gld_lds16(const uint4* g, uint4* l) {
  __builtin_amdgcn_global_load_lds(
      (const __attribute__((address_space(1))) void*)g,
      (__attribute__((address_space(3))) void*)l, 16, 0, 0);
}

// block = 256 threads, one row of 256 elements (prefill LN)
__device__ __forceinline__ float ln_norm_256(float x, float g, float b, float* sbuf, int tid) {
  float s = wave_sum64(x);
  if ((tid & 63) == 0) sbuf[tid >> 6] = s;
  __syncthreads();
  float mean = (sbuf[0] + sbuf[1] + sbuf[2] + sbuf[3]) * (1.0f / 256.0f);
  __syncthreads();
  float d = x - mean;
  float vs = wave_sum64(d * d);
  if ((tid & 63) == 0) sbuf[tid >> 6] = vs;
  __syncthreads();
  float var = (sbuf[0] + sbuf[1] + sbuf[2] + sbuf[3]) * (1.0f / 256.0f);
  return d * rsqrtf(var + 1e-5f) * g + b;
}

// ======================= prefill kernels (unchanged) =======================
__global__ __launch_bounds__(256) void k_gemm(
    const float* __restrict__ A, const float* __restrict__ W,
    const float* __restrict__ bias, const float* __restrict__ Rres,
    float* __restrict__ C, int M, int N, int K, int act, int outmode,
    float* __restrict__ qout, __hip_bfloat16* __restrict__ kc,
    __hip_bfloat16* __restrict__ vc, __hip_bfloat16* __restrict__ c6,
    int rows_per_b, int pos_base)
{
  __shared__ float As[BK][BM + 2];
  __shared__ float Ws[BK][BN + 4];
  const int tid = threadIdx.x;
  const int bm0 = blockIdx.y * BM;
  const int bn0 = blockIdx.x * BN;
  const int r = tid >> 4, c = tid & 15;
  const int am = tid >> 3, ak = (tid & 7) << 1;
  const int wn = tid >> 2, wk = (tid & 3) << 2;
  const float* Aptr = A + (size_t)(bm0 + am) * K + ak;
  const float* Wptr = W + (size_t)(bn0 + wn) * K + wk;
  float acc[2][4] = {{0.f, 0.f, 0.f, 0.f}, {0.f, 0.f, 0.f, 0.f}};
  for (int k0 = 0; k0 < K; k0 += BK) {
    float2 av = *(const float2*)(Aptr + k0);
    float4 wv = *(const float4*)(Wptr + k0);
    As[ak][am] = av.x;  As[ak + 1][am] = av.y;
    Ws[wk][wn] = wv.x;  Ws[wk + 1][wn] = wv.y;
    Ws[wk + 2][wn] = wv.z;  Ws[wk + 3][wn] = wv.w;
    __syncthreads();
#pragma unroll
    for (int kk = 0; kk < BK; kk++) {
      const float2 a = *(const float2*)&As[kk][r << 1];
      const float4 w = *(const float4*)&Ws[kk][c << 2];
      acc[0][0] += a.x * w.x; acc[0][1] += a.x * w.y;
      acc[0][2] += a.x * w.z; acc[0][3] += a.x * w.w;
      acc[1][0] += a.y * w.x; acc[1][1] += a.y * w.y;
      acc[1][2] += a.y * w.z; acc[1][3] += a.y * w.w;
    }
    __syncthreads();
  }
#pragma unroll
  for (int i = 0; i < 2; i++) {
    const int row = bm0 + (r << 1) + i;
    const int b = row / rows_per_b;
    const int t = pos_base + row % rows_per_b;
#pragma unroll
    for (int j = 0; j < 4; j++) {
      const int n = bn0 + (c << 2) + j;
      float v = acc[i][j] + bias[n];
      if (Rres) v += Rres[(size_t)row * N + n];
      if (act) v = gelu_f(v);
      if (outmode == 0) {
        C[(size_t)row * N + n] = v;
      } else if (outmode == 1) {
        if (n < 256) qout[(size_t)row * DMODEL + n] = v;
        else if (n < 512) kc[((size_t)b * S_TOT + t) * DMODEL + (n - 256)] = __float2bfloat16(v);
        else vc[((size_t)b * S_TOT + t) * DMODEL + (n - 512)] = __float2bfloat16(v);
      } else {
        const int j6 = n >> 8;
        c6[(size_t)j6 * ((size_t)BATCH * S_TOT * DMODEL) +
           ((size_t)b * S_TOT + t) * DMODEL + (n & 255)] = __float2bfloat16(v);
      }
    }
  }
}

__global__ __launch_bounds__(64) void k_attn(
    const float* __restrict__ qbuf, const __hip_bfloat16* __restrict__ kc,
    const __hip_bfloat16* __restrict__ vc, float* __restrict__ outb,
    int rows_per_b, int pos_base)
{
  __shared__ float qs[DHEAD];
  __shared__ float ss[S_TOT];
  const int bid = blockIdx.x;
  const int h = bid & (HEADS - 1);
  const int row = bid >> 3;
  const int b = row / rows_per_b;
  const int t = pos_base + row % rows_per_b;
  const int nk = t + 1;
  const int lane = threadIdx.x;
  if (lane < DHEAD) qs[lane] = qbuf[(size_t)row * DMODEL + h * DHEAD + lane];
  __syncthreads();
  float mx = -1e30f;
  for (int k0 = lane; k0 < nk; k0 += 64) {
    const __hip_bfloat16* kp = kc + ((size_t)b * S_TOT + k0) * DMODEL + h * DHEAD;
    float s = 0.f;
#pragma unroll
    for (int i = 0; i < DHEAD; i++) s += qs[i] * __bfloat162float(kp[i]);
    s *= 0.17677669529663687f;
    ss[k0] = s;
    mx = fmaxf(mx, s);
  }
  mx = wave_max64(mx);
  float sum = 0.f;
  for (int k0 = lane; k0 < nk; k0 += 64) {
    float e = expf(ss[k0] - mx);
    ss[k0] = e;
    sum += e;
  }
  sum = wave_sum64(sum);
  __syncthreads();
  const float inv = 1.0f / sum;
  if (lane < DHEAD) {
    float o = 0.f;
    for (int k0 = 0; k0 < nk; k0++)
      o += ss[k0] * __bfloat162float(vc[((size_t)b * S_TOT + k0) * DMODEL + h * DHEAD + lane]);
    outb[(size_t)row * DMODEL + h * DHEAD + lane] = o * inv;
  }
}

__global__ __launch_bounds__(256) void k_ln(
    const float* __restrict__ Z, const float* __restrict__ g,
    const float* __restrict__ b, float* __restrict__ out)
{
  __shared__ float sbuf[4];
  const int row = blockIdx.x, tid = threadIdx.x;
  float x = Z[(size_t)row * DMODEL + tid];
  out[(size_t)row * DMODEL + tid] = ln_norm_256(x, g[tid], b[tid], sbuf, tid);
}

__global__ __launch_bounds__(256) void k_embed(
    const float* __restrict__ past, const float* __restrict__ in_W,
    const float* __restrict__ in_b, const float* __restrict__ pos_emb,
    const float* __restrict__ ln_w, const float* __restrict__ ln_b,
    float* __restrict__ Aout)
{
  __shared__ float sbuf[4];
  const int rowid = blockIdx.x;
  const int b = rowid / PAST_N, t = rowid % PAST_N;
  const int tid = threadIdx.x;
  float dx = 0.f, dy = 0.f;
  if (t > 0) {
    dx = past[((size_t)b * PAST_N + t) * 2 + 0] - past[((size_t)b * PAST_N + t - 1) * 2 + 0];
    dy = past[((size_t)b * PAST_N + t) * 2 + 1] - past[((size_t)b * PAST_N + t - 1) * 2 + 1];
  }
  float v = in_W[tid * 2 + 0] * dx + in_W[tid * 2 + 1] * dy + in_b[tid] +
            pos_emb[(size_t)t * DMODEL + tid];
  Aout[(size_t)rowid * DMODEL + tid] = ln_norm_256(v, ln_w[tid], ln_b[tid], sbuf, tid);
}

__global__ __launch_bounds__(256) void k_prepack(
    const float* __restrict__ caW, const float* __restrict__ cab,
    float* __restrict__ Wckv, float* __restrict__ bckv)
{
  const int n = blockIdx.x, tid = threadIdx.x;
  const int j = n >> 8, dcol = n & 255;
  const int l = j >> 1, kv = j & 1;
  const int srow = l * 768 + 256 + kv * 256 + dcol;
  Wckv[(size_t)n * 256 + tid] = caW[(size_t)srow * 256 + tid];
  if (tid == 0) bckv[n] = cab[l * 768 + 256 + kv * 256 + dcol];
}

__global__ __launch_bounds__(64) void k_readout(
    const float* __restrict__ X, const float* __restrict__ out_W,
    const float* __restrict__ out_b, const float* __restrict__ past,
    float* __restrict__ cur, float* __restrict__ ndb, float* __restrict__ out,
    int rows_per_b, int s, int init)
{
  const int b = blockIdx.x, lane = threadIdx.x;
  const int row = b * rows_per_b + rows_per_b - 1;
  float p0 = 0.f, p1 = 0.f;
  for (int d = lane; d < DMODEL; d += 64) {
    const float xv = X[(size_t)row * DMODEL + d];
    p0 += xv * out_W[d];
    p1 += xv * out_W[DMODEL + d];
  }
  p0 = wave_sum64(p0);
  p1 = wave_sum64(p1);
  if (lane == 0) {
    const float nd0 = p0 + out_b[0];
    const float nd1 = p1 + out_b[1];
    float c0, c1;
    if (init) {
      c0 = past[((size_t)b * PAST_N + PAST_N - 1) * 2 + 0];
      c1 = past[((size_t)b * PAST_N + PAST_N - 1) * 2 + 1];
    } else {
      c0 = cur[b * 2 + 0];
      c1 = cur[b * 2 + 1];
    }
    c0 += nd0; c1 += nd1;
    cur[b * 2 + 0] = c0; cur[b * 2 + 1] = c1;
    ndb[b * 2 + 0] = nd0; ndb[b * 2 + 1] = nd1;
    out[((size_t)b * FUT_N + s) * 2 + 0] = c0;
    out[((size_t)b * FUT_N + s) * 2 + 1] = c1;
  }
}

// ======================= decode stream pack (4 replicas) =======================
__global__ __launch_bounds__(256) void k_pack_stream(
    const float* __restrict__ sa_Wqkv, const float* __restrict__ sa_Wo,
    const float* __restrict__ ca_Wqkv, const float* __restrict__ ca_Wo,
    const float* __restrict__ ff1_W, const float* __restrict__ ff2_W,
    uint4* __restrict__ Wd)
{
  const unsigned g = blockIdx.x * 256 + threadIdx.x;
  if (g >= TOTAL_U4) return;
  const unsigned tile = g >> 11, off = g & 2047u;
  const float* src = nullptr;
  if (tile < 32) {
    if (off < 1536) {
      const int k8 = tile, n = off;
      const int j = n >> 8, dcol = n & 255, l = j >> 1, kv = j & 1;
      src = ca_Wqkv + (size_t)l * 196608 + (size_t)(256 + kv * 256 + dcol) * 256 + 8 * k8;
    }
  } else {
    const unsigned r = tile - 32, l = r / 60, p = r % 60;
    if (p < 16) {
      if (off < 1536) {
        const int row = off / 768, n = off % 768, k8 = 2 * p + row;
        src = sa_Wqkv + (size_t)l * 196608 + (size_t)n * 256 + 8 * k8;
      }
    } else if (p < 20) {
      const int k8 = 8 * (p - 16) + (off >> 8), n = off & 255;
      src = sa_Wo + (size_t)l * 65536 + (size_t)n * 256 + 8 * k8;
    } else if (p < 24) {
      const int k8 = 8 * (p - 20) + (off >> 8), n = off & 255;
      src = ca_Wqkv + (size_t)l * 196608 + (size_t)n * 256 + 8 * k8;
    } else if (p < 28) {
      const int k8 = 8 * (p - 24) + (off >> 8), n = off & 255;
      src = ca_Wo + (size_t)l * 65536 + (size_t)n * 256 + 8 * k8;
    } else if (p < 44) {
      const int row = off >> 10, n = off & 1023, k8 = 2 * (p - 28) + row;
      src = ff1_W + (size_t)l * 262144 + (size_t)n * 256 + 8 * k8;
    } else {
      const int k8 = 8 * (p - 44) + (off >> 8), n = off & 255;
      src = ff2_W + (size_t)l * 262144 + (size_t)n * 1024 + 8 * k8;
    }
  }
  uint4 u = {0u, 0u, 0u, 0u};
  if (src) {
    u.x = ((uint32_t)f2bf(src[1]) << 16) | (uint32_t)f2bf(src[0]);
    u.y = ((uint32_t)f2bf(src[3]) << 16) | (uint32_t)f2bf(src[2]);
    u.z = ((uint32_t)f2bf(src[5]) << 16) | (uint32_t)f2bf(src[4]);
    u.w = ((uint32_t)f2bf(src[7]) << 16) | (uint32_t)f2bf(src[6]);
  }
#pragma unroll
  for (int c = 0; c < NCOPY; c++) Wd[(size_t)c * TOTAL_U4 + g] = u;
}

// ======================= fused 19-step decode =======================
// one WG (512 thr) per batch element; weights stream through a 4-slot 128KB
// LDS ring via global_load_lds; counted vmcnt(8) keeps 2-3 tiles in flight.
// WG reads stream replica (b&3) to cut same-address congestion.
__global__ __launch_bounds__(NT) void k_decode(
    const uint4* __restrict__ Wd, const float* __restrict__ bckv,
    const float* __restrict__ in_W, const float* __restrict__ in_b,
    const float* __restrict__ pos_emb,
    const float* __restrict__ ln0_w, const float* __restrict__ ln0_b,
    const float* __restrict__ sa_bqkv, const float* __restrict__ sa_bo,
    const float* __restrict__ ca_bqkv, const float* __restrict__ ca_bo,
    const float* __restrict__ ff1_b, const float* __restrict__ ff2_b,
    const float* __restrict__ ln1_w, const float* __restrict__ ln1_b,
    const float* __restrict__ ln2_w, const float* __restrict__ ln2_b,
    const float* __restrict__ ln3_w, const float* __restrict__ ln3_b,
    const float* __restrict__ out_W, const float* __restrict__ out_b,
    __hip_bfloat16* __restrict__ Ksa, __hip_bfloat16* __restrict__ Vsa,
    __hip_bfloat16* __restrict__ C6,
    const float* __restrict__ ndb, const float* __restrict__ cur,
    float* __restrict__ out)
{
  const int b = blockIdx.x;
  const int tid = threadIdx.x;
  const size_t slab = (size_t)BATCH * S_TOT * DMODEL;
  const uint4* Wbase = Wd + (size_t)(b & (NCOPY - 1)) * TOTAL_U4;

  __shared__ __align__(16) uint4 lds_w[4 * TILE_U4];   // 128 KB
  __shared__ __align__(16) float x[256];
  __shared__ __align__(16) float xt[256];
  __shared__ __align__(16) float q[256];
  __shared__ __align__(16) float att[256];
  __shared__ __align__(16) float hbuf[1024];
  __shared__ float pred[NT];
  __shared__ float kn[256], vn[256];
  __shared__ __align__(16) float ckvn[1536];
  __shared__ float ss[8][72];
  __shared__ float sb[8], sb2[8];
  __shared__ float ndc[4];

  const float4* x4x = (const float4*)x;
  const float4* x4t = (const float4*)xt;
  const float4* a4  = (const float4*)att;
  const float4* h4  = (const float4*)hbuf;

  // ---- preload ALL per-tid constants into registers (one-time) ----
  const bool lo = tid < 256;
  const float c_bk0 = bckv[tid], c_bk1 = bckv[tid + 512], c_bk2 = bckv[tid + 1024];
  float c_inW0 = 0.f, c_inW1 = 0.f, c_inb = 0.f, c_l0w = 0.f, c_l0b = 0.f;
  if (lo) {
    c_inW0 = in_W[2 * tid]; c_inW1 = in_W[2 * tid + 1]; c_inb = in_b[tid];
    c_l0w = ln0_w[tid];     c_l0b = ln0_b[tid];
  }
  float bq0[LAYERS], bq1[LAYERS], bso[LAYERS], bcq[LAYERS], bco[LAYERS];
  float bf10[LAYERS], bf11[LAYERS], bf2[LAYERS];
  float w1[LAYERS], bb1[LAYERS], w2[LAYERS], bb2[LAYERS], w3[LAYERS], bb3[LAYERS];
#pragma unroll
  for (int l = 0; l < LAYERS; l++) {
    bq0[l] = sa_bqkv[l * 768 + tid];
    bq1[l] = lo ? sa_bqkv[l * 768 + 512 + tid] : 0.f;
    bso[l] = lo ? sa_bo[l * 256 + tid] : 0.f;
    bcq[l] = lo ? ca_bqkv[l * 768 + tid] : 0.f;
    bco[l] = lo ? ca_bo[l * 256 + tid] : 0.f;
    bf10[l] = ff1_b[l * 1024 + tid];
    bf11[l] = ff1_b[l * 1024 + 512 + tid];
    bf2[l] = lo ? ff2_b[l * 256 + tid] : 0.f;
    w1[l] = lo ? ln1_w[l * 256 + tid] : 0.f;  bb1[l] = lo ? ln1_b[l * 256 + tid] : 0.f;
    w2[l] = lo ? ln2_w[l * 256 + tid] : 0.f;  bb2[l] = lo ? ln2_b[l * 256 + tid] : 0.f;
    w3[l] = lo ? ln3_w[l * 256 + tid] : 0.f;  bb3[l] = lo ? ln3_b[l * 256 + tid] : 0.f;
  }
  float c_ow[4] = {0.f, 0.f, 0.f, 0.f};
  float c_ob = 0.f;
  if (tid < 128) {
    const int d0 = tid >> 6, ll = tid & 63;
#pragma unroll
    for (int j = 0; j < 4; j++) c_ow[j] = out_W[d0 * 256 + ll + 64 * j];
    c_ob = out_b[d0];
  }
  if (tid == 0) {
    ndc[0] = ndb[2 * b];     ndc[1] = ndb[2 * b + 1];
    ndc[2] = cur[2 * b];     ndc[3] = cur[2 * b + 1];
  }
  // flush const loads so the vmcnt queue holds only tile prefetches
  asm volatile("s_waitcnt vmcnt(0)" ::: "memory");

  auto issue_tile = [&](unsigned g) {
    const unsigned sidx = g % (unsigned)TILES_STEP;
    const unsigned slot = g & 3u;
    const uint4* src = Wbase + (size_t)sidx * TILE_U4 + tid;
    uint4* dst = &lds_w[slot * TILE_U4 + tid];
#pragma unroll
    for (int j = 0; j < 4; j++) gld_lds16(src + j * 512, dst + j * 512);
  };
  // entering compute of tile g: wait for g (allow 2 tiles = 8 loads younger),
  // barrier (slot g-1's readers done), issue g+3 into that slot.
  auto tile_wait_issue = [&](unsigned g) {
    __builtin_amdgcn_sched_barrier(0);
    asm volatile("s_waitcnt vmcnt(8) lgkmcnt(0)" ::: "memory");
    __builtin_amdgcn_sched_barrier(0);
    __builtin_amdgcn_s_barrier();
    __builtin_amdgcn_sched_barrier(0);
    issue_tile(g + 3);
    __builtin_amdgcn_sched_barrier(0);
  };

  auto ln_store = [&](float v, float gw, float gb, float* dst) {
    float vv = lo ? v : 0.f;
    float s  = wave_sum64(vv);
    float s2 = wave_sum64(vv * vv);
    if ((tid & 63) == 0) { sb[tid >> 6] = s; sb2[tid >> 6] = s2; }
    SYNC();
    float mean = (sb[0] + sb[1] + sb[2] + sb[3]) * (1.0f / 256.0f);
    float ex2  = (sb2[0] + sb2[1] + sb2[2] + sb2[3]) * (1.0f / 256.0f);
    float var = ex2 - mean * mean;
    if (lo) dst[tid] = (vv - mean) * rsqrtf(var + 1e-5f) * gw + gb;
    SYNC();
  };

  // attention: 1 wave = 1 head; wide loads (K: uint4, V: uint32 pairs)
  auto attn8 = [&](const __hip_bfloat16* Kc, const __hip_bfloat16* Vc,
                   const float* knw, const float* vnw, int pos) {
    const int h = tid >> 6, lane = tid & 63;
    const float* qh = q + h * 32;
    float mx = -1e30f;
    for (int k0 = lane; k0 <= pos; k0 += 64) {
      float s = 0.f;
      if (k0 == pos) {
        const float* kp = knw + h * 32;
#pragma unroll
        for (int i = 0; i < 32; i++) s += qh[i] * kp[i];
      } else {
        const uint4* kp = (const uint4*)(Kc + ((size_t)b * S_TOT + k0) * DMODEL + h * 32);
        const uint4 w0 = kp[0], w1 = kp[1], w2 = kp[2], w3 = kp[3];
        s = dot8q(w0, qh) + dot8q(w1, qh + 8) + dot8q(w2, qh + 16) + dot8q(w3, qh + 24);
      }
      s *= 0.17677669529663687f;
      ss[h][k0] = s;
      mx = fmaxf(mx, s);
    }
    mx = wave_max64(mx);
    float sum = 0.f;
    for (int k0 = lane; k0 <= pos; k0 += 64) {
      float e = __expf(ss[h][k0] - mx);
      ss[h][k0] = e;
      sum += e;
    }
    sum = wave_sum64(sum);
    const float inv = 1.0f / sum;
    // V-pass: 4-way key-parallel × 16 d-pairs (uint32 = 2 bf16 per load)
    const int kpar = lane >> 4, d2 = lane & 15;
    const uint32_t* vbase = (const uint32_t*)(Vc + (size_t)b * S_TOT * DMODEL + h * 32) + d2;
    float oA = 0.f, oB = 0.f;
    for (int k0 = kpar; k0 < pos; k0 += 4) {
      const uint32_t w = vbase[(size_t)k0 * (DMODEL / 2)];
      const float p = ss[h][k0];
      oA += p * bl16(w);
      oB += p * bh16(w);
    }
    oA += __shfl_xor(oA, 16, 64); oA += __shfl_xor(oA, 32, 64);
    oB += __shfl_xor(oB, 16, 64); oB += __shfl_xor(oB, 32, 64);
    if (kpar == 0) {
      const float p = ss[h][pos];
      oA += p * vnw[h * 32 + 2 * d2];
      oB += p * vnw[h * 32 + 2 * d2 + 1];
      att[h * 32 + 2 * d2]     = oA * inv;
      att[h * 32 + 2 * d2 + 1] = oB * inv;
    }
  };

  const int n8 = tid & 255, half = tid >> 8;
  unsigned gt = 0;
  issue_tile(0);
  issue_tile(1);
  issue_tile(2);

  for (int s = 1; s < FUT_N; s++) {
    const int pos = PAST_N - 1 + s;
    SYNCV();  // step-boundary drain (cache-store -> next-step read visibility)

    // 1. token embed + LN0 -> xt ; copy to x  (pos_emb: 1 global row/step)
    float xe = 0.f;
    if (lo) {
      xe = c_inW0 * ndc[0] + c_inW1 * ndc[1] + c_inb + pos_emb[(size_t)pos * DMODEL + tid];
    }
    ln_store(xe, c_l0w, c_l0b, xt);
    if (lo) x[tid] = xt[tid];

    // 2. CKV: 32 tiles, cols tid, tid+512, tid+1024, x = xt
    {
      float a0 = 0.f, a1 = 0.f, a2 = 0.f;
      for (int t = 0; t < 32; t++) {
        tile_wait_issue(gt);
        const uint4* T = &lds_w[(gt & 3u) * TILE_U4];
        const float4 xa = x4t[2 * t], xb = x4t[2 * t + 1];
        a0 = fma8u(T[tid],        xa, xb, a0);
        a1 = fma8u(T[tid + 512],  xa, xb, a1);
        a2 = fma8u(T[tid + 1024], xa, xb, a2);
        gt++;
      }
      float v0 = a0 + c_bk0;
      float v1 = a1 + c_bk1;
      float v2 = a2 + c_bk2;
      ckvn[tid] = v0; ckvn[tid + 512] = v1; ckvn[tid + 1024] = v2;
      {
        int n = tid;
        C6[(size_t)(n >> 8) * slab + ((size_t)b * S_TOT + pos) * DMODEL + (n & 255)] = __float2bfloat16(v0);
        n = tid + 512;
        C6[(size_t)(n >> 8) * slab + ((size_t)b * S_TOT + pos) * DMODEL + (n & 255)] = __float2bfloat16(v1);
        n = tid + 1024;
        C6[(size_t)(n >> 8) * slab + ((size_t)b * S_TOT + pos) * DMODEL + (n & 255)] = __float2bfloat16(v2);
      }
      SYNC();
    }

#pragma unroll
    for (int l = 0; l < LAYERS; l++) {
      // a. QKV: 16 tiles (rows 2t,2t+1 of [32][768]); x source = x
      {
        float q0 = 0.f, q1 = 0.f;
        for (int t = 0; t < 16; t++) {
          tile_wait_issue(gt);
          const uint4* T = &lds_w[(gt & 3u) * TILE_U4];
          const float4 xa0 = x4x[4 * t],     xb0 = x4x[4 * t + 1];
          const float4 xa1 = x4x[4 * t + 2], xb1 = x4x[4 * t + 3];
          q0 = fma8u(T[tid],       xa0, xb0, q0);
          q0 = fma8u(T[768 + tid], xa1, xb1, q0);
          if (lo) {
            q1 = fma8u(T[512 + tid],  xa0, xb0, q1);
            q1 = fma8u(T[1280 + tid], xa1, xb1, q1);
          }
          gt++;
        }
        {
          const int n = tid;
          float v = q0 + bq0[l];
          if (n < 256) q[n] = v;
          else {
            kn[n - 256] = v;
            Ksa[(size_t)l * slab + ((size_t)b * S_TOT + pos) * DMODEL + (n - 256)] = __float2bfloat16(v);
          }
        }
        if (lo) {
          const int n = tid + 512;
          float v = q1 + bq1[l];
          vn[n - 512] = v;
          Vsa[(size_t)l * slab + ((size_t)b * S_TOT + pos) * DMODEL + (n - 512)] = __float2bfloat16(v);
        }
        SYNC();
      }
      // b. SA attention
      attn8(Ksa + (size_t)l * slab, Vsa + (size_t)l * slab, kn, vn, pos);
      SYNC();
      // c. WO: 4 tiles; split-K by half; x = att
      {
        float acc = 0.f;
        for (int t = 0; t < 4; t++) {
          tile_wait_issue(gt);
          const uint4* T = &lds_w[(gt & 3u) * TILE_U4];
#pragma unroll
          for (int rr = 0; rr < 4; rr++) {
            const int k8 = 8 * t + 4 * half + rr;
            acc = fma8u(T[(4 * half + rr) * 256 + n8], a4[2 * k8], a4[2 * k8 + 1], acc);
          }
          gt++;
        }
        pred[tid] = acc;
        SYNC();
        float v = lo ? (x[tid] + pred[tid] + pred[tid + 256] + bso[l]) : 0.f;
        ln_store(v, w1[l], bb1[l], x);
      }
      // d. CAQ: 4 tiles; x source = x
      {
        float acc = 0.f;
        for (int t = 0; t < 4; t++) {
          tile_wait_issue(gt);
          const uint4* T = &lds_w[(gt & 3u) * TILE_U4];
#pragma unroll
          for (int rr = 0; rr < 4; rr++) {
            const int k8 = 8 * t + 4 * half + rr;
            acc = fma8u(T[(4 * half + rr) * 256 + n8], x4x[2 * k8], x4x[2 * k8 + 1], acc);
          }
          gt++;
        }
        pred[tid] = acc;
        SYNC();
        if (lo) q[tid] = pred[tid] + pred[tid + 256] + bcq[l];
        SYNC();
      }
      // e. CA attention
      attn8(C6 + (size_t)(2 * l) * slab, C6 + (size_t)(2 * l + 1) * slab,
            ckvn + l * 512, ckvn + l * 512 + 256, pos);
      SYNC();
      // f. CAO: 4 tiles; x = att
      {
        float acc = 0.f;
        for (int t = 0; t < 4; t++) {
          tile_wait_issue(gt);
          const uint4* T = &lds_w[(gt & 3u) * TILE_U4];
#pragma unroll
          for (int rr = 0; rr < 4; rr++) {
            const int k8 = 8 * t + 4 * half + rr;
            acc = fma8u(T[(4 * half + rr) * 256 + n8], a4[2 * k8], a4[2 * k8 + 1], acc);
          }
          gt++;
        }
        pred[tid] = acc;
        SYNC();
        float v = lo ? (x[tid] + pred[tid] + pred[tid + 256] + bco[l]) : 0.f;
        ln_store(v, w2[l], bb2[l], x);
      }
      // g. FF1: 16 tiles; cols tid, tid+512
      {
        float f0 = 0.f, f1 = 0.f;
        for (int t = 0; t < 16; t++) {
          tile_wait_issue(gt);
          const uint4* T = &lds_w[(gt & 3u) * TILE_U4];
          const float4 xa0 = x4x[4 * t],     xb0 = x4x[4 * t + 1];
          const float4 xa1 = x4x[4 * t + 2], xb1 = x4x[4 * t + 3];
          f0 = fma8u(T[tid],        xa0, xb0, f0);
          f0 = fma8u(T[1024 + tid], xa1, xb1, f0);
          f1 = fma8u(T[512 + tid],  xa0, xb0, f1);
          f1 = fma8u(T[1536 + tid], xa1, xb1, f1);
          gt++;
        }
        hbuf[tid]       = gelu_f(f0 + bf10[l]);
        hbuf[tid + 512] = gelu_f(f1 + bf11[l]);
        SYNC();
      }
      // h. FF2: 16 tiles; split-K by half; x = hbuf
      {
        float acc = 0.f;
        for (int t = 0; t < 16; t++) {
          tile_wait_issue(gt);
          const uint4* T = &lds_w[(gt & 3u) * TILE_U4];
#pragma unroll
          for (int rr = 0; rr < 4; rr++) {
            const int k8 = 8 * t + 4 * half + rr;
            acc = fma8u(T[(4 * half + rr) * 256 + n8], h4[2 * k8], h4[2 * k8 + 1], acc);
          }
          gt++;
        }
        pred[tid] = acc;
        SYNC();
        float v = lo ? (x[tid] + pred[tid] + pred[tid + 256] + bf2[l]) : 0.f;
        ln_store(v, w3[l], bb3[l], x);
      }
    }

    // readout (register out_W)
    {
      const int lane = tid & 63;
      if (tid < 128) {
        const int d0 = tid >> 6;
        float p = 0.f;
#pragma unroll
        for (int j = 0; j < 4; j++) p += x[lane + 64 * j] * c_ow[j];
        p = wave_sum64(p);
        if (lane == 0) {
          const float nd = p + c_ob;
          ndc[d0] = nd;
          const float c = ndc[2 + d0] + nd;
          ndc[2 + d0] = c;
          out[((size_t)b * FUT_N + s) * 2 + d0] = c;
        }
      }
      SYNC();
    }
  }
  asm volatile("s_waitcnt vmcnt(0)" ::: "memory");  // drain before endpgm
}

// ======================= host launch =======================
extern "C" void kernel_launch(void* const* d_in, const int* in_sizes, int n_in,
                              void* d_out, int out_size, void* d_ws, size_t ws_size,
                              hipStream_t stream)
{
  const float* past    = (const float*)d_in[0];
  const float* in_W    = (const float*)d_in[1];
  const float* in_b    = (const float*)d_in[2];
  const float* pos_emb = (const float*)d_in[3];
  const float* ln0_w   = (const float*)d_in[4];
  const float* ln0_b   = (const float*)d_in[5];
  const float* sa_Wqkv = (const float*)d_in[6];
  const float* sa_bqkv = (const float*)d_in[7];
  const float* sa_Wo   = (const float*)d_in[8];
  const float* sa_bo   = (const float*)d_in[9];
  const float* ca_Wqkv = (const float*)d_in[10];
  const float* ca_bqkv = (const float*)d_in[11];
  const float* ca_Wo   = (const float*)d_in[12];
  const float* ca_bo   = (const float*)d_in[13];
  const float* ff1_W   = (const float*)d_in[14];
  const float* ff1_b   = (const float*)d_in[15];
  const float* ff2_W   = (const float*)d_in[16];
  const float* ff2_b   = (const float*)d_in[17];
  const float* ln1_w   = (const float*)d_in[18];
  const float* ln1_b   = (const float*)d_in[19];
  const float* ln2_w   = (const float*)d_in[20];
  const float* ln2_b   = (const float*)d_in[21];
  const float* ln3_w   = (const float*)d_in[22];
  const float* ln3_b   = (const float*)d_in[23];
  const float* out_W   = (const float*)d_in[24];
  const float* out_b   = (const float*)d_in[25];
  float* out = (float*)d_out;

  const size_t Mpre = (size_t)BATCH * PAST_N;              // 6400
  const size_t slab = (size_t)BATCH * S_TOT * DMODEL;      // 2,293,760

  float* ws_f = (float*)d_ws;
  float* A    = ws_f;
  float* Bb   = A + Mpre * DMODEL;
  float* qb   = Bb + Mpre * DMODEL;
  float* at   = qb + Mpre * DMODEL;
  float* hb   = at + Mpre * DMODEL;
  float* Wckv = hb + Mpre * FFD;
  float* bckv = Wckv + (size_t)1536 * 256;
  float* ndb  = bckv + 1536;
  float* cur  = ndb + 256;
  __hip_bfloat16* Ksa = (__hip_bfloat16*)(cur + 256);
  __hip_bfloat16* Vsa = Ksa + 3 * slab;
  __hip_bfloat16* C6  = Vsa + 3 * slab;
  // 4 stream replicas alias A..hb (52.4 MB, dead after prefill+readout(init)).
  // NCOPY * TOTAL_U4 * 16B = 27.8 MB < 52.4 MB.
  uint4* Wd = (uint4*)A;

  const size_t need = ((size_t)(C6 + 6 * slab) - (size_t)d_ws);
  if (ws_size < need) return;

  auto layer = [&](int l, int M, int rpb, int pbase) {
    const float* Wqkv = sa_Wqkv + (size_t)l * 768 * 256;
    __hip_bfloat16* kcl = Ksa + (size_t)l * slab;
    __hip_bfloat16* vcl = Vsa + (size_t)l * slab;
    k_gemm<<<dim3(768 / BN, M / BM), 256, 0, stream>>>(
        A, Wqkv, sa_bqkv + l * 768, nullptr, nullptr, M, 768, 256, 0, 1,
        qb, kcl, vcl, nullptr, rpb, pbase);
    k_attn<<<M * HEADS, 64, 0, stream>>>(qb, kcl, vcl, at, rpb, pbase);
    k_gemm<<<dim3(256 / BN, M / BM), 256, 0, stream>>>(
        at, sa_Wo + (size_t)l * 65536, sa_bo + l * 256, A, Bb, M, 256, 256, 0, 0,
        nullptr, nullptr, nullptr, nullptr, 1, 0);
    k_ln<<<M, 256, 0, stream>>>(Bb, ln1_w + l * 256, ln1_b + l * 256, A);
    k_gemm<<<dim3(256 / BN, M / BM), 256, 0, stream>>>(
        A, ca_Wqkv + (size_t)l * 768 * 256, ca_bqkv + l * 768, nullptr, qb,
        M, 256, 256, 0, 0, nullptr, nullptr, nullptr, nullptr, 1, 0);
    k_attn<<<M * HEADS, 64, 0, stream>>>(
        qb, C6 + (size_t)(2 * l) * slab, C6 + (size_t)(2 * l + 1) * slab, at, rpb, pbase);
    k_gemm<<<dim3(256 / BN, M / BM), 256, 0, stream>>>(
        at, ca_Wo + (size_t)l * 65536, ca_bo + l * 256, A, Bb, M, 256, 256, 0, 0,
        nullptr, nullptr, nullptr, nullptr, 1, 0);
    k_ln<<<M, 256, 0, stream>>>(Bb, ln2_w + l * 256, ln2_b + l * 256, A);
    k_gemm<<<dim3(FFD / BN, M / BM), 256, 0, stream>>>(
        A, ff1_W + (size_t)l * FFD * 256, ff1_b + l * FFD, nullptr, hb,
        M, FFD, 256, 1, 0, nullptr, nullptr, nullptr, nullptr, 1, 0);
    k_gemm<<<dim3(256 / BN, M / BM), 256, 0, stream>>>(
        hb, ff2_W + (size_t)l * 256 * FFD, ff2_b + l * 256, A, Bb, M, 256, FFD, 0, 0,
        nullptr, nullptr, nullptr, nullptr, 1, 0);
    k_ln<<<M, 256, 0, stream>>>(Bb, ln3_w + l * 256, ln3_b + l * 256, A);
  };

  // ---- prefill over past 50 positions ----
  k_prepack<<<1536, 256, 0, stream>>>(ca_Wqkv, ca_bqkv, Wckv, bckv);
  k_embed<<<(int)Mpre, 256, 0, stream>>>(past, in_W, in_b, pos_emb, ln0_w, ln0_b, A);
  k_gemm<<<dim3(1536 / BN, (int)Mpre / BM), 256, 0, stream>>>(
      A, Wckv, bckv, nullptr, nullptr, (int)Mpre, 1536, 256, 0, 2,
      nullptr, nullptr, nullptr, C6, PAST_N, 0);
  for (int l = 0; l < LAYERS; l++) layer(l, (int)Mpre, PAST_N, 0);
  k_readout<<<BATCH, 64, 0, stream>>>(A, out_W, out_b, past, cur, ndb, out, PAST_N, 0, 1);

  // ---- pack decode weight stream (4 replicas into dead prefill scratch) ----
  k_pack_stream<<<(TOTAL_U4 + 255) / 256, 256, 0, stream>>>(
      sa_Wqkv, sa_Wo, ca_Wqkv, ca_Wo, ff1_W, ff2_W, Wd);

  // ---- fused 19-step decode: one WG per batch element ----
  k_decode<<<BATCH, NT, 0, stream>>>(
      Wd, bckv, in_W, in_b, pos_emb, ln0_w, ln0_b,
      sa_bqkv, sa_bo, ca_bqkv, ca_bo, ff1_b, ff2_b,
      ln1_w, ln1_b, ln2_w, ln2_b, ln3_w, ln3_b,
      out_W, out_b, Ksa, Vsa, C6, ndb, cur, out);
}

// Round 9
// 4424.121 us; speedup vs baseline: 3.6378x; 1.2046x over previous
//
#include <hip/hip_runtime.h>
#include <hip/hip_bf16.h>

#define DMODEL 256
#define S_TOT  70
#define BATCH  128
#define HEADS  8
#define DHEAD  32
#define PAST_N 50
#define FUT_N  20
#define LAYERS 3
#define FFD    1024

#define BM 32
#define BN 64
#define BK 16

#define NT 512
// ---- decode weight stream: per-wave sub-tile sequences. Sub-tile = 256 uint4
// (4KB) = 8 cols x 32 k8-groups (f16 pairs). Per wave per step: 192 sub-tiles:
// CKV 24, then per layer [QKV 12 | WO 4 | CAQ 4 | CAO 4 | FF1 16 | FF2 16].
// Layout: Wd[((w*192 + n)<<8) + e], e = k8*8 + c.
#define SUBT_W   192
#define TOTAL_ENT (8 * SUBT_W * 256)

__device__ __forceinline__ float wave_sum64(float v) {
#pragma unroll
  for (int off = 32; off > 0; off >>= 1) v += __shfl_xor(v, off, 64);
  return v;
}
__device__ __forceinline__ float wave_max64(float v) {
#pragma unroll
  for (int off = 32; off > 0; off >>= 1) v = fmaxf(v, __shfl_xor(v, off, 64));
  return v;
}
__device__ __forceinline__ float gelu_f(float x) {
  return 0.5f * x * (1.0f + erff(x * 0.7071067811865476f));
}
__device__ __forceinline__ float bl16(uint32_t w) { return __uint_as_float(w << 16); }
__device__ __forceinline__ float bh16(uint32_t w) { return __uint_as_float(w & 0xffff0000u); }
__device__ __forceinline__ uint16_t f2h(float v) {
  _Float16 h = (_Float16)v;
  return __builtin_bit_cast(uint16_t, h);
}
__device__ __forceinline__ uint32_t pk2(float lo_, float hi_) {
  return ((uint32_t)f2h(hi_) << 16) | (uint32_t)f2h(lo_);
}
// f16 packed dot2-accumulate: acc += a.lo*b.lo + a.hi*b.hi
__device__ __forceinline__ float fdot2a(uint32_t a, uint32_t b, float acc) {
  asm("v_dot2_f32_f16 %0, %1, %2, %0" : "+v"(acc) : "v"(a), "v"(b));
  return acc;
}

// raw barrier + LDS fence (no vmcnt drain — preserves per-wave prefetch queues)
#define SYNC() do { __builtin_amdgcn_sched_barrier(0); \
  asm volatile("s_waitcnt lgkmcnt(0)" ::: "memory"); \
  __builtin_amdgcn_s_barrier(); \
  __builtin_amdgcn_sched_barrier(0); } while (0)
#define VMWAIT8() do { __builtin_amdgcn_sched_barrier(0); \
  asm volatile("s_waitcnt vmcnt(8)" ::: "memory"); \
  __builtin_amdgcn_sched_barrier(0); } while (0)

__device__ __forceinline__ void gld_lds16(const uint4* g, uint4* l) {
  __builtin_amdgcn_global_load_lds(
      (const __attribute__((address_space(1))) void*)g,
      (__attribute__((address_space(3))) void*)l, 16, 0, 0);
}

__device__ __forceinline__ float ln_norm_256(float x, float g, float b, float* sbuf, int tid) {
  float s = wave_sum64(x);
  if ((tid & 63) == 0) sbuf[tid >> 6] = s;
  __syncthreads();
  float mean = (sbuf[0] + sbuf[1] + sbuf[2] + sbuf[3]) * (1.0f / 256.0f);
  __syncthreads();
  float d = x - mean;
  float vs = wave_sum64(d * d);
  if ((tid & 63) == 0) sbuf[tid >> 6] = vs;
  __syncthreads();
  float var = (sbuf[0] + sbuf[1] + sbuf[2] + sbuf[3]) * (1.0f / 256.0f);
  return d * rsqrtf(var + 1e-5f) * g + b;
}

// ======================= prefill kernels (unchanged) =======================
__global__ __launch_bounds__(256) void k_gemm(
    const float* __restrict__ A, const float* __restrict__ W,
    const float* __restrict__ bias, const float* __restrict__ Rres,
    float* __restrict__ C, int M, int N, int K, int act, int outmode,
    float* __restrict__ qout, __hip_bfloat16* __restrict__ kc,
    __hip_bfloat16* __restrict__ vc, __hip_bfloat16* __restrict__ c6,
    int rows_per_b, int pos_base)
{
  __shared__ float As[BK][BM + 2];
  __shared__ float Ws[BK][BN + 4];
  const int tid = threadIdx.x;
  const int bm0 = blockIdx.y * BM;
  const int bn0 = blockIdx.x * BN;
  const int r = tid >> 4, c = tid & 15;
  const int am = tid >> 3, ak = (tid & 7) << 1;
  const int wn = tid >> 2, wk = (tid & 3) << 2;
  const float* Aptr = A + (size_t)(bm0 + am) * K + ak;
  const float* Wptr = W + (size_t)(bn0 + wn) * K + wk;
  float acc[2][4] = {{0.f, 0.f, 0.f, 0.f}, {0.f, 0.f, 0.f, 0.f}};
  for (int k0 = 0; k0 < K; k0 += BK) {
    float2 av = *(const float2*)(Aptr + k0);
    float4 wv = *(const float4*)(Wptr + k0);
    As[ak][am] = av.x;  As[ak + 1][am] = av.y;
    Ws[wk][wn] = wv.x;  Ws[wk + 1][wn] = wv.y;
    Ws[wk + 2][wn] = wv.z;  Ws[wk + 3][wn] = wv.w;
    __syncthreads();
#pragma unroll
    for (int kk = 0; kk < BK; kk++) {
      const float2 a = *(const float2*)&As[kk][r << 1];
      const float4 w = *(const float4*)&Ws[kk][c << 2];
      acc[0][0] += a.x * w.x; acc[0][1] += a.x * w.y;
      acc[0][2] += a.x * w.z; acc[0][3] += a.x * w.w;
      acc[1][0] += a.y * w.x; acc[1][1] += a.y * w.y;
      acc[1][2] += a.y * w.z; acc[1][3] += a.y * w.w;
    }
    __syncthreads();
  }
#pragma unroll
  for (int i = 0; i < 2; i++) {
    const int row = bm0 + (r << 1) + i;
    const int b = row / rows_per_b;
    const int t = pos_base + row % rows_per_b;
#pragma unroll
    for (int j = 0; j < 4; j++) {
      const int n = bn0 + (c << 2) + j;
      float v = acc[i][j] + bias[n];
      if (Rres) v += Rres[(size_t)row * N + n];
      if (act) v = gelu_f(v);
      if (outmode == 0) {
        C[(size_t)row * N + n] = v;
      } else if (outmode == 1) {
        if (n < 256) qout[(size_t)row * DMODEL + n] = v;
        else if (n < 512) kc[((size_t)b * S_TOT + t) * DMODEL + (n - 256)] = __float2bfloat16(v);
        else vc[((size_t)b * S_TOT + t) * DMODEL + (n - 512)] = __float2bfloat16(v);
      } else {
        const int j6 = n >> 8;
        c6[(size_t)j6 * ((size_t)BATCH * S_TOT * DMODEL) +
           ((size_t)b * S_TOT + t) * DMODEL + (n & 255)] = __float2bfloat16(v);
      }
    }
  }
}

__global__ __launch_bounds__(64) void k_attn(
    const float* __restrict__ qbuf, const __hip_bfloat16* __restrict__ kc,
    const __hip_bfloat16* __restrict__ vc, float* __restrict__ outb,
    int rows_per_b, int pos_base)
{
  __shared__ float qs[DHEAD];
  __shared__ float ss[S_TOT];
  const int bid = blockIdx.x;
  const int h = bid & (HEADS - 1);
  const int row = bid >> 3;
  const int b = row / rows_per_b;
  const int t = pos_base + row % rows_per_b;
  const int nk = t + 1;
  const int lane = threadIdx.x;
  if (lane < DHEAD) qs[lane] = qbuf[(size_t)row * DMODEL + h * DHEAD + lane];
  __syncthreads();
  float mx = -1e30f;
  for (int k0 = lane; k0 < nk; k0 += 64) {
    const __hip_bfloat16* kp = kc + ((size_t)b * S_TOT + k0) * DMODEL + h * DHEAD;
    float s = 0.f;
#pragma unroll
    for (int i = 0; i < DHEAD; i++) s += qs[i] * __bfloat162float(kp[i]);
    s *= 0.17677669529663687f;
    ss[k0] = s;
    mx = fmaxf(mx, s);
  }
  mx = wave_max64(mx);
  float sum = 0.f;
  for (int k0 = lane; k0 < nk; k0 += 64) {
    float e = expf(ss[k0] - mx);
    ss[k0] = e;
    sum += e;
  }
  sum = wave_sum64(sum);
  __syncthreads();
  const float inv = 1.0f / sum;
  if (lane < DHEAD) {
    float o = 0.f;
    for (int k0 = 0; k0 < nk; k0++)
      o += ss[k0] * __bfloat162float(vc[((size_t)b * S_TOT + k0) * DMODEL + h * DHEAD + lane]);
    outb[(size_t)row * DMODEL + h * DHEAD + lane] = o * inv;
  }
}

__global__ __launch_bounds__(256) void k_ln(
    const float* __restrict__ Z, const float* __restrict__ g,
    const float* __restrict__ b, float* __restrict__ out)
{
  __shared__ float sbuf[4];
  const int row = blockIdx.x, tid = threadIdx.x;
  float x = Z[(size_t)row * DMODEL + tid];
  out[(size_t)row * DMODEL + tid] = ln_norm_256(x, g[tid], b[tid], sbuf, tid);
}

__global__ __launch_bounds__(256) void k_embed(
    const float* __restrict__ past, const float* __restrict__ in_W,
    const float* __restrict__ in_b, const float* __restrict__ pos_emb,
    const float* __restrict__ ln_w, const float* __restrict__ ln_b,
    float* __restrict__ Aout)
{
  __shared__ float sbuf[4];
  const int rowid = blockIdx.x;
  const int b = rowid / PAST_N, t = rowid % PAST_N;
  const int tid = threadIdx.x;
  float dx = 0.f, dy = 0.f;
  if (t > 0) {
    dx = past[((size_t)b * PAST_N + t) * 2 + 0] - past[((size_t)b * PAST_N + t - 1) * 2 + 0];
    dy = past[((size_t)b * PAST_N + t) * 2 + 1] - past[((size_t)b * PAST_N + t - 1) * 2 + 1];
  }
  float v = in_W[tid * 2 + 0] * dx + in_W[tid * 2 + 1] * dy + in_b[tid] +
            pos_emb[(size_t)t * DMODEL + tid];
  Aout[(size_t)rowid * DMODEL + tid] = ln_norm_256(v, ln_w[tid], ln_b[tid], sbuf, tid);
}

__global__ __launch_bounds__(256) void k_prepack(
    const float* __restrict__ caW, const float* __restrict__ cab,
    float* __restrict__ Wckv, float* __restrict__ bckv)
{
  const int n = blockIdx.x, tid = threadIdx.x;
  const int j = n >> 8, dcol = n & 255;
  const int l = j >> 1, kv = j & 1;
  const int srow = l * 768 + 256 + kv * 256 + dcol;
  Wckv[(size_t)n * 256 + tid] = caW[(size_t)srow * 256 + tid];
  if (tid == 0) bckv[n] = cab[l * 768 + 256 + kv * 256 + dcol];
}

__global__ __launch_bounds__(64) void k_readout(
    const float* __restrict__ X, const float* __restrict__ out_W,
    const float* __restrict__ out_b, const float* __restrict__ past,
    float* __restrict__ cur, float* __restrict__ ndb, float* __restrict__ out,
    int rows_per_b, int s, int init)
{
  const int b = blockIdx.x, lane = threadIdx.x;
  const int row = b * rows_per_b + rows_per_b - 1;
  float p0 = 0.f, p1 = 0.f;
  for (int d = lane; d < DMODEL; d += 64) {
    const float xv = X[(size_t)row * DMODEL + d];
    p0 += xv * out_W[d];
    p1 += xv * out_W[DMODEL + d];
  }
  p0 = wave_sum64(p0);
  p1 = wave_sum64(p1);
  if (lane == 0) {
    const float nd0 = p0 + out_b[0];
    const float nd1 = p1 + out_b[1];
    float c0, c1;
    if (init) {
      c0 = past[((size_t)b * PAST_N + PAST_N - 1) * 2 + 0];
      c1 = past[((size_t)b * PAST_N + PAST_N - 1) * 2 + 1];
    } else {
      c0 = cur[b * 2 + 0];
      c1 = cur[b * 2 + 1];
    }
    c0 += nd0; c1 += nd1;
    cur[b * 2 + 0] = c0; cur[b * 2 + 1] = c1;
    ndb[b * 2 + 0] = nd0; ndb[b * 2 + 1] = nd1;
    out[((size_t)b * FUT_N + s) * 2 + 0] = c0;
    out[((size_t)b * FUT_N + s) * 2 + 1] = c1;
  }
}

// ======================= decode stream pack (per-wave, f16 pairs) ==========
__global__ __launch_bounds__(256) void k_pack_stream(
    const float* __restrict__ sa_Wqkv, const float* __restrict__ sa_Wo,
    const float* __restrict__ ca_Wqkv, const float* __restrict__ ca_Wo,
    const float* __restrict__ ff1_W, const float* __restrict__ ff2_W,
    uint4* __restrict__ Wd)
{
  const unsigned gidx = blockIdx.x * 256 + threadIdx.x;
  if (gidx >= TOTAL_ENT) return;
  const unsigned w = gidx / (SUBT_W * 256);
  const unsigned r = gidx % (SUBT_W * 256);
  const unsigned n = r >> 8, e = r & 255u;
  const int k8 = e >> 3, c = e & 7;
  const float* src;
  if (n < 24) {
    const int col = (int)(w * 8 + 64 * n + c);
    const int j6 = col >> 8, dcol = col & 255, lq = j6 >> 1, kv = j6 & 1;
    src = ca_Wqkv + (size_t)lq * 196608 + (size_t)(256 + kv * 256 + dcol) * 256 + 8 * k8;
  } else {
    const unsigned m = n - 24;
    const int l = m / 56, p = m % 56;
    if (p < 12)      { const int col = w * 8 + 64 * p + c;        src = sa_Wqkv + (size_t)l * 196608 + (size_t)col * 256 + 8 * k8; }
    else if (p < 16) { const int col = w * 8 + 64 * (p - 12) + c; src = sa_Wo   + (size_t)l * 65536  + (size_t)col * 256 + 8 * k8; }
    else if (p < 20) { const int col = w * 8 + 64 * (p - 16) + c; src = ca_Wqkv + (size_t)l * 196608 + (size_t)col * 256 + 8 * k8; }
    else if (p < 24) { const int col = w * 8 + 64 * (p - 20) + c; src = ca_Wo   + (size_t)l * 65536  + (size_t)col * 256 + 8 * k8; }
    else if (p < 40) { const int col = w * 8 + 64 * (p - 24) + c; src = ff1_W   + (size_t)l * 262144 + (size_t)col * 256 + 8 * k8; }
    else {
      const unsigned mm = p - 40;
      const int col = w * 8 + 64 * (mm >> 2) + c;
      const int kk8 = (int)(mm & 3) * 32 + k8;
      src = ff2_W + (size_t)l * 262144 + (size_t)col * 1024 + 8 * kk8;
    }
  }
  uint4 u;
  u.x = ((uint32_t)f2h(src[1]) << 16) | (uint32_t)f2h(src[0]);
  u.y = ((uint32_t)f2h(src[3]) << 16) | (uint32_t)f2h(src[2]);
  u.z = ((uint32_t)f2h(src[5]) << 16) | (uint32_t)f2h(src[4]);
  u.w = ((uint32_t)f2h(src[7]) << 16) | (uint32_t)f2h(src[6]);
  Wd[gidx] = u;
}

// ======================= fused 19-step decode =======================
// one WG (512 thr = 8 waves) per batch element. Each WAVE owns a private
// 4-slot x 4KB LDS ring and streams its own weight sub-tiles with a
// per-wave vmcnt(8) pipeline — NO per-tile barriers; barriers only at
// phase boundaries. GEMV math = packed-f16 v_dot2_f32_f16.
__global__ __launch_bounds__(NT) void k_decode(
    const uint4* __restrict__ Wd, const float* __restrict__ bckv,
    const float* __restrict__ in_W, const float* __restrict__ in_b,
    const float* __restrict__ pos_emb,
    const float* __restrict__ ln0_w, const float* __restrict__ ln0_b,
    const float* __restrict__ sa_bqkv, const float* __restrict__ sa_bo,
    const float* __restrict__ ca_bqkv, const float* __restrict__ ca_bo,
    const float* __restrict__ ff1_b, const float* __restrict__ ff2_b,
    const float* __restrict__ ln1_w, const float* __restrict__ ln1_b,
    const float* __restrict__ ln2_w, const float* __restrict__ ln2_b,
    const float* __restrict__ ln3_w, const float* __restrict__ ln3_b,
    const float* __restrict__ out_W, const float* __restrict__ out_b,
    __hip_bfloat16* __restrict__ Ksa, __hip_bfloat16* __restrict__ Vsa,
    __hip_bfloat16* __restrict__ C6,
    const float* __restrict__ ndb, const float* __restrict__ cur,
    float* __restrict__ out)
{
  const int b = blockIdx.x;
  const int tid = threadIdx.x;
  const int wv = tid >> 6, lane = tid & 63;
  const size_t slab = (size_t)BATCH * S_TOT * DMODEL;

  __shared__ __align__(16) uint4 ring[8 * 4 * 256];   // 128 KB (8 waves x 4 slots x 4KB)
  __shared__ __align__(16) float x[256];
  __shared__ __align__(16) float xt[256];
  __shared__ __align__(16) float q[256];
  __shared__ __align__(16) float hbuf[1024];
  __shared__ __align__(16) float pred[256];
  __shared__ __align__(16) float kn[256], vn[256];
  __shared__ __align__(16) float ckvn[1536];
  __shared__ __align__(16) uint32_t xh[128], xth[128], atth[128], hh[512];
  __shared__ float ss[8][72];
  __shared__ float sb[8], sb2[8];
  __shared__ float ndc[4];

  // ---- preload per-tid constants to registers ----
  const bool lo = tid < 256;
  const float c_bk0 = bckv[tid], c_bk1 = bckv[tid + 512], c_bk2 = bckv[tid + 1024];
  float c_inW0 = 0.f, c_inW1 = 0.f, c_inb = 0.f, c_l0w = 0.f, c_l0b = 0.f;
  if (lo) {
    c_inW0 = in_W[2 * tid]; c_inW1 = in_W[2 * tid + 1]; c_inb = in_b[tid];
    c_l0w = ln0_w[tid];     c_l0b = ln0_b[tid];
  }
  float bq0[LAYERS], bq1[LAYERS], bso[LAYERS], bcq[LAYERS], bco[LAYERS];
  float bf10[LAYERS], bf11[LAYERS], bf2[LAYERS];
  float w1[LAYERS], bb1[LAYERS], w2[LAYERS], bb2[LAYERS], w3[LAYERS], bb3[LAYERS];
#pragma unroll
  for (int l = 0; l < LAYERS; l++) {
    bq0[l] = sa_bqkv[l * 768 + tid];
    bq1[l] = lo ? sa_bqkv[l * 768 + 512 + tid] : 0.f;
    bso[l] = lo ? sa_bo[l * 256 + tid] : 0.f;
    bcq[l] = lo ? ca_bqkv[l * 768 + tid] : 0.f;
    bco[l] = lo ? ca_bo[l * 256 + tid] : 0.f;
    bf10[l] = ff1_b[l * 1024 + tid];
    bf11[l] = ff1_b[l * 1024 + 512 + tid];
    bf2[l] = lo ? ff2_b[l * 256 + tid] : 0.f;
    w1[l] = lo ? ln1_w[l * 256 + tid] : 0.f;  bb1[l] = lo ? ln1_b[l * 256 + tid] : 0.f;
    w2[l] = lo ? ln2_w[l * 256 + tid] : 0.f;  bb2[l] = lo ? ln2_b[l * 256 + tid] : 0.f;
    w3[l] = lo ? ln3_w[l * 256 + tid] : 0.f;  bb3[l] = lo ? ln3_b[l * 256 + tid] : 0.f;
  }
  float c_ow[4] = {0.f, 0.f, 0.f, 0.f};
  float c_ob = 0.f;
  if (tid < 128) {
    const int d0 = tid >> 6, ll = tid & 63;
#pragma unroll
    for (int j = 0; j < 4; j++) c_ow[j] = out_W[d0 * 256 + ll + 64 * j];
    c_ob = out_b[d0];
  }
  if (tid == 0) {
    ndc[0] = ndb[2 * b];     ndc[1] = ndb[2 * b + 1];
    ndc[2] = cur[2 * b];     ndc[3] = cur[2 * b + 1];
  }
  asm volatile("s_waitcnt vmcnt(0)" ::: "memory");

  auto issue = [&](unsigned g) {
    const unsigned sidx = g % (unsigned)SUBT_W;
    const unsigned slot = g & 3u;
    const uint4* src = Wd + (((size_t)wv * SUBT_W + sidx) << 8) + lane;
    uint4* dst = &ring[(((unsigned)wv << 2) | slot) * 256u + (unsigned)lane];
#pragma unroll
    for (int j = 0; j < 4; j++) gld_lds16(src + (j << 6), dst + (j << 6));
  };

  // per-wave GEMV over cnt column-groups (8 cols each), kch K-chunks of 32 k8
  auto gemv = [&](unsigned& g, int cnt, int kch, const uint4* xp, auto&& emit) {
    const int kq = lane >> 3, c = lane & 7;
    for (int i = 0; i < cnt; i++) {
      float acc = 0.f;
      for (int kc = 0; kc < kch; kc++) {
        VMWAIT8();
        issue(g + 3);
        const uint4* S = &ring[(((unsigned)wv << 2) | (g & 3u)) * 256u];
#pragma unroll
        for (int j = 0; j < 4; j++) {
          const int k8 = kq * 4 + j;
          const uint4 W = S[k8 * 8 + c];
          const uint4 X = xp[kc * 32 + k8];
          acc = fdot2a(W.x, X.x, acc);
          acc = fdot2a(W.y, X.y, acc);
          acc = fdot2a(W.z, X.z, acc);
          acc = fdot2a(W.w, X.w, acc);
        }
        g++;
      }
      acc += __shfl_xor(acc, 8, 64);
      acc += __shfl_xor(acc, 16, 64);
      acc += __shfl_xor(acc, 32, 64);
      if (lane < 8) emit((wv << 3) + (i << 6) + lane, acc);
    }
  };

  // value LN + f32 store + packed-f16 mirror (shfl pair trick)
  auto ln_store = [&](float v, float gw_, float gb_, float* dst, uint32_t* dsth) {
    float vv = lo ? v : 0.f;
    float s  = wave_sum64(vv);
    float s2 = wave_sum64(vv * vv);
    if ((tid & 63) == 0) { sb[tid >> 6] = s; sb2[tid >> 6] = s2; }
    SYNC();
    float mean = (sb[0] + sb[1] + sb[2] + sb[3]) * (1.0f / 256.0f);
    float ex2  = (sb2[0] + sb2[1] + sb2[2] + sb2[3]) * (1.0f / 256.0f);
    float var = ex2 - mean * mean;
    float vn_ = (vv - mean) * rsqrtf(var + 1e-5f) * gw_ + gb_;
    float vo = __shfl_xor(vn_, 1, 64);
    if (lo) {
      dst[tid] = vn_;
      if (!(tid & 1)) dsth[tid >> 1] = pk2(vn_, vo);
    }
    SYNC();
  };

  // attention: 1 wave = 1 head; output packed to atth
  auto attn8 = [&](const __hip_bfloat16* Kc, const __hip_bfloat16* Vc,
                   const float* knw, const float* vnw, int pos) {
    const int h = wv;
    const float* qh = q + h * 32;
    float mx = -1e30f;
    for (int k0 = lane; k0 <= pos; k0 += 64) {
      float s = 0.f;
      if (k0 == pos) {
        const float* kp = knw + h * 32;
#pragma unroll
        for (int i = 0; i < 32; i++) s += qh[i] * kp[i];
      } else {
        const uint32_t* kp = (const uint32_t*)(Kc + ((size_t)b * S_TOT + k0) * DMODEL + h * 32);
#pragma unroll
        for (int i = 0; i < 16; i++) {
          uint32_t w = kp[i];
          s += bl16(w) * qh[2 * i];
          s += bh16(w) * qh[2 * i + 1];
        }
      }
      s *= 0.17677669529663687f;
      ss[h][k0] = s;
      mx = fmaxf(mx, s);
    }
    mx = wave_max64(mx);
    float sum = 0.f;
    for (int k0 = lane; k0 <= pos; k0 += 64) {
      float e = __expf(ss[h][k0] - mx);
      ss[h][k0] = e;
      sum += e;
    }
    sum = wave_sum64(sum);
    const float inv = 1.0f / sum;
    const int kpar = lane >> 4, d2 = lane & 15;
    const uint32_t* vbase = (const uint32_t*)(Vc + (size_t)b * S_TOT * DMODEL + h * 32) + d2;
    float oA = 0.f, oB = 0.f;
    for (int k0 = kpar; k0 < pos; k0 += 4) {
      const uint32_t w = vbase[(size_t)k0 * (DMODEL / 2)];
      const float p = ss[h][k0];
      oA += p * bl16(w);
      oB += p * bh16(w);
    }
    oA += __shfl_xor(oA, 16, 64); oA += __shfl_xor(oA, 32, 64);
    oB += __shfl_xor(oB, 16, 64); oB += __shfl_xor(oB, 32, 64);
    if (kpar == 0) {
      const float p = ss[h][pos];
      oA += p * vnw[h * 32 + 2 * d2];
      oB += p * vnw[h * 32 + 2 * d2 + 1];
      atth[h * 16 + d2] = pk2(oA * inv, oB * inv);
    }
  };

  unsigned g = 0;
  issue(0); issue(1); issue(2);

  for (int s = 1; s < FUT_N; s++) {
    const int pos = PAST_N - 1 + s;

    // 1. token embed + LN0 -> xt/xth ; copy to x/xh
    float xe = 0.f;
    if (lo) {
      xe = c_inW0 * ndc[0] + c_inW1 * ndc[1] + c_inb + pos_emb[(size_t)pos * DMODEL + tid];
    }
    ln_store(xe, c_l0w, c_l0b, xt, xth);
    if (lo) x[tid] = xt[tid];
    if (tid < 128) xh[tid] = xth[tid];

    // 2. CKV (24 sub-tiles/wave), input xth
    gemv(g, 24, 1, (const uint4*)xth, [&](int col, float a) { ckvn[col] = a; });
    SYNC();
    {
      float v0 = ckvn[tid] + c_bk0;
      float v1 = ckvn[tid + 512] + c_bk1;
      float v2 = ckvn[tid + 1024] + c_bk2;
      ckvn[tid] = v0; ckvn[tid + 512] = v1; ckvn[tid + 1024] = v2;
      int n = tid;
      C6[(size_t)(n >> 8) * slab + ((size_t)b * S_TOT + pos) * DMODEL + (n & 255)] = __float2bfloat16(v0);
      n = tid + 512;
      C6[(size_t)(n >> 8) * slab + ((size_t)b * S_TOT + pos) * DMODEL + (n & 255)] = __float2bfloat16(v1);
      n = tid + 1024;
      C6[(size_t)(n >> 8) * slab + ((size_t)b * S_TOT + pos) * DMODEL + (n & 255)] = __float2bfloat16(v2);
      SYNC();
    }

#pragma unroll
    for (int l = 0; l < LAYERS; l++) {
      // a. QKV (12/wave), input xh -> raw q/kn/vn
      gemv(g, 12, 1, (const uint4*)xh, [&](int col, float a) {
        if (col < 256) q[col] = a;
        else if (col < 512) kn[col - 256] = a;
        else vn[col - 512] = a;
      });
      SYNC();
      {
        if (tid < 256) q[tid] += bq0[l];
        else {
          float v2 = kn[tid - 256] + bq0[l];
          kn[tid - 256] = v2;
          Ksa[(size_t)l * slab + ((size_t)b * S_TOT + pos) * DMODEL + (tid - 256)] = __float2bfloat16(v2);
        }
        if (lo) {
          float v2 = vn[tid] + bq1[l];
          vn[tid] = v2;
          Vsa[(size_t)l * slab + ((size_t)b * S_TOT + pos) * DMODEL + tid] = __float2bfloat16(v2);
        }
        SYNC();
      }
      // b. SA attention
      attn8(Ksa + (size_t)l * slab, Vsa + (size_t)l * slab, kn, vn, pos);
      SYNC();
      // c. WO (4/wave), input atth
      gemv(g, 4, 1, (const uint4*)atth, [&](int col, float a) { pred[col] = a; });
      SYNC();
      ln_store(lo ? (x[tid] + pred[tid] + bso[l]) : 0.f, w1[l], bb1[l], x, xh);
      // d. CAQ (4/wave), input xh
      gemv(g, 4, 1, (const uint4*)xh, [&](int col, float a) { pred[col] = a; });
      SYNC();
      if (lo) q[tid] = pred[tid] + bcq[l];
      SYNC();
      // e. CA attention
      attn8(C6 + (size_t)(2 * l) * slab, C6 + (size_t)(2 * l + 1) * slab,
            ckvn + l * 512, ckvn + l * 512 + 256, pos);
      SYNC();
      // f. CAO (4/wave), input atth
      gemv(g, 4, 1, (const uint4*)atth, [&](int col, float a) { pred[col] = a; });
      SYNC();
      ln_store(lo ? (x[tid] + pred[tid] + bco[l]) : 0.f, w2[l], bb2[l], x, xh);
      // g. FF1 (16/wave), input xh -> raw hbuf
      gemv(g, 16, 1, (const uint4*)xh, [&](int col, float a) { hbuf[col] = a; });
      SYNC();
      {
        float g0 = gelu_f(hbuf[tid] + bf10[l]);
        float g1 = gelu_f(hbuf[tid + 512] + bf11[l]);
        float o0 = __shfl_xor(g0, 1, 64), o1 = __shfl_xor(g1, 1, 64);
        if (!(tid & 1)) {
          hh[tid >> 1] = pk2(g0, o0);
          hh[(tid + 512) >> 1] = pk2(g1, o1);
        }
        SYNC();
      }
      // h. FF2 (4 col-groups x 4 K-chunks/wave), input hh
      gemv(g, 4, 4, (const uint4*)hh, [&](int col, float a) { pred[col] = a; });
      SYNC();
      ln_store(lo ? (x[tid] + pred[tid] + bf2[l]) : 0.f, w3[l], bb3[l], x, xh);
    }

    // readout (register out_W)
    {
      const int ll = tid & 63;
      if (tid < 128) {
        const int d0 = tid >> 6;
        float p = 0.f;
#pragma unroll
        for (int j = 0; j < 4; j++) p += x[ll + 64 * j] * c_ow[j];
        p = wave_sum64(p);
        if (ll == 0) {
          const float nd = p + c_ob;
          ndc[d0] = nd;
          const float c = ndc[2 + d0] + nd;
          ndc[2 + d0] = c;
          out[((size_t)b * FUT_N + s) * 2 + d0] = c;
        }
      }
      SYNC();
    }
  }
  asm volatile("s_waitcnt vmcnt(0)" ::: "memory");
}

// ======================= host launch =======================
extern "C" void kernel_launch(void* const* d_in, const int* in_sizes, int n_in,
                              void* d_out, int out_size, void* d_ws, size_t ws_size,
                              hipStream_t stream)
{
  const float* past    = (const float*)d_in[0];
  const float* in_W    = (const float*)d_in[1];
  const float* in_b    = (const float*)d_in[2];
  const float* pos_emb = (const float*)d_in[3];
  const float* ln0_w   = (const float*)d_in[4];
  const float* ln0_b   = (const float*)d_in[5];
  const float* sa_Wqkv = (const float*)d_in[6];
  const float* sa_bqkv = (const float*)d_in[7];
  const float* sa_Wo   = (const float*)d_in[8];
  const float* sa_bo   = (const float*)d_in[9];
  const float* ca_Wqkv = (const float*)d_in[10];
  const float* ca_bqkv = (const float*)d_in[11];
  const float* ca_Wo   = (const float*)d_in[12];
  const float* ca_bo   = (const float*)d_in[13];
  const float* ff1_W   = (const float*)d_in[14];
  const float* ff1_b   = (const float*)d_in[15];
  const float* ff2_W   = (const float*)d_in[16];
  const float* ff2_b   = (const float*)d_in[17];
  const float* ln1_w   = (const float*)d_in[18];
  const float* ln1_b   = (const float*)d_in[19];
  const float* ln2_w   = (const float*)d_in[20];
  const float* ln2_b   = (const float*)d_in[21];
  const float* ln3_w   = (const float*)d_in[22];
  const float* ln3_b   = (const float*)d_in[23];
  const float* out_W   = (const float*)d_in[24];
  const float* out_b   = (const float*)d_in[25];
  float* out = (float*)d_out;

  const size_t Mpre = (size_t)BATCH * PAST_N;              // 6400
  const size_t slab = (size_t)BATCH * S_TOT * DMODEL;      // 2,293,760

  float* ws_f = (float*)d_ws;
  float* A    = ws_f;
  float* Bb   = A + Mpre * DMODEL;
  float* qb   = Bb + Mpre * DMODEL;
  float* at   = qb + Mpre * DMODEL;
  float* hb   = at + Mpre * DMODEL;
  float* Wckv = hb + Mpre * FFD;
  float* bckv = Wckv + (size_t)1536 * 256;
  float* ndb  = bckv + 1536;
  float* cur  = ndb + 256;
  __hip_bfloat16* Ksa = (__hip_bfloat16*)(cur + 256);
  __hip_bfloat16* Vsa = Ksa + 3 * slab;
  __hip_bfloat16* C6  = Vsa + 3 * slab;
  // stream aliases A (6.29MB needed, A region is 6.55MB; dead after prefill)
  uint4* Wd = (uint4*)A;

  const size_t need = ((size_t)(C6 + 6 * slab) - (size_t)d_ws);
  if (ws_size < need) return;

  auto layer = [&](int l, int M, int rpb, int pbase) {
    const float* Wqkv = sa_Wqkv + (size_t)l * 768 * 256;
    __hip_bfloat16* kcl = Ksa + (size_t)l * slab;
    __hip_bfloat16* vcl = Vsa + (size_t)l * slab;
    k_gemm<<<dim3(768 / BN, M / BM), 256, 0, stream>>>(
        A, Wqkv, sa_bqkv + l * 768, nullptr, nullptr, M, 768, 256, 0, 1,
        qb, kcl, vcl, nullptr, rpb, pbase);
    k_attn<<<M * HEADS, 64, 0, stream>>>(qb, kcl, vcl, at, rpb, pbase);
    k_gemm<<<dim3(256 / BN, M / BM), 256, 0, stream>>>(
        at, sa_Wo + (size_t)l * 65536, sa_bo + l * 256, A, Bb, M, 256, 256, 0, 0,
        nullptr, nullptr, nullptr, nullptr, 1, 0);
    k_ln<<<M, 256, 0, stream>>>(Bb, ln1_w + l * 256, ln1_b + l * 256, A);
    k_gemm<<<dim3(256 / BN, M / BM), 256, 0, stream>>>(
        A, ca_Wqkv + (size_t)l * 768 * 256, ca_bqkv + l * 768, nullptr, qb,
        M, 256, 256, 0, 0, nullptr, nullptr, nullptr, nullptr, 1, 0);
    k_attn<<<M * HEADS, 64, 0, stream>>>(
        qb, C6 + (size_t)(2 * l) * slab, C6 + (size_t)(2 * l + 1) * slab, at, rpb, pbase);
    k_gemm<<<dim3(256 / BN, M / BM), 256, 0, stream>>>(
        at, ca_Wo + (size_t)l * 65536, ca_bo + l * 256, A, Bb, M, 256, 256, 0, 0,
        nullptr, nullptr, nullptr, nullptr, 1, 0);
    k_ln<<<M, 256, 0, stream>>>(Bb, ln2_w + l * 256, ln2_b + l * 256, A);
    k_gemm<<<dim3(FFD / BN, M / BM), 256, 0, stream>>>(
        A, ff1_W + (size_t)l * FFD * 256, ff1_b + l * FFD, nullptr, hb,
        M, FFD, 256, 1, 0, nullptr, nullptr, nullptr, nullptr, 1, 0);
    k_gemm<<<dim3(256 / BN, M / BM), 256, 0, stream>>>(
        hb, ff2_W + (size_t)l * 256 * FFD, ff2_b + l * 256, A, Bb, M, 256, FFD, 0, 0,
        nullptr, nullptr, nullptr, nullptr, 1, 0);
    k_ln<<<M, 256, 0, stream>>>(Bb, ln3_w + l * 256, ln3_b + l * 256, A);
  };

  // ---- prefill over past 50 positions ----
  k_prepack<<<1536, 256, 0, stream>>>(ca_Wqkv, ca_bqkv, Wckv, bckv);
  k_embed<<<(int)Mpre, 256, 0, stream>>>(past, in_W, in_b, pos_emb, ln0_w, ln0_b, A);
  k_gemm<<<dim3(1536 / BN, (int)Mpre / BM), 256, 0, stream>>>(
      A, Wckv, bckv, nullptr, nullptr, (int)Mpre, 1536, 256, 0, 2,
      nullptr, nullptr, nullptr, C6, PAST_N, 0);
  for (int l = 0; l < LAYERS; l++) layer(l, (int)Mpre, PAST_N, 0);
  k_readout<<<BATCH, 64, 0, stream>>>(A, out_W, out_b, past, cur, ndb, out, PAST_N, 0, 1);

  // ---- pack decode weight stream (into A scratch, dead after prefill) ----
  k_pack_stream<<<(TOTAL_ENT + 255) / 256, 256, 0, stream>>>(
      sa_Wqkv, sa_Wo, ca_Wqkv, ca_Wo, ff1_W, ff2_W, Wd);

  // ---- fused 19-step decode: one WG per batch element ----
  k_decode<<<BATCH, NT, 0, stream>>>(
      Wd, bckv, in_W, in_b, pos_emb, ln0_w, ln0_b,
      sa_bqkv, sa_bo, ca_bqkv, ca_bo, ff1_b, ff2_b,
      ln1_w, ln1_b, ln2_w, ln2_b, ln3_w, ln3_b,
      out_W, out_b, Ksa, Vsa, C6, ndb, cur, out);
}

// Round 10
// 3516.961 us; speedup vs baseline: 4.5762x; 1.2579x over previous
//
#include <hip/hip_runtime.h>
#include <hip/hip_bf16.h>

#define DMODEL 256
#define S_TOT  70
#define BATCH  128
#define HEADS  8
#define DHEAD  32
#define PAST_N 50
#define FUT_N  20
#define LAYERS 3
#define FFD    1024

#define NT 512
// ---- decode weight stream: per-wave sub-tile sequences. Sub-tile = 256 uint4
// (4KB). Entry e = j*64 + l holds W[k8=(l>>3)*4+j][col c=l&7] as 8 f16 —
// lane l reads S[j*64+l]: LINEAR (bank-conflict-free). Per wave per step 192
// sub-tiles: CKV 24, per layer [QKV 12 | WO 4 | CAQ 4 | CAO 4 | FF1 16 | FF2 16].
#define SUBT_W   192
#define TOTAL_ENT (8 * SUBT_W * 256)

__device__ __forceinline__ float wave_sum64(float v) {
#pragma unroll
  for (int off = 32; off > 0; off >>= 1) v += __shfl_xor(v, off, 64);
  return v;
}
__device__ __forceinline__ float wave_max64(float v) {
#pragma unroll
  for (int off = 32; off > 0; off >>= 1) v = fmaxf(v, __shfl_xor(v, off, 64));
  return v;
}
__device__ __forceinline__ float gelu_f(float x) {
  return 0.5f * x * (1.0f + erff(x * 0.7071067811865476f));
}
__device__ __forceinline__ uint16_t f2bf(float v) {
  uint32_t b = __float_as_uint(v);
  return (uint16_t)((b + 0x7fffu + ((b >> 16) & 1u)) >> 16);
}
__device__ __forceinline__ float bl16(uint32_t w) { return __uint_as_float(w << 16); }
__device__ __forceinline__ float bh16(uint32_t w) { return __uint_as_float(w & 0xffff0000u); }
__device__ __forceinline__ uint16_t f2h(float v) {
  _Float16 h = (_Float16)v;
  return __builtin_bit_cast(uint16_t, h);
}
__device__ __forceinline__ uint32_t pk2(float lo_, float hi_) {
  return ((uint32_t)f2h(hi_) << 16) | (uint32_t)f2h(lo_);
}
__device__ __forceinline__ float fdot2a(uint32_t a, uint32_t b, float acc) {
  asm("v_dot2_f32_f16 %0, %1, %2, %0" : "+v"(acc) : "v"(a), "v"(b));
  return acc;
}

#define SYNC() do { __builtin_amdgcn_sched_barrier(0); \
  asm volatile("s_waitcnt lgkmcnt(0)" ::: "memory"); \
  __builtin_amdgcn_s_barrier(); \
  __builtin_amdgcn_sched_barrier(0); } while (0)
#define VMWAIT8() do { __builtin_amdgcn_sched_barrier(0); \
  asm volatile("s_waitcnt vmcnt(8)" ::: "memory"); \
  __builtin_amdgcn_sched_barrier(0); } while (0)

__device__ __forceinline__ void gld_lds16(const uint4* g, uint4* l) {
  __builtin_amdgcn_global_load_lds(
      (const __attribute__((address_space(1))) void*)g,
      (__attribute__((address_space(3))) void*)l, 16, 0, 0);
}

__device__ __forceinline__ float ln_norm_256(float x, float g, float b, float* sbuf, int tid) {
  float s = wave_sum64(x);
  if ((tid & 63) == 0) sbuf[tid >> 6] = s;
  __syncthreads();
  float mean = (sbuf[0] + sbuf[1] + sbuf[2] + sbuf[3]) * (1.0f / 256.0f);
  __syncthreads();
  float d = x - mean;
  float vs = wave_sum64(d * d);
  if ((tid & 63) == 0) sbuf[tid >> 6] = vs;
  __syncthreads();
  float var = (sbuf[0] + sbuf[1] + sbuf[2] + sbuf[3]) * (1.0f / 256.0f);
  return d * rsqrtf(var + 1e-5f) * g + b;
}

// ======================= MFMA bf16 prefill GEMM =======================
// tile 128(M) x 64(N), BK=64, 4 waves (each 32x64), double-buffered LDS,
// rows padded +8 bf16 (16B) -> benign bank pattern. fp32 in, bf16 MFMA, f32 acc.
#define LDK 72

__global__ __launch_bounds__(256) void k_gemm_mf(
    const float* __restrict__ A, const float* __restrict__ W,
    const float* __restrict__ bias, const float* __restrict__ Rres,
    float* __restrict__ C, int M, int N, int K, int act, int outmode,
    float* __restrict__ qout, __hip_bfloat16* __restrict__ kc,
    __hip_bfloat16* __restrict__ vc, __hip_bfloat16* __restrict__ c6,
    int rows_per_b, int pos_base)
{
  typedef __attribute__((ext_vector_type(8))) short bf8;
  typedef __attribute__((ext_vector_type(4))) float f4;
  __shared__ short Al[2][128 * LDK];
  __shared__ short Bl[2][64 * LDK];
  const int tid = threadIdx.x;
  const int wv = tid >> 6, lane = tid & 63;
  const int bm0 = blockIdx.y * 128, bn0 = blockIdx.x * 64;
  const int nkt = K >> 6;
  const int ar = tid >> 1, ah = (tid & 1) << 5;   // A stage: row, k-half(32)
  const int br = tid >> 2, bq = (tid & 3) << 4;   // B stage: n-row, k-quarter(16)

  f4 acc[2][4];
#pragma unroll
  for (int i = 0; i < 2; i++)
#pragma unroll
    for (int j = 0; j < 4; j++) acc[i][j] = (f4)0.f;

  auto stage = [&](int buf, int kt) {
    const int k0 = kt << 6;
    const float* ap = A + (size_t)(bm0 + ar) * K + k0 + ah;
    float4 av[8];
#pragma unroll
    for (int u = 0; u < 8; u++) av[u] = *(const float4*)(ap + 4 * u);
    const float* wp = W + (size_t)(bn0 + br) * K + k0 + bq;
    float4 wv4[4];
#pragma unroll
    for (int u = 0; u < 4; u++) wv4[u] = *(const float4*)(wp + 4 * u);
    short* ad = &Al[buf][ar * LDK + ah];
#pragma unroll
    for (int u = 0; u < 8; u++) {
      short4 sv = {(short)f2bf(av[u].x), (short)f2bf(av[u].y),
                   (short)f2bf(av[u].z), (short)f2bf(av[u].w)};
      *(short4*)(ad + 4 * u) = sv;
    }
    short* bd = &Bl[buf][br * LDK + bq];
#pragma unroll
    for (int u = 0; u < 4; u++) {
      short4 sv = {(short)f2bf(wv4[u].x), (short)f2bf(wv4[u].y),
                   (short)f2bf(wv4[u].z), (short)f2bf(wv4[u].w)};
      *(short4*)(bd + 4 * u) = sv;
    }
  };

  auto comp = [&](int buf) {
    const int am = wv * 32 + (lane & 15);
    const int bn = lane & 15;
    const int kb = (lane >> 4) * 8;
#pragma unroll
    for (int kk = 0; kk < 2; kk++) {
      const int ko = kk * 32 + kb;
      bf8 a0 = *(const bf8*)&Al[buf][am * LDK + ko];
      bf8 a1 = *(const bf8*)&Al[buf][(am + 16) * LDK + ko];
      bf8 b0 = *(const bf8*)&Bl[buf][bn * LDK + ko];
      bf8 b1 = *(const bf8*)&Bl[buf][(bn + 16) * LDK + ko];
      bf8 b2 = *(const bf8*)&Bl[buf][(bn + 32) * LDK + ko];
      bf8 b3 = *(const bf8*)&Bl[buf][(bn + 48) * LDK + ko];
      acc[0][0] = __builtin_amdgcn_mfma_f32_16x16x32_bf16(a0, b0, acc[0][0], 0, 0, 0);
      acc[0][1] = __builtin_amdgcn_mfma_f32_16x16x32_bf16(a0, b1, acc[0][1], 0, 0, 0);
      acc[0][2] = __builtin_amdgcn_mfma_f32_16x16x32_bf16(a0, b2, acc[0][2], 0, 0, 0);
      acc[0][3] = __builtin_amdgcn_mfma_f32_16x16x32_bf16(a0, b3, acc[0][3], 0, 0, 0);
      acc[1][0] = __builtin_amdgcn_mfma_f32_16x16x32_bf16(a1, b0, acc[1][0], 0, 0, 0);
      acc[1][1] = __builtin_amdgcn_mfma_f32_16x16x32_bf16(a1, b1, acc[1][1], 0, 0, 0);
      acc[1][2] = __builtin_amdgcn_mfma_f32_16x16x32_bf16(a1, b2, acc[1][2], 0, 0, 0);
      acc[1][3] = __builtin_amdgcn_mfma_f32_16x16x32_bf16(a1, b3, acc[1][3], 0, 0, 0);
    }
  };

  stage(0, 0);
  __syncthreads();
  for (int kt = 0; kt < nkt; kt++) {
    if (kt + 1 < nkt) stage((kt & 1) ^ 1, kt + 1);
    comp(kt & 1);
    __syncthreads();
  }

  // epilogue: C/D layout col=lane&15, row=(lane>>4)*4+reg
  const int n0 = bn0 + (lane & 15);
  const int r0 = bm0 + wv * 32 + (lane >> 4) * 4;
#pragma unroll
  for (int i = 0; i < 2; i++) {
#pragma unroll
    for (int r = 0; r < 4; r++) {
      const int row = r0 + i * 16 + r;
      const int b = row / rows_per_b;
      const int t = pos_base + row % rows_per_b;
#pragma unroll
      for (int j = 0; j < 4; j++) {
        const int n = n0 + j * 16;
        float v = acc[i][j][r] + bias[n];
        if (Rres) v += Rres[(size_t)row * N + n];
        if (act) v = gelu_f(v);
        if (outmode == 0) {
          C[(size_t)row * N + n] = v;
        } else if (outmode == 1) {
          if (n < 256) qout[(size_t)row * DMODEL + n] = v;
          else if (n < 512) kc[((size_t)b * S_TOT + t) * DMODEL + (n - 256)] = __float2bfloat16(v);
          else vc[((size_t)b * S_TOT + t) * DMODEL + (n - 512)] = __float2bfloat16(v);
        } else {
          const int j6 = n >> 8;
          c6[(size_t)j6 * ((size_t)BATCH * S_TOT * DMODEL) +
             ((size_t)b * S_TOT + t) * DMODEL + (n & 255)] = __float2bfloat16(v);
        }
      }
    }
  }
}

// ======================= other prefill kernels (unchanged) =================
__global__ __launch_bounds__(64) void k_attn(
    const float* __restrict__ qbuf, const __hip_bfloat16* __restrict__ kc,
    const __hip_bfloat16* __restrict__ vc, float* __restrict__ outb,
    int rows_per_b, int pos_base)
{
  __shared__ float qs[DHEAD];
  __shared__ float ss[S_TOT];
  const int bid = blockIdx.x;
  const int h = bid & (HEADS - 1);
  const int row = bid >> 3;
  const int b = row / rows_per_b;
  const int t = pos_base + row % rows_per_b;
  const int nk = t + 1;
  const int lane = threadIdx.x;
  if (lane < DHEAD) qs[lane] = qbuf[(size_t)row * DMODEL + h * DHEAD + lane];
  __syncthreads();
  float mx = -1e30f;
  for (int k0 = lane; k0 < nk; k0 += 64) {
    const __hip_bfloat16* kp = kc + ((size_t)b * S_TOT + k0) * DMODEL + h * DHEAD;
    float s = 0.f;
#pragma unroll
    for (int i = 0; i < DHEAD; i++) s += qs[i] * __bfloat162float(kp[i]);
    s *= 0.17677669529663687f;
    ss[k0] = s;
    mx = fmaxf(mx, s);
  }
  mx = wave_max64(mx);
  float sum = 0.f;
  for (int k0 = lane; k0 < nk; k0 += 64) {
    float e = expf(ss[k0] - mx);
    ss[k0] = e;
    sum += e;
  }
  sum = wave_sum64(sum);
  __syncthreads();
  const float inv = 1.0f / sum;
  if (lane < DHEAD) {
    float o = 0.f;
    for (int k0 = 0; k0 < nk; k0++)
      o += ss[k0] * __bfloat162float(vc[((size_t)b * S_TOT + k0) * DMODEL + h * DHEAD + lane]);
    outb[(size_t)row * DMODEL + h * DHEAD + lane] = o * inv;
  }
}

__global__ __launch_bounds__(256) void k_ln(
    const float* __restrict__ Z, const float* __restrict__ g,
    const float* __restrict__ b, float* __restrict__ out)
{
  __shared__ float sbuf[4];
  const int row = blockIdx.x, tid = threadIdx.x;
  float x = Z[(size_t)row * DMODEL + tid];
  out[(size_t)row * DMODEL + tid] = ln_norm_256(x, g[tid], b[tid], sbuf, tid);
}

__global__ __launch_bounds__(256) void k_embed(
    const float* __restrict__ past, const float* __restrict__ in_W,
    const float* __restrict__ in_b, const float* __restrict__ pos_emb,
    const float* __restrict__ ln_w, const float* __restrict__ ln_b,
    float* __restrict__ Aout)
{
  __shared__ float sbuf[4];
  const int rowid = blockIdx.x;
  const int b = rowid / PAST_N, t = rowid % PAST_N;
  const int tid = threadIdx.x;
  float dx = 0.f, dy = 0.f;
  if (t > 0) {
    dx = past[((size_t)b * PAST_N + t) * 2 + 0] - past[((size_t)b * PAST_N + t - 1) * 2 + 0];
    dy = past[((size_t)b * PAST_N + t) * 2 + 1] - past[((size_t)b * PAST_N + t - 1) * 2 + 1];
  }
  float v = in_W[tid * 2 + 0] * dx + in_W[tid * 2 + 1] * dy + in_b[tid] +
            pos_emb[(size_t)t * DMODEL + tid];
  Aout[(size_t)rowid * DMODEL + tid] = ln_norm_256(v, ln_w[tid], ln_b[tid], sbuf, tid);
}

__global__ __launch_bounds__(256) void k_prepack(
    const float* __restrict__ caW, const float* __restrict__ cab,
    float* __restrict__ Wckv, float* __restrict__ bckv)
{
  const int n = blockIdx.x, tid = threadIdx.x;
  const int j = n >> 8, dcol = n & 255;
  const int l = j >> 1, kv = j & 1;
  const int srow = l * 768 + 256 + kv * 256 + dcol;
  Wckv[(size_t)n * 256 + tid] = caW[(size_t)srow * 256 + tid];
  if (tid == 0) bckv[n] = cab[l * 768 + 256 + kv * 256 + dcol];
}

__global__ __launch_bounds__(64) void k_readout(
    const float* __restrict__ X, const float* __restrict__ out_W,
    const float* __restrict__ out_b, const float* __restrict__ past,
    float* __restrict__ cur, float* __restrict__ ndb, float* __restrict__ out,
    int rows_per_b, int s, int init)
{
  const int b = blockIdx.x, lane = threadIdx.x;
  const int row = b * rows_per_b + rows_per_b - 1;
  float p0 = 0.f, p1 = 0.f;
  for (int d = lane; d < DMODEL; d += 64) {
    const float xv = X[(size_t)row * DMODEL + d];
    p0 += xv * out_W[d];
    p1 += xv * out_W[DMODEL + d];
  }
  p0 = wave_sum64(p0);
  p1 = wave_sum64(p1);
  if (lane == 0) {
    const float nd0 = p0 + out_b[0];
    const float nd1 = p1 + out_b[1];
    float c0, c1;
    if (init) {
      c0 = past[((size_t)b * PAST_N + PAST_N - 1) * 2 + 0];
      c1 = past[((size_t)b * PAST_N + PAST_N - 1) * 2 + 1];
    } else {
      c0 = cur[b * 2 + 0];
      c1 = cur[b * 2 + 1];
    }
    c0 += nd0; c1 += nd1;
    cur[b * 2 + 0] = c0; cur[b * 2 + 1] = c1;
    ndb[b * 2 + 0] = nd0; ndb[b * 2 + 1] = nd1;
    out[((size_t)b * FUT_N + s) * 2 + 0] = c0;
    out[((size_t)b * FUT_N + s) * 2 + 1] = c1;
  }
}

// ======================= decode stream pack (conflict-free entry order) ====
__global__ __launch_bounds__(256) void k_pack_stream(
    const float* __restrict__ sa_Wqkv, const float* __restrict__ sa_Wo,
    const float* __restrict__ ca_Wqkv, const float* __restrict__ ca_Wo,
    const float* __restrict__ ff1_W, const float* __restrict__ ff2_W,
    uint4* __restrict__ Wd)
{
  const unsigned gidx = blockIdx.x * 256 + threadIdx.x;
  if (gidx >= TOTAL_ENT) return;
  const unsigned w = gidx / (SUBT_W * 256);
  const unsigned r = gidx % (SUBT_W * 256);
  const unsigned n = r >> 8, e = r & 255u;
  const int el = e & 63, ej = e >> 6;
  const int k8 = ((el >> 3) << 2) | ej;   // in-subtile k8 for lane el at step ej
  const int c = el & 7;
  const float* src;
  if (n < 24) {
    const int col = (int)(w * 8 + 64 * n + c);
    const int j6 = col >> 8, dcol = col & 255, lq = j6 >> 1, kv = j6 & 1;
    src = ca_Wqkv + (size_t)lq * 196608 + (size_t)(256 + kv * 256 + dcol) * 256 + 8 * k8;
  } else {
    const unsigned m = n - 24;
    const int l = m / 56, p = m % 56;
    if (p < 12)      { const int col = w * 8 + 64 * p + c;        src = sa_Wqkv + (size_t)l * 196608 + (size_t)col * 256 + 8 * k8; }
    else if (p < 16) { const int col = w * 8 + 64 * (p - 12) + c; src = sa_Wo   + (size_t)l * 65536  + (size_t)col * 256 + 8 * k8; }
    else if (p < 20) { const int col = w * 8 + 64 * (p - 16) + c; src = ca_Wqkv + (size_t)l * 196608 + (size_t)col * 256 + 8 * k8; }
    else if (p < 24) { const int col = w * 8 + 64 * (p - 20) + c; src = ca_Wo   + (size_t)l * 65536  + (size_t)col * 256 + 8 * k8; }
    else if (p < 40) { const int col = w * 8 + 64 * (p - 24) + c; src = ff1_W   + (size_t)l * 262144 + (size_t)col * 256 + 8 * k8; }
    else {
      const unsigned mm = p - 40;
      const int col = w * 8 + 64 * (mm >> 2) + c;
      const int kk8 = (int)(mm & 3) * 32 + k8;
      src = ff2_W + (size_t)l * 262144 + (size_t)col * 1024 + 8 * kk8;
    }
  }
  uint4 u;
  u.x = ((uint32_t)f2h(src[1]) << 16) | (uint32_t)f2h(src[0]);
  u.y = ((uint32_t)f2h(src[3]) << 16) | (uint32_t)f2h(src[2]);
  u.z = ((uint32_t)f2h(src[5]) << 16) | (uint32_t)f2h(src[4]);
  u.w = ((uint32_t)f2h(src[7]) << 16) | (uint32_t)f2h(src[6]);
  Wd[gidx] = u;
}

// ======================= fused 19-step decode =======================
__global__ __launch_bounds__(NT) void k_decode(
    const uint4* __restrict__ Wd, const float* __restrict__ bckv,
    const float* __restrict__ in_W, const float* __restrict__ in_b,
    const float* __restrict__ pos_emb,
    const float* __restrict__ ln0_w, const float* __restrict__ ln0_b,
    const float* __restrict__ sa_bqkv, const float* __restrict__ sa_bo,
    const float* __restrict__ ca_bqkv, const float* __restrict__ ca_bo,
    const float* __restrict__ ff1_b, const float* __restrict__ ff2_b,
    const float* __restrict__ ln1_w, const float* __restrict__ ln1_b,
    const float* __restrict__ ln2_w, const float* __restrict__ ln2_b,
    const float* __restrict__ ln3_w, const float* __restrict__ ln3_b,
    const float* __restrict__ out_W, const float* __restrict__ out_b,
    __hip_bfloat16* __restrict__ Ksa, __hip_bfloat16* __restrict__ Vsa,
    __hip_bfloat16* __restrict__ C6,
    const float* __restrict__ ndb, const float* __restrict__ cur,
    float* __restrict__ out)
{
  const int b = blockIdx.x;
  const int tid = threadIdx.x;
  const int wv = tid >> 6, lane = tid & 63;
  const int sv = (wv + b) & 7;   // stream slot: desync same-XCD CUs
  const size_t slab = (size_t)BATCH * S_TOT * DMODEL;

  __shared__ __align__(16) uint4 ring[8 * 4 * 256];   // 128 KB
  __shared__ __align__(16) float x[256];
  __shared__ __align__(16) float xt[256];
  __shared__ __align__(16) float q[256];
  __shared__ __align__(16) float hbuf[1024];
  __shared__ __align__(16) float pred[256];
  __shared__ __align__(16) float kn[256], vn[256];
  __shared__ __align__(16) float ckvn[1536];
  __shared__ __align__(16) uint32_t xh[128], xth[128], atth[128], hh[512];
  __shared__ float ss[8][72];
  __shared__ float sb[8], sb2[8];
  __shared__ float ndc[4];

  const bool lo = tid < 256;
  const float c_bk0 = bckv[tid], c_bk1 = bckv[tid + 512], c_bk2 = bckv[tid + 1024];
  float c_inW0 = 0.f, c_inW1 = 0.f, c_inb = 0.f, c_l0w = 0.f, c_l0b = 0.f;
  if (lo) {
    c_inW0 = in_W[2 * tid]; c_inW1 = in_W[2 * tid + 1]; c_inb = in_b[tid];
    c_l0w = ln0_w[tid];     c_l0b = ln0_b[tid];
  }
  float bq0[LAYERS], bq1[LAYERS], bso[LAYERS], bcq[LAYERS], bco[LAYERS];
  float bf10[LAYERS], bf11[LAYERS], bf2[LAYERS];
  float w1[LAYERS], bb1[LAYERS], w2[LAYERS], bb2[LAYERS], w3[LAYERS], bb3[LAYERS];
#pragma unroll
  for (int l = 0; l < LAYERS; l++) {
    bq0[l] = sa_bqkv[l * 768 + tid];
    bq1[l] = lo ? sa_bqkv[l * 768 + 512 + tid] : 0.f;
    bso[l] = lo ? sa_bo[l * 256 + tid] : 0.f;
    bcq[l] = lo ? ca_bqkv[l * 768 + tid] : 0.f;
    bco[l] = lo ? ca_bo[l * 256 + tid] : 0.f;
    bf10[l] = ff1_b[l * 1024 + tid];
    bf11[l] = ff1_b[l * 1024 + 512 + tid];
    bf2[l] = lo ? ff2_b[l * 256 + tid] : 0.f;
    w1[l] = lo ? ln1_w[l * 256 + tid] : 0.f;  bb1[l] = lo ? ln1_b[l * 256 + tid] : 0.f;
    w2[l] = lo ? ln2_w[l * 256 + tid] : 0.f;  bb2[l] = lo ? ln2_b[l * 256 + tid] : 0.f;
    w3[l] = lo ? ln3_w[l * 256 + tid] : 0.f;  bb3[l] = lo ? ln3_b[l * 256 + tid] : 0.f;
  }
  float c_ow[4] = {0.f, 0.f, 0.f, 0.f};
  float c_ob = 0.f;
  if (tid < 128) {
    const int d0 = tid >> 6, ll = tid & 63;
#pragma unroll
    for (int j = 0; j < 4; j++) c_ow[j] = out_W[d0 * 256 + ll + 64 * j];
    c_ob = out_b[d0];
  }
  if (tid == 0) {
    ndc[0] = ndb[2 * b];     ndc[1] = ndb[2 * b + 1];
    ndc[2] = cur[2 * b];     ndc[3] = cur[2 * b + 1];
  }
  asm volatile("s_waitcnt vmcnt(0)" ::: "memory");

  auto issue = [&](unsigned g) {
    const unsigned sidx = g % (unsigned)SUBT_W;
    const unsigned slot = g & 3u;
    const uint4* src = Wd + (((size_t)sv * SUBT_W + sidx) << 8) + lane;
    uint4* dst = &ring[(((unsigned)wv << 2) | slot) * 256u + (unsigned)lane];
#pragma unroll
    for (int j = 0; j < 4; j++) gld_lds16(src + (j << 6), dst + (j << 6));
  };

  // kch==1 GEMV: X hoisted to registers; W reads LINEAR (conflict-free)
  auto gemv1 = [&](unsigned& g, int cnt, const uint4* xp, auto&& emit) {
    const int kq = lane >> 3;
    const uint4 Xa = xp[kq * 4 + 0], Xb = xp[kq * 4 + 1];
    const uint4 Xc = xp[kq * 4 + 2], Xd = xp[kq * 4 + 3];
    for (int i = 0; i < cnt; i++) {
      VMWAIT8();
      issue(g + 3);
      const uint4* S = &ring[(((unsigned)wv << 2) | (g & 3u)) * 256u];
      const uint4 W0 = S[lane], W1 = S[64 + lane], W2 = S[128 + lane], W3 = S[192 + lane];
      float acc = 0.f;
      acc = fdot2a(W0.x, Xa.x, acc); acc = fdot2a(W0.y, Xa.y, acc);
      acc = fdot2a(W0.z, Xa.z, acc); acc = fdot2a(W0.w, Xa.w, acc);
      acc = fdot2a(W1.x, Xb.x, acc); acc = fdot2a(W1.y, Xb.y, acc);
      acc = fdot2a(W1.z, Xb.z, acc); acc = fdot2a(W1.w, Xb.w, acc);
      acc = fdot2a(W2.x, Xc.x, acc); acc = fdot2a(W2.y, Xc.y, acc);
      acc = fdot2a(W2.z, Xc.z, acc); acc = fdot2a(W2.w, Xc.w, acc);
      acc = fdot2a(W3.x, Xd.x, acc); acc = fdot2a(W3.y, Xd.y, acc);
      acc = fdot2a(W3.z, Xd.z, acc); acc = fdot2a(W3.w, Xd.w, acc);
      g++;
      acc += __shfl_xor(acc, 8, 64);
      acc += __shfl_xor(acc, 16, 64);
      acc += __shfl_xor(acc, 32, 64);
      if (lane < 8) emit((sv << 3) + (i << 6) + lane, acc);
    }
  };

  // FF2 GEMV: cnt=4 col-groups x kch=4 K-chunks
  auto gemv4 = [&](unsigned& g, const uint4* xp, auto&& emit) {
    const int kq = lane >> 3;
    for (int i = 0; i < 4; i++) {
      float acc = 0.f;
      for (int kc = 0; kc < 4; kc++) {
        const uint4 Xa = xp[kc * 32 + kq * 4 + 0], Xb = xp[kc * 32 + kq * 4 + 1];
        const uint4 Xc = xp[kc * 32 + kq * 4 + 2], Xd = xp[kc * 32 + kq * 4 + 3];
        VMWAIT8();
        issue(g + 3);
        const uint4* S = &ring[(((unsigned)wv << 2) | (g & 3u)) * 256u];
        const uint4 W0 = S[lane], W1 = S[64 + lane], W2 = S[128 + lane], W3 = S[192 + lane];
        acc = fdot2a(W0.x, Xa.x, acc); acc = fdot2a(W0.y, Xa.y, acc);
        acc = fdot2a(W0.z, Xa.z, acc); acc = fdot2a(W0.w, Xa.w, acc);
        acc = fdot2a(W1.x, Xb.x, acc); acc = fdot2a(W1.y, Xb.y, acc);
        acc = fdot2a(W1.z, Xb.z, acc); acc = fdot2a(W1.w, Xb.w, acc);
        acc = fdot2a(W2.x, Xc.x, acc); acc = fdot2a(W2.y, Xc.y, acc);
        acc = fdot2a(W2.z, Xc.z, acc); acc = fdot2a(W2.w, Xc.w, acc);
        acc = fdot2a(W3.x, Xd.x, acc); acc = fdot2a(W3.y, Xd.y, acc);
        acc = fdot2a(W3.z, Xd.z, acc); acc = fdot2a(W3.w, Xd.w, acc);
        g++;
      }
      acc += __shfl_xor(acc, 8, 64);
      acc += __shfl_xor(acc, 16, 64);
      acc += __shfl_xor(acc, 32, 64);
      if (lane < 8) emit((sv << 3) + (i << 6) + lane, acc);
    }
  };

  auto ln_store = [&](float v, float gw_, float gb_, float* dst, uint32_t* dsth) {
    float vv = lo ? v : 0.f;
    float s  = wave_sum64(vv);
    float s2 = wave_sum64(vv * vv);
    if ((tid & 63) == 0) { sb[tid >> 6] = s; sb2[tid >> 6] = s2; }
    SYNC();
    float mean = (sb[0] + sb[1] + sb[2] + sb[3]) * (1.0f / 256.0f);
    float ex2  = (sb2[0] + sb2[1] + sb2[2] + sb2[3]) * (1.0f / 256.0f);
    float var = ex2 - mean * mean;
    float vn_ = (vv - mean) * rsqrtf(var + 1e-5f) * gw_ + gb_;
    float vo = __shfl_xor(vn_, 1, 64);
    if (lo) {
      dst[tid] = vn_;
      if (!(tid & 1)) dsth[tid >> 1] = pk2(vn_, vo);
    }
    SYNC();
  };

  auto attn8 = [&](const __hip_bfloat16* Kc, const __hip_bfloat16* Vc,
                   const float* knw, const float* vnw, int pos) {
    const int h = wv;
    const float* qh = q + h * 32;
    float mx = -1e30f;
    for (int k0 = lane; k0 <= pos; k0 += 64) {
      float s = 0.f;
      if (k0 == pos) {
        const float* kp = knw + h * 32;
#pragma unroll
        for (int i = 0; i < 32; i++) s += qh[i] * kp[i];
      } else {
        const uint32_t* kp = (const uint32_t*)(Kc + ((size_t)b * S_TOT + k0) * DMODEL + h * 32);
#pragma unroll
        for (int i = 0; i < 16; i++) {
          uint32_t w = kp[i];
          s += bl16(w) * qh[2 * i];
          s += bh16(w) * qh[2 * i + 1];
        }
      }
      s *= 0.17677669529663687f;
      ss[h][k0] = s;
      mx = fmaxf(mx, s);
    }
    mx = wave_max64(mx);
    float sum = 0.f;
    for (int k0 = lane; k0 <= pos; k0 += 64) {
      float e = __expf(ss[h][k0] - mx);
      ss[h][k0] = e;
      sum += e;
    }
    sum = wave_sum64(sum);
    const float inv = 1.0f / sum;
    const int kpar = lane >> 4, d2 = lane & 15;
    const uint32_t* vbase = (const uint32_t*)(Vc + (size_t)b * S_TOT * DMODEL + h * 32) + d2;
    float oA = 0.f, oB = 0.f;
    for (int k0 = kpar; k0 < pos; k0 += 4) {
      const uint32_t w = vbase[(size_t)k0 * (DMODEL / 2)];
      const float p = ss[h][k0];
      oA += p * bl16(w);
      oB += p * bh16(w);
    }
    oA += __shfl_xor(oA, 16, 64); oA += __shfl_xor(oA, 32, 64);
    oB += __shfl_xor(oB, 16, 64); oB += __shfl_xor(oB, 32, 64);
    if (kpar == 0) {
      const float p = ss[h][pos];
      oA += p * vnw[h * 32 + 2 * d2];
      oB += p * vnw[h * 32 + 2 * d2 + 1];
      atth[h * 16 + d2] = pk2(oA * inv, oB * inv);
    }
  };

  unsigned g = 0;
  issue(0); issue(1); issue(2);

  for (int s = 1; s < FUT_N; s++) {
    const int pos = PAST_N - 1 + s;

    float xe = 0.f;
    if (lo) {
      xe = c_inW0 * ndc[0] + c_inW1 * ndc[1] + c_inb + pos_emb[(size_t)pos * DMODEL + tid];
    }
    ln_store(xe, c_l0w, c_l0b, xt, xth);
    if (lo) x[tid] = xt[tid];
    if (tid < 128) xh[tid] = xth[tid];

    // CKV (24/wave), input xth
    gemv1(g, 24, (const uint4*)xth, [&](int col, float a) { ckvn[col] = a; });
    SYNC();
    {
      float v0 = ckvn[tid] + c_bk0;
      float v1 = ckvn[tid + 512] + c_bk1;
      float v2 = ckvn[tid + 1024] + c_bk2;
      ckvn[tid] = v0; ckvn[tid + 512] = v1; ckvn[tid + 1024] = v2;
      int n = tid;
      C6[(size_t)(n >> 8) * slab + ((size_t)b * S_TOT + pos) * DMODEL + (n & 255)] = __float2bfloat16(v0);
      n = tid + 512;
      C6[(size_t)(n >> 8) * slab + ((size_t)b * S_TOT + pos) * DMODEL + (n & 255)] = __float2bfloat16(v1);
      n = tid + 1024;
      C6[(size_t)(n >> 8) * slab + ((size_t)b * S_TOT + pos) * DMODEL + (n & 255)] = __float2bfloat16(v2);
      SYNC();
    }

#pragma unroll
    for (int l = 0; l < LAYERS; l++) {
      // a. QKV (12/wave), input xh
      gemv1(g, 12, (const uint4*)xh, [&](int col, float a) {
        if (col < 256) q[col] = a;
        else if (col < 512) kn[col - 256] = a;
        else vn[col - 512] = a;
      });
      SYNC();
      {
        if (tid < 256) q[tid] += bq0[l];
        else {
          float v2 = kn[tid - 256] + bq0[l];
          kn[tid - 256] = v2;
          Ksa[(size_t)l * slab + ((size_t)b * S_TOT + pos) * DMODEL + (tid - 256)] = __float2bfloat16(v2);
        }
        if (lo) {
          float v2 = vn[tid] + bq1[l];
          vn[tid] = v2;
          Vsa[(size_t)l * slab + ((size_t)b * S_TOT + pos) * DMODEL + tid] = __float2bfloat16(v2);
        }
        SYNC();
      }
      // b. SA attention
      attn8(Ksa + (size_t)l * slab, Vsa + (size_t)l * slab, kn, vn, pos);
      SYNC();
      // c. WO (4/wave), input atth
      gemv1(g, 4, (const uint4*)atth, [&](int col, float a) { pred[col] = a; });
      SYNC();
      ln_store(lo ? (x[tid] + pred[tid] + bso[l]) : 0.f, w1[l], bb1[l], x, xh);
      // d. CAQ (4/wave), input xh
      gemv1(g, 4, (const uint4*)xh, [&](int col, float a) { pred[col] = a; });
      SYNC();
      if (lo) q[tid] = pred[tid] + bcq[l];
      SYNC();
      // e. CA attention
      attn8(C6 + (size_t)(2 * l) * slab, C6 + (size_t)(2 * l + 1) * slab,
            ckvn + l * 512, ckvn + l * 512 + 256, pos);
      SYNC();
      // f. CAO (4/wave), input atth
      gemv1(g, 4, (const uint4*)atth, [&](int col, float a) { pred[col] = a; });
      SYNC();
      ln_store(lo ? (x[tid] + pred[tid] + bco[l]) : 0.f, w2[l], bb2[l], x, xh);
      // g. FF1 (16/wave), input xh
      gemv1(g, 16, (const uint4*)xh, [&](int col, float a) { hbuf[col] = a; });
      SYNC();
      {
        float g0 = gelu_f(hbuf[tid] + bf10[l]);
        float g1 = gelu_f(hbuf[tid + 512] + bf11[l]);
        float o0 = __shfl_xor(g0, 1, 64), o1 = __shfl_xor(g1, 1, 64);
        if (!(tid & 1)) {
          hh[tid >> 1] = pk2(g0, o0);
          hh[(tid + 512) >> 1] = pk2(g1, o1);
        }
        SYNC();
      }
      // h. FF2 (4x4/wave), input hh
      gemv4(g, (const uint4*)hh, [&](int col, float a) { pred[col] = a; });
      SYNC();
      ln_store(lo ? (x[tid] + pred[tid] + bf2[l]) : 0.f, w3[l], bb3[l], x, xh);
    }

    // readout
    {
      const int ll = tid & 63;
      if (tid < 128) {
        const int d0 = tid >> 6;
        float p = 0.f;
#pragma unroll
        for (int j = 0; j < 4; j++) p += x[ll + 64 * j] * c_ow[j];
        p = wave_sum64(p);
        if (ll == 0) {
          const float nd = p + c_ob;
          ndc[d0] = nd;
          const float c = ndc[2 + d0] + nd;
          ndc[2 + d0] = c;
          out[((size_t)b * FUT_N + s) * 2 + d0] = c;
        }
      }
      SYNC();
    }
  }
  asm volatile("s_waitcnt vmcnt(0)" ::: "memory");
}

// ======================= host launch =======================
extern "C" void kernel_launch(void* const* d_in, const int* in_sizes, int n_in,
                              void* d_out, int out_size, void* d_ws, size_t ws_size,
                              hipStream_t stream)
{
  const float* past    = (const float*)d_in[0];
  const float* in_W    = (const float*)d_in[1];
  const float* in_b    = (const float*)d_in[2];
  const float* pos_emb = (const float*)d_in[3];
  const float* ln0_w   = (const float*)d_in[4];
  const float* ln0_b   = (const float*)d_in[5];
  const float* sa_Wqkv = (const float*)d_in[6];
  const float* sa_bqkv = (const float*)d_in[7];
  const float* sa_Wo   = (const float*)d_in[8];
  const float* sa_bo   = (const float*)d_in[9];
  const float* ca_Wqkv = (const float*)d_in[10];
  const float* ca_bqkv = (const float*)d_in[11];
  const float* ca_Wo   = (const float*)d_in[12];
  const float* ca_bo   = (const float*)d_in[13];
  const float* ff1_W   = (const float*)d_in[14];
  const float* ff1_b   = (const float*)d_in[15];
  const float* ff2_W   = (const float*)d_in[16];
  const float* ff2_b   = (const float*)d_in[17];
  const float* ln1_w   = (const float*)d_in[18];
  const float* ln1_b   = (const float*)d_in[19];
  const float* ln2_w   = (const float*)d_in[20];
  const float* ln2_b   = (const float*)d_in[21];
  const float* ln3_w   = (const float*)d_in[22];
  const float* ln3_b   = (const float*)d_in[23];
  const float* out_W   = (const float*)d_in[24];
  const float* out_b   = (const float*)d_in[25];
  float* out = (float*)d_out;

  const size_t Mpre = (size_t)BATCH * PAST_N;              // 6400
  const size_t slab = (size_t)BATCH * S_TOT * DMODEL;      // 2,293,760

  float* ws_f = (float*)d_ws;
  float* A    = ws_f;
  float* Bb   = A + Mpre * DMODEL;
  float* qb   = Bb + Mpre * DMODEL;
  float* at   = qb + Mpre * DMODEL;
  float* hb   = at + Mpre * DMODEL;
  float* Wckv = hb + Mpre * FFD;
  float* bckv = Wckv + (size_t)1536 * 256;
  float* ndb  = bckv + 1536;
  float* cur  = ndb + 256;
  __hip_bfloat16* Ksa = (__hip_bfloat16*)(cur + 256);
  __hip_bfloat16* Vsa = Ksa + 3 * slab;
  __hip_bfloat16* C6  = Vsa + 3 * slab;
  uint4* Wd = (uint4*)A;  // decode stream aliases A (dead after prefill)

  const size_t need = ((size_t)(C6 + 6 * slab) - (size_t)d_ws);
  if (ws_size < need) return;

  auto layer = [&](int l, int M, int rpb, int pbase) {
    const float* Wqkv = sa_Wqkv + (size_t)l * 768 * 256;
    __hip_bfloat16* kcl = Ksa + (size_t)l * slab;
    __hip_bfloat16* vcl = Vsa + (size_t)l * slab;
    k_gemm_mf<<<dim3(768 / 64, M / 128), 256, 0, stream>>>(
        A, Wqkv, sa_bqkv + l * 768, nullptr, nullptr, M, 768, 256, 0, 1,
        qb, kcl, vcl, nullptr, rpb, pbase);
    k_attn<<<M * HEADS, 64, 0, stream>>>(qb, kcl, vcl, at, rpb, pbase);
    k_gemm_mf<<<dim3(256 / 64, M / 128), 256, 0, stream>>>(
        at, sa_Wo + (size_t)l * 65536, sa_bo + l * 256, A, Bb, M, 256, 256, 0, 0,
        nullptr, nullptr, nullptr, nullptr, 1, 0);
    k_ln<<<M, 256, 0, stream>>>(Bb, ln1_w + l * 256, ln1_b + l * 256, A);
    k_gemm_mf<<<dim3(256 / 64, M / 128), 256, 0, stream>>>(
        A, ca_Wqkv + (size_t)l * 768 * 256, ca_bqkv + l * 768, nullptr, qb,
        M, 256, 256, 0, 0, nullptr, nullptr, nullptr, nullptr, 1, 0);
    k_attn<<<M * HEADS, 64, 0, stream>>>(
        qb, C6 + (size_t)(2 * l) * slab, C6 + (size_t)(2 * l + 1) * slab, at, rpb, pbase);
    k_gemm_mf<<<dim3(256 / 64, M / 128), 256, 0, stream>>>(
        at, ca_Wo + (size_t)l * 65536, ca_bo + l * 256, A, Bb, M, 256, 256, 0, 0,
        nullptr, nullptr, nullptr, nullptr, 1, 0);
    k_ln<<<M, 256, 0, stream>>>(Bb, ln2_w + l * 256, ln2_b + l * 256, A);
    k_gemm_mf<<<dim3(FFD / 64, M / 128), 256, 0, stream>>>(
        A, ff1_W + (size_t)l * FFD * 256, ff1_b + l * FFD, nullptr, hb,
        M, FFD, 256, 1, 0, nullptr, nullptr, nullptr, nullptr, 1, 0);
    k_gemm_mf<<<dim3(256 / 64, M / 128), 256, 0, stream>>>(
        hb, ff2_W + (size_t)l * 256 * FFD, ff2_b + l * 256, A, Bb, M, 256, FFD, 0, 0,
        nullptr, nullptr, nullptr, nullptr, 1, 0);
    k_ln<<<M, 256, 0, stream>>>(Bb, ln3_w + l * 256, ln3_b + l * 256, A);
  };

  // ---- prefill over past 50 positions ----
  k_prepack<<<1536, 256, 0, stream>>>(ca_Wqkv, ca_bqkv, Wckv, bckv);
  k_embed<<<(int)Mpre, 256, 0, stream>>>(past, in_W, in_b, pos_emb, ln0_w, ln0_b, A);
  k_gemm_mf<<<dim3(1536 / 64, (int)Mpre / 128), 256, 0, stream>>>(
      A, Wckv, bckv, nullptr, nullptr, (int)Mpre, 1536, 256, 0, 2,
      nullptr, nullptr, nullptr, C6, PAST_N, 0);
  for (int l = 0; l < LAYERS; l++) layer(l, (int)Mpre, PAST_N, 0);
  k_readout<<<BATCH, 64, 0, stream>>>(A, out_W, out_b, past, cur, ndb, out, PAST_N, 0, 1);

  // ---- pack decode weight stream (into A scratch, dead after prefill) ----
  k_pack_stream<<<(TOTAL_ENT + 255) / 256, 256, 0, stream>>>(
      sa_Wqkv, sa_Wo, ca_Wqkv, ca_Wo, ff1_W, ff2_W, Wd);

  // ---- fused 19-step decode: one WG per batch element ----
  k_decode<<<BATCH, NT, 0, stream>>>(
      Wd, bckv, in_W, in_b, pos_emb, ln0_w, ln0_b,
      sa_bqkv, sa_bo, ca_bqkv, ca_bo, ff1_b, ff2_b,
      ln1_w, ln1_b, ln2_w, ln2_b, ln3_w, ln3_b,
      out_W, out_b, Ksa, Vsa, C6, ndb, cur, out);
}

// Round 11
// 3439.753 us; speedup vs baseline: 4.6789x; 1.0224x over previous
//
#include <hip/hip_runtime.h>
#include <hip/hip_bf16.h>

#define DMODEL 256
#define S_TOT  70
#define BATCH  128
#define HEADS  8
#define DHEAD  32
#define PAST_N 50
#define FUT_N  20
#define LAYERS 3
#define FFD    1024

#define NT 512
// ---- decode weight stream: per-wave sub-tile sequences. Sub-tile = 256 uint4
// (4KB) = 32 cols x 8 k8-groups; entry e = kh*128 + j*32 + col holds
// W[k8 = base + kh*4 + j][colbase + col] (8 f16). Lane owns a column ->
// register accumulate, ONE shfl_xor(32) per block (no per-subtile reduce).
// Per wave per step 192 sub-tiles: CKV 6blk*4, per layer [QKV 3*4 | WO 4 |
// CAQ 4 | CAO 4 | FF1 4*4 | FF2 1*16].
#define SUBT_W   192
#define TOTAL_ENT (8 * SUBT_W * 256)

__device__ __forceinline__ float wave_sum64(float v) {
#pragma unroll
  for (int off = 32; off > 0; off >>= 1) v += __shfl_xor(v, off, 64);
  return v;
}
__device__ __forceinline__ float wave_max64(float v) {
#pragma unroll
  for (int off = 32; off > 0; off >>= 1) v = fmaxf(v, __shfl_xor(v, off, 64));
  return v;
}
__device__ __forceinline__ float gelu_f(float x) {
  return 0.5f * x * (1.0f + erff(x * 0.7071067811865476f));
}
__device__ __forceinline__ uint16_t f2bf(float v) {
  uint32_t b = __float_as_uint(v);
  return (uint16_t)((b + 0x7fffu + ((b >> 16) & 1u)) >> 16);
}
__device__ __forceinline__ float bl16(uint32_t w) { return __uint_as_float(w << 16); }
__device__ __forceinline__ float bh16(uint32_t w) { return __uint_as_float(w & 0xffff0000u); }
__device__ __forceinline__ uint16_t f2h(float v) {
  _Float16 h = (_Float16)v;
  return __builtin_bit_cast(uint16_t, h);
}
__device__ __forceinline__ uint32_t pk2(float lo_, float hi_) {
  return ((uint32_t)f2h(hi_) << 16) | (uint32_t)f2h(lo_);
}
__device__ __forceinline__ float fdot2a(uint32_t a, uint32_t b, float acc) {
  asm("v_dot2_f32_f16 %0, %1, %2, %0" : "+v"(acc) : "v"(a), "v"(b));
  return acc;
}

#define SYNC() do { __builtin_amdgcn_sched_barrier(0); \
  asm volatile("s_waitcnt lgkmcnt(0)" ::: "memory"); \
  __builtin_amdgcn_s_barrier(); \
  __builtin_amdgcn_sched_barrier(0); } while (0)
#define VMWAIT8() do { __builtin_amdgcn_sched_barrier(0); \
  asm volatile("s_waitcnt vmcnt(8)" ::: "memory"); \
  __builtin_amdgcn_sched_barrier(0); } while (0)

__device__ __forceinline__ void gld_lds16(const uint4* g, uint4* l) {
  __builtin_amdgcn_global_load_lds(
      (const __attribute__((address_space(1))) void*)g,
      (__attribute__((address_space(3))) void*)l, 16, 0, 0);
}

__device__ __forceinline__ float ln_norm_256(float x, float g, float b, float* sbuf, int tid) {
  float s = wave_sum64(x);
  if ((tid & 63) == 0) sbuf[tid >> 6] = s;
  __syncthreads();
  float mean = (sbuf[0] + sbuf[1] + sbuf[2] + sbuf[3]) * (1.0f / 256.0f);
  __syncthreads();
  float d = x - mean;
  float vs = wave_sum64(d * d);
  if ((tid & 63) == 0) sbuf[tid >> 6] = vs;
  __syncthreads();
  float var = (sbuf[0] + sbuf[1] + sbuf[2] + sbuf[3]) * (1.0f / 256.0f);
  return d * rsqrtf(var + 1e-5f) * g + b;
}

// ======================= MFMA bf16 prefill GEMM =======================
#define LDK 72

__global__ __launch_bounds__(256) void k_gemm_mf(
    const float* __restrict__ A, const float* __restrict__ W,
    const float* __restrict__ bias, const float* __restrict__ Rres,
    float* __restrict__ C, int M, int N, int K, int act, int outmode,
    float* __restrict__ qout, __hip_bfloat16* __restrict__ kc,
    __hip_bfloat16* __restrict__ vc, __hip_bfloat16* __restrict__ c6,
    int rows_per_b, int pos_base)
{
  typedef __attribute__((ext_vector_type(8))) short bf8;
  typedef __attribute__((ext_vector_type(4))) float f4;
  __shared__ short Al[2][128 * LDK];
  __shared__ short Bl[2][64 * LDK];
  const int tid = threadIdx.x;
  const int wv = tid >> 6, lane = tid & 63;
  const int bm0 = blockIdx.y * 128, bn0 = blockIdx.x * 64;
  const int nkt = K >> 6;
  const int ar = tid >> 1, ah = (tid & 1) << 5;
  const int br = tid >> 2, bq = (tid & 3) << 4;

  f4 acc[2][4];
#pragma unroll
  for (int i = 0; i < 2; i++)
#pragma unroll
    for (int j = 0; j < 4; j++) acc[i][j] = (f4)0.f;

  auto stage = [&](int buf, int kt) {
    const int k0 = kt << 6;
    const float* ap = A + (size_t)(bm0 + ar) * K + k0 + ah;
    float4 av[8];
#pragma unroll
    for (int u = 0; u < 8; u++) av[u] = *(const float4*)(ap + 4 * u);
    const float* wp = W + (size_t)(bn0 + br) * K + k0 + bq;
    float4 wv4[4];
#pragma unroll
    for (int u = 0; u < 4; u++) wv4[u] = *(const float4*)(wp + 4 * u);
    short* ad = &Al[buf][ar * LDK + ah];
#pragma unroll
    for (int u = 0; u < 8; u++) {
      short4 sv = {(short)f2bf(av[u].x), (short)f2bf(av[u].y),
                   (short)f2bf(av[u].z), (short)f2bf(av[u].w)};
      *(short4*)(ad + 4 * u) = sv;
    }
    short* bd = &Bl[buf][br * LDK + bq];
#pragma unroll
    for (int u = 0; u < 4; u++) {
      short4 sv = {(short)f2bf(wv4[u].x), (short)f2bf(wv4[u].y),
                   (short)f2bf(wv4[u].z), (short)f2bf(wv4[u].w)};
      *(short4*)(bd + 4 * u) = sv;
    }
  };

  auto comp = [&](int buf) {
    const int am = wv * 32 + (lane & 15);
    const int bn = lane & 15;
    const int kb = (lane >> 4) * 8;
#pragma unroll
    for (int kk = 0; kk < 2; kk++) {
      const int ko = kk * 32 + kb;
      bf8 a0 = *(const bf8*)&Al[buf][am * LDK + ko];
      bf8 a1 = *(const bf8*)&Al[buf][(am + 16) * LDK + ko];
      bf8 b0 = *(const bf8*)&Bl[buf][bn * LDK + ko];
      bf8 b1 = *(const bf8*)&Bl[buf][(bn + 16) * LDK + ko];
      bf8 b2 = *(const bf8*)&Bl[buf][(bn + 32) * LDK + ko];
      bf8 b3 = *(const bf8*)&Bl[buf][(bn + 48) * LDK + ko];
      acc[0][0] = __builtin_amdgcn_mfma_f32_16x16x32_bf16(a0, b0, acc[0][0], 0, 0, 0);
      acc[0][1] = __builtin_amdgcn_mfma_f32_16x16x32_bf16(a0, b1, acc[0][1], 0, 0, 0);
      acc[0][2] = __builtin_amdgcn_mfma_f32_16x16x32_bf16(a0, b2, acc[0][2], 0, 0, 0);
      acc[0][3] = __builtin_amdgcn_mfma_f32_16x16x32_bf16(a0, b3, acc[0][3], 0, 0, 0);
      acc[1][0] = __builtin_amdgcn_mfma_f32_16x16x32_bf16(a1, b0, acc[1][0], 0, 0, 0);
      acc[1][1] = __builtin_amdgcn_mfma_f32_16x16x32_bf16(a1, b1, acc[1][1], 0, 0, 0);
      acc[1][2] = __builtin_amdgcn_mfma_f32_16x16x32_bf16(a1, b2, acc[1][2], 0, 0, 0);
      acc[1][3] = __builtin_amdgcn_mfma_f32_16x16x32_bf16(a1, b3, acc[1][3], 0, 0, 0);
    }
  };

  stage(0, 0);
  __syncthreads();
  for (int kt = 0; kt < nkt; kt++) {
    if (kt + 1 < nkt) stage((kt & 1) ^ 1, kt + 1);
    comp(kt & 1);
    __syncthreads();
  }

  const int n0 = bn0 + (lane & 15);
  const int r0 = bm0 + wv * 32 + (lane >> 4) * 4;
#pragma unroll
  for (int i = 0; i < 2; i++) {
#pragma unroll
    for (int r = 0; r < 4; r++) {
      const int row = r0 + i * 16 + r;
      const int b = row / rows_per_b;
      const int t = pos_base + row % rows_per_b;
#pragma unroll
      for (int j = 0; j < 4; j++) {
        const int n = n0 + j * 16;
        float v = acc[i][j][r] + bias[n];
        if (Rres) v += Rres[(size_t)row * N + n];
        if (act) v = gelu_f(v);
        if (outmode == 0) {
          C[(size_t)row * N + n] = v;
        } else if (outmode == 1) {
          if (n < 256) qout[(size_t)row * DMODEL + n] = v;
          else if (n < 512) kc[((size_t)b * S_TOT + t) * DMODEL + (n - 256)] = __float2bfloat16(v);
          else vc[((size_t)b * S_TOT + t) * DMODEL + (n - 512)] = __float2bfloat16(v);
        } else {
          const int j6 = n >> 8;
          c6[(size_t)j6 * ((size_t)BATCH * S_TOT * DMODEL) +
             ((size_t)b * S_TOT + t) * DMODEL + (n & 255)] = __float2bfloat16(v);
        }
      }
    }
  }
}

// ======================= other prefill kernels (unchanged) =================
__global__ __launch_bounds__(64) void k_attn(
    const float* __restrict__ qbuf, const __hip_bfloat16* __restrict__ kc,
    const __hip_bfloat16* __restrict__ vc, float* __restrict__ outb,
    int rows_per_b, int pos_base)
{
  __shared__ float qs[DHEAD];
  __shared__ float ss[S_TOT];
  const int bid = blockIdx.x;
  const int h = bid & (HEADS - 1);
  const int row = bid >> 3;
  const int b = row / rows_per_b;
  const int t = pos_base + row % rows_per_b;
  const int nk = t + 1;
  const int lane = threadIdx.x;
  if (lane < DHEAD) qs[lane] = qbuf[(size_t)row * DMODEL + h * DHEAD + lane];
  __syncthreads();
  float mx = -1e30f;
  for (int k0 = lane; k0 < nk; k0 += 64) {
    const __hip_bfloat16* kp = kc + ((size_t)b * S_TOT + k0) * DMODEL + h * DHEAD;
    float s = 0.f;
#pragma unroll
    for (int i = 0; i < DHEAD; i++) s += qs[i] * __bfloat162float(kp[i]);
    s *= 0.17677669529663687f;
    ss[k0] = s;
    mx = fmaxf(mx, s);
  }
  mx = wave_max64(mx);
  float sum = 0.f;
  for (int k0 = lane; k0 < nk; k0 += 64) {
    float e = expf(ss[k0] - mx);
    ss[k0] = e;
    sum += e;
  }
  sum = wave_sum64(sum);
  __syncthreads();
  const float inv = 1.0f / sum;
  if (lane < DHEAD) {
    float o = 0.f;
    for (int k0 = 0; k0 < nk; k0++)
      o += ss[k0] * __bfloat162float(vc[((size_t)b * S_TOT + k0) * DMODEL + h * DHEAD + lane]);
    outb[(size_t)row * DMODEL + h * DHEAD + lane] = o * inv;
  }
}

__global__ __launch_bounds__(256) void k_ln(
    const float* __restrict__ Z, const float* __restrict__ g,
    const float* __restrict__ b, float* __restrict__ out)
{
  __shared__ float sbuf[4];
  const int row = blockIdx.x, tid = threadIdx.x;
  float x = Z[(size_t)row * DMODEL + tid];
  out[(size_t)row * DMODEL + tid] = ln_norm_256(x, g[tid], b[tid], sbuf, tid);
}

__global__ __launch_bounds__(256) void k_embed(
    const float* __restrict__ past, const float* __restrict__ in_W,
    const float* __restrict__ in_b, const float* __restrict__ pos_emb,
    const float* __restrict__ ln_w, const float* __restrict__ ln_b,
    float* __restrict__ Aout)
{
  __shared__ float sbuf[4];
  const int rowid = blockIdx.x;
  const int b = rowid / PAST_N, t = rowid % PAST_N;
  const int tid = threadIdx.x;
  float dx = 0.f, dy = 0.f;
  if (t > 0) {
    dx = past[((size_t)b * PAST_N + t) * 2 + 0] - past[((size_t)b * PAST_N + t - 1) * 2 + 0];
    dy = past[((size_t)b * PAST_N + t) * 2 + 1] - past[((size_t)b * PAST_N + t - 1) * 2 + 1];
  }
  float v = in_W[tid * 2 + 0] * dx + in_W[tid * 2 + 1] * dy + in_b[tid] +
            pos_emb[(size_t)t * DMODEL + tid];
  Aout[(size_t)rowid * DMODEL + tid] = ln_norm_256(v, ln_w[tid], ln_b[tid], sbuf, tid);
}

__global__ __launch_bounds__(256) void k_prepack(
    const float* __restrict__ caW, const float* __restrict__ cab,
    float* __restrict__ Wckv, float* __restrict__ bckv)
{
  const int n = blockIdx.x, tid = threadIdx.x;
  const int j = n >> 8, dcol = n & 255;
  const int l = j >> 1, kv = j & 1;
  const int srow = l * 768 + 256 + kv * 256 + dcol;
  Wckv[(size_t)n * 256 + tid] = caW[(size_t)srow * 256 + tid];
  if (tid == 0) bckv[n] = cab[l * 768 + 256 + kv * 256 + dcol];
}

__global__ __launch_bounds__(64) void k_readout(
    const float* __restrict__ X, const float* __restrict__ out_W,
    const float* __restrict__ out_b, const float* __restrict__ past,
    float* __restrict__ cur, float* __restrict__ ndb, float* __restrict__ out,
    int rows_per_b, int s, int init)
{
  const int b = blockIdx.x, lane = threadIdx.x;
  const int row = b * rows_per_b + rows_per_b - 1;
  float p0 = 0.f, p1 = 0.f;
  for (int d = lane; d < DMODEL; d += 64) {
    const float xv = X[(size_t)row * DMODEL + d];
    p0 += xv * out_W[d];
    p1 += xv * out_W[DMODEL + d];
  }
  p0 = wave_sum64(p0);
  p1 = wave_sum64(p1);
  if (lane == 0) {
    const float nd0 = p0 + out_b[0];
    const float nd1 = p1 + out_b[1];
    float c0, c1;
    if (init) {
      c0 = past[((size_t)b * PAST_N + PAST_N - 1) * 2 + 0];
      c1 = past[((size_t)b * PAST_N + PAST_N - 1) * 2 + 1];
    } else {
      c0 = cur[b * 2 + 0];
      c1 = cur[b * 2 + 1];
    }
    c0 += nd0; c1 += nd1;
    cur[b * 2 + 0] = c0; cur[b * 2 + 1] = c1;
    ndb[b * 2 + 0] = nd0; ndb[b * 2 + 1] = nd1;
    out[((size_t)b * FUT_N + s) * 2 + 0] = c0;
    out[((size_t)b * FUT_N + s) * 2 + 1] = c1;
  }
}

// ======================= decode stream pack (col-per-lane layout) ==========
__global__ __launch_bounds__(256) void k_pack_stream(
    const float* __restrict__ sa_Wqkv, const float* __restrict__ sa_Wo,
    const float* __restrict__ ca_Wqkv, const float* __restrict__ ca_Wo,
    const float* __restrict__ ff1_W, const float* __restrict__ ff2_W,
    uint4* __restrict__ Wd)
{
  const unsigned gidx = blockIdx.x * 256 + threadIdx.x;
  if (gidx >= TOTAL_ENT) return;
  const unsigned w = gidx / (SUBT_W * 256);
  const unsigned r = gidx % (SUBT_W * 256);
  const unsigned n = r >> 8, e = r & 255u;
  const int kh = e >> 7, j = (e >> 5) & 3, c = e & 31;
  const int k8l = kh * 4 + j;   // k8 within sub-tile (0..7)
  const float* src;
  if (n < 24) {
    // CKV: 6 blocks x 4 subtiles; col = w*192 + blk*32 + c; k8 = st*8 + k8l
    const int blk = n >> 2, st = n & 3;
    const int col = (int)(w * 192 + blk * 32 + c);
    const int k8 = st * 8 + k8l;
    const int j6 = col >> 8, dcol = col & 255, lq = j6 >> 1, kv = j6 & 1;
    src = ca_Wqkv + (size_t)lq * 196608 + (size_t)(256 + kv * 256 + dcol) * 256 + 8 * k8;
  } else {
    const unsigned m = n - 24;
    const int l = m / 56, p = m % 56;
    if (p < 12) {          // QKV: 3 blocks x 4
      const int blk = p >> 2, st = p & 3;
      const int col = w * 96 + blk * 32 + c;
      const int k8 = st * 8 + k8l;
      src = sa_Wqkv + (size_t)l * 196608 + (size_t)col * 256 + 8 * k8;
    } else if (p < 16) {   // WO: 1 block x 4
      const int st = p - 12;
      const int col = w * 32 + c;
      const int k8 = st * 8 + k8l;
      src = sa_Wo + (size_t)l * 65536 + (size_t)col * 256 + 8 * k8;
    } else if (p < 20) {   // CAQ
      const int st = p - 16;
      const int col = w * 32 + c;
      const int k8 = st * 8 + k8l;
      src = ca_Wqkv + (size_t)l * 196608 + (size_t)col * 256 + 8 * k8;
    } else if (p < 24) {   // CAO
      const int st = p - 20;
      const int col = w * 32 + c;
      const int k8 = st * 8 + k8l;
      src = ca_Wo + (size_t)l * 65536 + (size_t)col * 256 + 8 * k8;
    } else if (p < 40) {   // FF1: 4 blocks x 4
      const int pp = p - 24;
      const int blk = pp >> 2, st = pp & 3;
      const int col = w * 128 + blk * 32 + c;
      const int k8 = st * 8 + k8l;
      src = ff1_W + (size_t)l * 262144 + (size_t)col * 256 + 8 * k8;
    } else {               // FF2: 1 block x 16 (K=1024)
      const int st = p - 40;
      const int col = w * 32 + c;
      const int k8 = st * 8 + k8l;
      src = ff2_W + (size_t)l * 262144 + (size_t)col * 1024 + 8 * k8;
    }
  }
  uint4 u;
  u.x = ((uint32_t)f2h(src[1]) << 16) | (uint32_t)f2h(src[0]);
  u.y = ((uint32_t)f2h(src[3]) << 16) | (uint32_t)f2h(src[2]);
  u.z = ((uint32_t)f2h(src[5]) << 16) | (uint32_t)f2h(src[4]);
  u.w = ((uint32_t)f2h(src[7]) << 16) | (uint32_t)f2h(src[6]);
  Wd[gidx] = u;
}

// ======================= fused 19-step decode =======================
__global__ __launch_bounds__(NT) void k_decode(
    const uint4* __restrict__ Wd, const float* __restrict__ bckv,
    const float* __restrict__ in_W, const float* __restrict__ in_b,
    const float* __restrict__ pos_emb,
    const float* __restrict__ ln0_w, const float* __restrict__ ln0_b,
    const float* __restrict__ sa_bqkv, const float* __restrict__ sa_bo,
    const float* __restrict__ ca_bqkv, const float* __restrict__ ca_bo,
    const float* __restrict__ ff1_b, const float* __restrict__ ff2_b,
    const float* __restrict__ ln1_w, const float* __restrict__ ln1_b,
    const float* __restrict__ ln2_w, const float* __restrict__ ln2_b,
    const float* __restrict__ ln3_w, const float* __restrict__ ln3_b,
    const float* __restrict__ out_W, const float* __restrict__ out_b,
    __hip_bfloat16* __restrict__ Ksa, __hip_bfloat16* __restrict__ Vsa,
    __hip_bfloat16* __restrict__ C6,
    const float* __restrict__ ndb, const float* __restrict__ cur,
    float* __restrict__ out)
{
  const int b = blockIdx.x;
  const int tid = threadIdx.x;
  const int wv = tid >> 6, lane = tid & 63;
  const int sv = (wv + b) & 7;   // stream slot: desync same-XCD CUs
  const size_t slab = (size_t)BATCH * S_TOT * DMODEL;

  __shared__ __align__(16) uint4 ring[8 * 4 * 256];   // 128 KB
  __shared__ __align__(16) float x[256];
  __shared__ __align__(16) float xt[256];
  __shared__ __align__(16) float q[256];
  __shared__ __align__(16) float hbuf[1024];
  __shared__ __align__(16) float pred[256];
  __shared__ __align__(16) float kn[256], vn[256];
  __shared__ __align__(16) float ckvn[1536];
  __shared__ __align__(16) uint32_t xh[128], xth[128], atth[128], hh[512];
  __shared__ float ss[8][72];
  __shared__ float sb[8], sb2[8];
  __shared__ float ndc[4];

  const bool lo = tid < 256;
  const float c_bk0 = bckv[tid], c_bk1 = bckv[tid + 512], c_bk2 = bckv[tid + 1024];
  float c_inW0 = 0.f, c_inW1 = 0.f, c_inb = 0.f, c_l0w = 0.f, c_l0b = 0.f;
  if (lo) {
    c_inW0 = in_W[2 * tid]; c_inW1 = in_W[2 * tid + 1]; c_inb = in_b[tid];
    c_l0w = ln0_w[tid];     c_l0b = ln0_b[tid];
  }
  float bq0[LAYERS], bq1[LAYERS], bso[LAYERS], bcq[LAYERS], bco[LAYERS];
  float bf10[LAYERS], bf11[LAYERS], bf2[LAYERS];
  float w1[LAYERS], bb1[LAYERS], w2[LAYERS], bb2[LAYERS], w3[LAYERS], bb3[LAYERS];
#pragma unroll
  for (int l = 0; l < LAYERS; l++) {
    bq0[l] = sa_bqkv[l * 768 + tid];
    bq1[l] = lo ? sa_bqkv[l * 768 + 512 + tid] : 0.f;
    bso[l] = lo ? sa_bo[l * 256 + tid] : 0.f;
    bcq[l] = lo ? ca_bqkv[l * 768 + tid] : 0.f;
    bco[l] = lo ? ca_bo[l * 256 + tid] : 0.f;
    bf10[l] = ff1_b[l * 1024 + tid];
    bf11[l] = ff1_b[l * 1024 + 512 + tid];
    bf2[l] = lo ? ff2_b[l * 256 + tid] : 0.f;
    w1[l] = lo ? ln1_w[l * 256 + tid] : 0.f;  bb1[l] = lo ? ln1_b[l * 256 + tid] : 0.f;
    w2[l] = lo ? ln2_w[l * 256 + tid] : 0.f;  bb2[l] = lo ? ln2_b[l * 256 + tid] : 0.f;
    w3[l] = lo ? ln3_w[l * 256 + tid] : 0.f;  bb3[l] = lo ? ln3_b[l * 256 + tid] : 0.f;
  }
  float c_ow[4] = {0.f, 0.f, 0.f, 0.f};
  float c_ob = 0.f;
  if (tid < 128) {
    const int d0 = tid >> 6, ll = tid & 63;
#pragma unroll
    for (int j = 0; j < 4; j++) c_ow[j] = out_W[d0 * 256 + ll + 64 * j];
    c_ob = out_b[d0];
  }
  if (tid == 0) {
    ndc[0] = ndb[2 * b];     ndc[1] = ndb[2 * b + 1];
    ndc[2] = cur[2 * b];     ndc[3] = cur[2 * b + 1];
  }
  asm volatile("s_waitcnt vmcnt(0)" ::: "memory");

  auto issue = [&](unsigned g) {
    const unsigned sidx = g % (unsigned)SUBT_W;
    const unsigned slot = g & 3u;
    const uint4* src = Wd + (((size_t)sv * SUBT_W + sidx) << 8) + lane;
    uint4* dst = &ring[(((unsigned)wv << 2) | slot) * 256u + (unsigned)lane];
#pragma unroll
    for (int j = 0; j < 4; j++) gld_lds16(src + (j << 6), dst + (j << 6));
  };

  // block GEMV: nblk column-blocks of 32, nst sub-tiles each (8 k8 per
  // sub-tile). Lane owns col (l&31); halves split K; ONE shfl per block.
  auto gemvB = [&](unsigned& g, int nblk, int nst, const uint4* xp, auto&& emit) {
    const int kh = lane >> 5, c = lane & 31;
    for (int bi = 0; bi < nblk; bi++) {
      float acc = 0.f;
      for (int st = 0; st < nst; st++) {
        VMWAIT8();
        issue(g + 3);
        const uint4* S = &ring[(((unsigned)wv << 2) | (g & 3u)) * 256u] + kh * 128 + c;
        const uint4 W0 = S[0], W1 = S[32], W2 = S[64], W3 = S[96];
        const int kb = st * 8 + kh * 4;
        const uint4 X0 = xp[kb], X1 = xp[kb + 1], X2 = xp[kb + 2], X3 = xp[kb + 3];
        acc = fdot2a(W0.x, X0.x, acc); acc = fdot2a(W0.y, X0.y, acc);
        acc = fdot2a(W0.z, X0.z, acc); acc = fdot2a(W0.w, X0.w, acc);
        acc = fdot2a(W1.x, X1.x, acc); acc = fdot2a(W1.y, X1.y, acc);
        acc = fdot2a(W1.z, X1.z, acc); acc = fdot2a(W1.w, X1.w, acc);
        acc = fdot2a(W2.x, X2.x, acc); acc = fdot2a(W2.y, X2.y, acc);
        acc = fdot2a(W2.z, X2.z, acc); acc = fdot2a(W2.w, X2.w, acc);
        acc = fdot2a(W3.x, X3.x, acc); acc = fdot2a(W3.y, X3.y, acc);
        acc = fdot2a(W3.z, X3.z, acc); acc = fdot2a(W3.w, X3.w, acc);
        g++;
      }
      acc += __shfl_xor(acc, 32, 64);
      if (lane < 32) emit(bi * 32 + c, acc);
    }
  };

  auto ln_store = [&](float v, float gw_, float gb_, float* dst, uint32_t* dsth) {
    float vv = lo ? v : 0.f;
    float s  = wave_sum64(vv);
    float s2 = wave_sum64(vv * vv);
    if ((tid & 63) == 0) { sb[tid >> 6] = s; sb2[tid >> 6] = s2; }
    SYNC();
    float mean = (sb[0] + sb[1] + sb[2] + sb[3]) * (1.0f / 256.0f);
    float ex2  = (sb2[0] + sb2[1] + sb2[2] + sb2[3]) * (1.0f / 256.0f);
    float var = ex2 - mean * mean;
    float vn_ = (vv - mean) * rsqrtf(var + 1e-5f) * gw_ + gb_;
    float vo = __shfl_xor(vn_, 1, 64);
    if (lo) {
      dst[tid] = vn_;
      if (!(tid & 1)) dsth[tid >> 1] = pk2(vn_, vo);
    }
    SYNC();
  };

  auto attn8 = [&](const __hip_bfloat16* Kc, const __hip_bfloat16* Vc,
                   const float* knw, const float* vnw, int pos) {
    const int h = wv;
    const float* qh = q + h * 32;
    float mx = -1e30f;
    for (int k0 = lane; k0 <= pos; k0 += 64) {
      float s = 0.f;
      if (k0 == pos) {
        const float* kp = knw + h * 32;
#pragma unroll
        for (int i = 0; i < 32; i++) s += qh[i] * kp[i];
      } else {
        const uint32_t* kp = (const uint32_t*)(Kc + ((size_t)b * S_TOT + k0) * DMODEL + h * 32);
#pragma unroll
        for (int i = 0; i < 16; i++) {
          uint32_t w = kp[i];
          s += bl16(w) * qh[2 * i];
          s += bh16(w) * qh[2 * i + 1];
        }
      }
      s *= 0.17677669529663687f;
      ss[h][k0] = s;
      mx = fmaxf(mx, s);
    }
    mx = wave_max64(mx);
    float sum = 0.f;
    for (int k0 = lane; k0 <= pos; k0 += 64) {
      float e = __expf(ss[h][k0] - mx);
      ss[h][k0] = e;
      sum += e;
    }
    sum = wave_sum64(sum);
    const float inv = 1.0f / sum;
    const int kpar = lane >> 4, d2 = lane & 15;
    const uint32_t* vbase = (const uint32_t*)(Vc + (size_t)b * S_TOT * DMODEL + h * 32) + d2;
    float oA = 0.f, oB = 0.f;
    for (int k0 = kpar; k0 < pos; k0 += 4) {
      const uint32_t w = vbase[(size_t)k0 * (DMODEL / 2)];
      const float p = ss[h][k0];
      oA += p * bl16(w);
      oB += p * bh16(w);
    }
    oA += __shfl_xor(oA, 16, 64); oA += __shfl_xor(oA, 32, 64);
    oB += __shfl_xor(oB, 16, 64); oB += __shfl_xor(oB, 32, 64);
    if (kpar == 0) {
      const float p = ss[h][pos];
      oA += p * vnw[h * 32 + 2 * d2];
      oB += p * vnw[h * 32 + 2 * d2 + 1];
      atth[h * 16 + d2] = pk2(oA * inv, oB * inv);
    }
  };

  unsigned g = 0;
  issue(0); issue(1); issue(2);

  for (int s = 1; s < FUT_N; s++) {
    const int pos = PAST_N - 1 + s;

    float xe = 0.f;
    if (lo) {
      xe = c_inW0 * ndc[0] + c_inW1 * ndc[1] + c_inb + pos_emb[(size_t)pos * DMODEL + tid];
    }
    ln_store(xe, c_l0w, c_l0b, xt, xth);
    if (lo) x[tid] = xt[tid];
    if (tid < 128) xh[tid] = xth[tid];

    // CKV: 6 blocks x 4, input xth; cols sv*192 + ...
    gemvB(g, 6, 4, (const uint4*)xth, [&](int cl, float a) { ckvn[sv * 192 + cl] = a; });
    SYNC();
    {
      float v0 = ckvn[tid] + c_bk0;
      float v1 = ckvn[tid + 512] + c_bk1;
      float v2 = ckvn[tid + 1024] + c_bk2;
      ckvn[tid] = v0; ckvn[tid + 512] = v1; ckvn[tid + 1024] = v2;
      int n = tid;
      C6[(size_t)(n >> 8) * slab + ((size_t)b * S_TOT + pos) * DMODEL + (n & 255)] = __float2bfloat16(v0);
      n = tid + 512;
      C6[(size_t)(n >> 8) * slab + ((size_t)b * S_TOT + pos) * DMODEL + (n & 255)] = __float2bfloat16(v1);
      n = tid + 1024;
      C6[(size_t)(n >> 8) * slab + ((size_t)b * S_TOT + pos) * DMODEL + (n & 255)] = __float2bfloat16(v2);
      SYNC();
    }

#pragma unroll
    for (int l = 0; l < LAYERS; l++) {
      // a. QKV: 3 blocks x 4, input xh; cols sv*96 + ...
      gemvB(g, 3, 4, (const uint4*)xh, [&](int cl, float a) {
        const int col = sv * 96 + cl;
        if (col < 256) q[col] = a;
        else if (col < 512) kn[col - 256] = a;
        else vn[col - 512] = a;
      });
      SYNC();
      {
        if (tid < 256) q[tid] += bq0[l];
        else {
          float v2 = kn[tid - 256] + bq0[l];
          kn[tid - 256] = v2;
          Ksa[(size_t)l * slab + ((size_t)b * S_TOT + pos) * DMODEL + (tid - 256)] = __float2bfloat16(v2);
        }
        if (lo) {
          float v2 = vn[tid] + bq1[l];
          vn[tid] = v2;
          Vsa[(size_t)l * slab + ((size_t)b * S_TOT + pos) * DMODEL + tid] = __float2bfloat16(v2);
        }
        SYNC();
      }
      // b. SA attention
      attn8(Ksa + (size_t)l * slab, Vsa + (size_t)l * slab, kn, vn, pos);
      SYNC();
      // c. WO: 1 block x 4, input atth
      gemvB(g, 1, 4, (const uint4*)atth, [&](int cl, float a) { pred[sv * 32 + cl] = a; });
      SYNC();
      ln_store(lo ? (x[tid] + pred[tid] + bso[l]) : 0.f, w1[l], bb1[l], x, xh);
      // d. CAQ: 1 block x 4, input xh
      gemvB(g, 1, 4, (const uint4*)xh, [&](int cl, float a) { pred[sv * 32 + cl] = a; });
      SYNC();
      if (lo) q[tid] = pred[tid] + bcq[l];
      SYNC();
      // e. CA attention
      attn8(C6 + (size_t)(2 * l) * slab, C6 + (size_t)(2 * l + 1) * slab,
            ckvn + l * 512, ckvn + l * 512 + 256, pos);
      SYNC();
      // f. CAO: 1 block x 4, input atth
      gemvB(g, 1, 4, (const uint4*)atth, [&](int cl, float a) { pred[sv * 32 + cl] = a; });
      SYNC();
      ln_store(lo ? (x[tid] + pred[tid] + bco[l]) : 0.f, w2[l], bb2[l], x, xh);
      // g. FF1: 4 blocks x 4, input xh; cols sv*128 + ...
      gemvB(g, 4, 4, (const uint4*)xh, [&](int cl, float a) { hbuf[sv * 128 + cl] = a; });
      SYNC();
      {
        float g0 = gelu_f(hbuf[tid] + bf10[l]);
        float g1 = gelu_f(hbuf[tid + 512] + bf11[l]);
        float o0 = __shfl_xor(g0, 1, 64), o1 = __shfl_xor(g1, 1, 64);
        if (!(tid & 1)) {
          hh[tid >> 1] = pk2(g0, o0);
          hh[(tid + 512) >> 1] = pk2(g1, o1);
        }
        SYNC();
      }
      // h. FF2: 1 block x 16 (K=1024), input hh
      gemvB(g, 1, 16, (const uint4*)hh, [&](int cl, float a) { pred[sv * 32 + cl] = a; });
      SYNC();
      ln_store(lo ? (x[tid] + pred[tid] + bf2[l]) : 0.f, w3[l], bb3[l], x, xh);
    }

    // readout
    {
      const int ll = tid & 63;
      if (tid < 128) {
        const int d0 = tid >> 6;
        float p = 0.f;
#pragma unroll
        for (int j = 0; j < 4; j++) p += x[ll + 64 * j] * c_ow[j];
        p = wave_sum64(p);
        if (ll == 0) {
          const float nd = p + c_ob;
          ndc[d0] = nd;
          const float c = ndc[2 + d0] + nd;
          ndc[2 + d0] = c;
          out[((size_t)b * FUT_N + s) * 2 + d0] = c;
        }
      }
      SYNC();
    }
  }
  asm volatile("s_waitcnt vmcnt(0)" ::: "memory");
}

// ======================= host launch =======================
extern "C" void kernel_launch(void* const* d_in, const int* in_sizes, int n_in,
                              void* d_out, int out_size, void* d_ws, size_t ws_size,
                              hipStream_t stream)
{
  const float* past    = (const float*)d_in[0];
  const float* in_W    = (const float*)d_in[1];
  const float* in_b    = (const float*)d_in[2];
  const float* pos_emb = (const float*)d_in[3];
  const float* ln0_w   = (const float*)d_in[4];
  const float* ln0_b   = (const float*)d_in[5];
  const float* sa_Wqkv = (const float*)d_in[6];
  const float* sa_bqkv = (const float*)d_in[7];
  const float* sa_Wo   = (const float*)d_in[8];
  const float* sa_bo   = (const float*)d_in[9];
  const float* ca_Wqkv = (const float*)d_in[10];
  const float* ca_bqkv = (const float*)d_in[11];
  const float* ca_Wo   = (const float*)d_in[12];
  const float* ca_bo   = (const float*)d_in[13];
  const float* ff1_W   = (const float*)d_in[14];
  const float* ff1_b   = (const float*)d_in[15];
  const float* ff2_W   = (const float*)d_in[16];
  const float* ff2_b   = (const float*)d_in[17];
  const float* ln1_w   = (const float*)d_in[18];
  const float* ln1_b   = (const float*)d_in[19];
  const float* ln2_w   = (const float*)d_in[20];
  const float* ln2_b   = (const float*)d_in[21];
  const float* ln3_w   = (const float*)d_in[22];
  const float* ln3_b   = (const float*)d_in[23];
  const float* out_W   = (const float*)d_in[24];
  const float* out_b   = (const float*)d_in[25];
  float* out = (float*)d_out;

  const size_t Mpre = (size_t)BATCH * PAST_N;              // 6400
  const size_t slab = (size_t)BATCH * S_TOT * DMODEL;      // 2,293,760

  float* ws_f = (float*)d_ws;
  float* A    = ws_f;
  float* Bb   = A + Mpre * DMODEL;
  float* qb   = Bb + Mpre * DMODEL;
  float* at   = qb + Mpre * DMODEL;
  float* hb   = at + Mpre * DMODEL;
  float* Wckv = hb + Mpre * FFD;
  float* bckv = Wckv + (size_t)1536 * 256;
  float* ndb  = bckv + 1536;
  float* cur  = ndb + 256;
  __hip_bfloat16* Ksa = (__hip_bfloat16*)(cur + 256);
  __hip_bfloat16* Vsa = Ksa + 3 * slab;
  __hip_bfloat16* C6  = Vsa + 3 * slab;
  uint4* Wd = (uint4*)A;  // decode stream aliases A (dead after prefill)

  const size_t need = ((size_t)(C6 + 6 * slab) - (size_t)d_ws);
  if (ws_size < need) return;

  auto layer = [&](int l, int M, int rpb, int pbase) {
    const float* Wqkv = sa_Wqkv + (size_t)l * 768 * 256;
    __hip_bfloat16* kcl = Ksa + (size_t)l * slab;
    __hip_bfloat16* vcl = Vsa + (size_t)l * slab;
    k_gemm_mf<<<dim3(768 / 64, M / 128), 256, 0, stream>>>(
        A, Wqkv, sa_bqkv + l * 768, nullptr, nullptr, M, 768, 256, 0, 1,
        qb, kcl, vcl, nullptr, rpb, pbase);
    k_attn<<<M * HEADS, 64, 0, stream>>>(qb, kcl, vcl, at, rpb, pbase);
    k_gemm_mf<<<dim3(256 / 64, M / 128), 256, 0, stream>>>(
        at, sa_Wo + (size_t)l * 65536, sa_bo + l * 256, A, Bb, M, 256, 256, 0, 0,
        nullptr, nullptr, nullptr, nullptr, 1, 0);
    k_ln<<<M, 256, 0, stream>>>(Bb, ln1_w + l * 256, ln1_b + l * 256, A);
    k_gemm_mf<<<dim3(256 / 64, M / 128), 256, 0, stream>>>(
        A, ca_Wqkv + (size_t)l * 768 * 256, ca_bqkv + l * 768, nullptr, qb,
        M, 256, 256, 0, 0, nullptr, nullptr, nullptr, nullptr, 1, 0);
    k_attn<<<M * HEADS, 64, 0, stream>>>(
        qb, C6 + (size_t)(2 * l) * slab, C6 + (size_t)(2 * l + 1) * slab, at, rpb, pbase);
    k_gemm_mf<<<dim3(256 / 64, M / 128), 256, 0, stream>>>(
        at, ca_Wo + (size_t)l * 65536, ca_bo + l * 256, A, Bb, M, 256, 256, 0, 0,
        nullptr, nullptr, nullptr, nullptr, 1, 0);
    k_ln<<<M, 256, 0, stream>>>(Bb, ln2_w + l * 256, ln2_b + l * 256, A);
    k_gemm_mf<<<dim3(FFD / 64, M / 128), 256, 0, stream>>>(
        A, ff1_W + (size_t)l * FFD * 256, ff1_b + l * FFD, nullptr, hb,
        M, FFD, 256, 1, 0, nullptr, nullptr, nullptr, nullptr, 1, 0);
    k_gemm_mf<<<dim3(256 / 64, M / 128), 256, 0, stream>>>(
        hb, ff2_W + (size_t)l * 256 * FFD, ff2_b + l * 256, A, Bb, M, 256, FFD, 0, 0,
        nullptr, nullptr, nullptr, nullptr, 1, 0);
    k_ln<<<M, 256, 0, stream>>>(Bb, ln3_w + l * 256, ln3_b + l * 256, A);
  };

  // ---- prefill over past 50 positions ----
  k_prepack<<<1536, 256, 0, stream>>>(ca_Wqkv, ca_bqkv, Wckv, bckv);
  k_embed<<<(int)Mpre, 256, 0, stream>>>(past, in_W, in_b, pos_emb, ln0_w, ln0_b, A);
  k_gemm_mf<<<dim3(1536 / 64, (int)Mpre / 128), 256, 0, stream>>>(
      A, Wckv, bckv, nullptr, nullptr, (int)Mpre, 1536, 256, 0, 2,
      nullptr, nullptr, nullptr, C6, PAST_N, 0);
  for (int l = 0; l < LAYERS; l++) layer(l, (int)Mpre, PAST_N, 0);
  k_readout<<<BATCH, 64, 0, stream>>>(A, out_W, out_b, past, cur, ndb, out, PAST_N, 0, 1);

  // ---- pack decode weight stream (into A scratch, dead after prefill) ----
  k_pack_stream<<<(TOTAL_ENT + 255) / 256, 256, 0, stream>>>(
      sa_Wqkv, sa_Wo, ca_Wqkv, ca_Wo, ff1_W, ff2_W, Wd);

  // ---- fused 19-step decode: one WG per batch element ----
  k_decode<<<BATCH, NT, 0, stream>>>(
      Wd, bckv, in_W, in_b, pos_emb, ln0_w, ln0_b,
      sa_bqkv, sa_bo, ca_bqkv, ca_bo, ff1_b, ff2_b,
      ln1_w, ln1_b, ln2_w, ln2_b, ln3_w, ln3_b,
      out_W, out_b, Ksa, Vsa, C6, ndb, cur, out);
}